// Round 12
// baseline (1520.734 us; speedup 1.0000x reference)
//
#include <hip/hip_runtime.h>
#include <stdint.h>

#define N_PTS 160000
#define C 128
#define K27 27
#define NCLU 2048
#define BN_EPS 1e-5f
#define KP 136   // padded LDS k-stride (bf16 elems) for K=128 GEMM tiles
#define KP2 264  // for K=256 fuse tile

typedef float f32x4 __attribute__((ext_vector_type(4)));
typedef float f32x16 __attribute__((ext_vector_type(16)));
typedef short s16x8 __attribute__((ext_vector_type(8)));

__device__ __forceinline__ float bf2f(unsigned short u){
  union { unsigned int i; float f; } v; v.i = ((unsigned int)u) << 16; return v.f;
}
__device__ __forceinline__ unsigned short f2bf(float f){
  union { float f; unsigned int i; } v; v.f = f;
  unsigned int u = v.i;
  u += 0x7FFFu + ((u >> 16) & 1u);
  return (unsigned short)(u >> 16);
}
__device__ __forceinline__ unsigned int pk(float a, float b){
  return (unsigned int)f2bf(a) | ((unsigned int)f2bf(b) << 16);
}
__device__ __forceinline__ void up2(int w, float& a, float& b){
  a = bf2f((unsigned short)(w & 0xFFFF));
  b = bf2f((unsigned short)(((unsigned int)w) >> 16));
}
__device__ __forceinline__ unsigned int encf(float f){
  union { float f; unsigned int i; } v; v.f = f;
  return ((int)v.i < 0) ? ~v.i : (v.i | 0x80000000u);
}
__device__ __forceinline__ float decf(unsigned int e){
  union { unsigned int i; float f; } v;
  v.i = ((int)e < 0) ? (e ^ 0x80000000u) : ~e;
  return v.f;
}
__device__ __forceinline__ void bn_coef(const float* st, const float* gamma, const float* beta,
                                        int c, float& sc, float& sh){
  float mean = st[c] * (1.0f / N_PTS);
  float var  = st[C + c] * (1.0f / N_PTS) - mean * mean;
  float g = gamma[c] * rsqrtf(fmaxf(var, 0.f) + BN_EPS);
  sc = g; sh = beta[c] - mean * g;
}

// ---------------- weight prep: f32 -> bf16, transposed to [n][k] ----------------
// tconv gets the conv-LDS XOR swizzle pre-applied (n&15: 16 slots over 32 lanes -> 2-way, free)
__global__ void k_prep_weights(const float* __restrict__ lw, const float* __restrict__ w,
                               const float* __restrict__ proj, const float* __restrict__ conv,
                               const float* __restrict__ fuse,
                               unsigned short* __restrict__ tlw, unsigned short* __restrict__ tw,
                               unsigned short* __restrict__ tproj, unsigned short* __restrict__ tconv,
                               unsigned short* __restrict__ tfuse)
{
  int z = blockIdx.x, tid = threadIdx.x;
  if (z < 64){
    const float* src; unsigned short* dst; bool swz = false;
    if (z < 3){ src = lw + z*16384; dst = tlw + z*16384; }
    else if (z < 6){ src = w + (z-3)*16384; dst = tw + (z-3)*16384; }
    else if (z < 10){ src = proj + (z-6)*16384; dst = tproj + (z-6)*16384; }
    else { src = conv + (z-10)*16384; dst = tconv + (z-10)*16384; swz = true; }
    for (int i = tid; i < 16384; i += 256){
      int n = i >> 7, k = i & 127;
      int pos = swz ? (n*128 + (((k >> 3) ^ (n & 15)) << 3) + (k & 7)) : i;
      dst[pos] = f2bf(src[k*128 + n]);
    }
  } else {
    for (int i = tid; i < 32768; i += 256){
      int n = i >> 8, k = i & 255;
      tfuse[i] = f2bf(fuse[k*128 + n]);
    }
  }
}

// ---------------- mask dtype detection (int32 vs packed bytes) ----------------
__global__ void k_detect_mask(const unsigned int* __restrict__ mw, int* __restrict__ mmode)
{
  __shared__ int flag;
  if (threadIdx.x == 0) flag = 0;
  __syncthreads();
  for (int i = threadIdx.x; i < 4096; i += 256)
    if (mw[i] > 1u) flag = 1;
  __syncthreads();
  if (threadIdx.x == 0) *mmode = flag;
}

// ---------------- cluster histogram / prefix / scatter ----------------
__global__ void k_hist(const int* __restrict__ c0, const int* __restrict__ c1,
                       const int* __restrict__ c2, int* __restrict__ hist)
{
  int idx = blockIdx.x*blockDim.x + threadIdx.x;
  int stride = gridDim.x*blockDim.x;
  for (; idx < 3*N_PTS; idx += stride){
    int j = idx / N_PTS, r = idx - j*N_PTS;
    const int* cp = (j==0)?c0:((j==1)?c1:c2);
    atomicAdd(&hist[j*NCLU + cp[r]], 1);
  }
}

__global__ void k_prefix(const int* __restrict__ hist, int* __restrict__ starts,
                         int* __restrict__ cursor)
{
  int j = blockIdx.x, tid = threadIdx.x;
  __shared__ int buf[NCLU];
  __shared__ int csum[256];
  for (int i = tid; i < NCLU; i += 256) buf[i] = hist[j*NCLU + i];
  __syncthreads();
  int s = 0;
  #pragma unroll
  for (int k = 0; k < 8; k++) s += buf[tid*8 + k];
  csum[tid] = s;
  __syncthreads();
  if (tid == 0){
    int run = 0;
    for (int i = 0; i < 256; i++){ int t = csum[i]; csum[i] = run; run += t; }
  }
  __syncthreads();
  int acc = csum[tid];
  #pragma unroll
  for (int k = 0; k < 8; k++){
    int i = tid*8 + k;
    starts[j*(NCLU+1) + i] = acc;
    cursor[j*NCLU + i] = acc;
    acc += buf[i];
  }
  if (tid == 255) starts[j*(NCLU+1) + NCLU] = acc;
}

__global__ void k_scatter(const int* __restrict__ c0, const int* __restrict__ c1,
                          const int* __restrict__ c2, int* __restrict__ cursor,
                          int* __restrict__ perm)
{
  int idx = blockIdx.x*blockDim.x + threadIdx.x;
  int stride = gridDim.x*blockDim.x;
  for (; idx < 3*N_PTS; idx += stride){
    int j = idx / N_PTS, r = idx - j*N_PTS;
    const int* cp = (j==0)?c0:((j==1)?c1:c2);
    int cl = cp[r];
    int slot = atomicAdd(&cursor[j*NCLU + cl], 1);
    perm[j*N_PTS + slot] = r;
  }
}

// ---------------- segment reduction V0: S1 = per-cluster sum of relu(bn(x)) ----------------
template<int V>
__global__ void k_seg(const unsigned short* __restrict__ X,
                      const int* __restrict__ perm, const int* __restrict__ starts,
                      const float* __restrict__ st, const float* __restrict__ gamma,
                      const float* __restrict__ beta, float* __restrict__ S)
{
  __shared__ float red[16*128];
  const int cl = blockIdx.x;
  const int p0 = starts[cl], p1 = starts[cl+1];
  const int g = threadIdx.x >> 4, s = threadIdx.x & 15;
  const int c0 = s * 8;
  float sc[8], sh[8];
  #pragma unroll
  for (int j = 0; j < 8; j++) bn_coef(st, gamma, beta, c0 + j, sc[j], sh[j]);
  float acc[8];
  #pragma unroll
  for (int j = 0; j < 8; j++) acc[j] = 0.f;
  for (int p = p0 + g; p < p1; p += 16){
    int row = perm[p];
    int4 v = *(const int4*)(X + (size_t)row*C + c0);
    float f[8];
    up2(v.x, f[0], f[1]); up2(v.y, f[2], f[3]); up2(v.z, f[4], f[5]); up2(v.w, f[6], f[7]);
    #pragma unroll
    for (int j = 0; j < 8; j++) acc[j] += fmaxf(f[j]*sc[j] + sh[j], 0.f);
  }
  #pragma unroll
  for (int j = 0; j < 8; j++) red[g*128 + c0 + j] = acc[j];
  __syncthreads();
  if (threadIdx.x < 128){
    float t = 0.f;
    #pragma unroll
    for (int gg = 0; gg < 16; gg++) t += red[gg*128 + threadIdx.x];
    S[cl*C + threadIdx.x] = t;
  }
}

// ---------------- single-pass seg12 ----------------
__global__ void k_seg12(const unsigned short* __restrict__ XP, const unsigned short* __restrict__ X2,
                        const int* __restrict__ perm, const int* __restrict__ starts,
                        const float* __restrict__ st, const float* __restrict__ gamma,
                        const float* __restrict__ beta, const unsigned int* __restrict__ genc,
                        float* __restrict__ S3)
{
  __shared__ float red[16*128];
  const int cl = blockIdx.x;
  const int p0 = starts[cl], p1 = starts[cl+1];
  const int g = threadIdx.x >> 4, s = threadIdx.x & 15;
  const int c0 = s * 8;
  const float gm = decf(*genc);
  float sc[8], sh[8];
  #pragma unroll
  for (int j = 0; j < 8; j++) bn_coef(st, gamma, beta, c0 + j, sc[j], sh[j]);

  float accN[8], accD[8];
  #pragma unroll
  for (int j = 0; j < 8; j++){ accN[j] = 0.f; accD[j] = 0.f; }
  for (int p = p0 + g; p < p1; p += 16){
    int row = perm[p];
    int4 v  = *(const int4*)(XP + (size_t)row*C + c0);
    int4 v2 = *(const int4*)(X2 + (size_t)row*C + c0);
    float f[8], x2[8];
    up2(v.x, f[0], f[1]); up2(v.y, f[2], f[3]); up2(v.z, f[4], f[5]); up2(v.w, f[6], f[7]);
    up2(v2.x, x2[0], x2[1]); up2(v2.y, x2[2], x2[3]); up2(v2.z, x2[4], x2[5]); up2(v2.w, x2[6], x2[7]);
    #pragma unroll
    for (int j = 0; j < 8; j++){
      float e = __expf(x2[j] - gm);
      accD[j] += e;
      accN[j] += fmaxf(f[j]*sc[j] + sh[j], 0.f) * e;
    }
  }
  #pragma unroll
  for (int j = 0; j < 8; j++) red[g*128 + c0 + j] = accN[j];
  __syncthreads();
  float tN = 0.f;
  if (threadIdx.x < 128){
    #pragma unroll
    for (int gg = 0; gg < 16; gg++) tN += red[gg*128 + threadIdx.x];
  }
  __syncthreads();
  #pragma unroll
  for (int j = 0; j < 8; j++) red[g*128 + c0 + j] = accD[j];
  __syncthreads();
  if (threadIdx.x < 128){
    float tD = 0.f;
    #pragma unroll
    for (int gg = 0; gg < 16; gg++) tD += red[gg*128 + threadIdx.x];
    S3[cl*C + threadIdx.x] = tN / (tD + 1e-6f);
  }
}

// ---------------- adaptive softmax weights (+ bf16 feat side-write) ----------------
__global__ void k_adp(const float* __restrict__ feat, const float* __restrict__ aW,
                      float* __restrict__ adp, unsigned short* __restrict__ featb)
{
  __shared__ float wsh[384];
  int tid = threadIdx.x;
  for (int i = tid; i < 384; i += 256) wsh[i] = aW[i];
  __syncthreads();
  int gidx = blockIdx.x*256 + tid;
  int stride = gridDim.x*256;
  for (int t4 = gidx; t4 < N_PTS*4; t4 += stride){
    int row = t4 >> 2, part = t4 & 3;
    float e0=0.f, e1=0.f, e2=0.f;
    const float* fr = feat + (size_t)row*C + part*32;
    unsigned int pb[16];
    #pragma unroll
    for (int c = 0; c < 32; c += 4){
      float4 v = *(const float4*)(fr + c);
      int cc = part*32 + c;
      e0 += v.x*wsh[cc*3+0] + v.y*wsh[(cc+1)*3+0] + v.z*wsh[(cc+2)*3+0] + v.w*wsh[(cc+3)*3+0];
      e1 += v.x*wsh[cc*3+1] + v.y*wsh[(cc+1)*3+1] + v.z*wsh[(cc+2)*3+1] + v.w*wsh[(cc+3)*3+1];
      e2 += v.x*wsh[cc*3+2] + v.y*wsh[(cc+1)*3+2] + v.z*wsh[(cc+2)*3+2] + v.w*wsh[(cc+3)*3+2];
      pb[(c>>1)]   = pk(v.x, v.y);
      pb[(c>>1)+1] = pk(v.z, v.w);
    }
    if (featb){
      int4* dst = (int4*)(featb + (size_t)row*C + part*32);
      dst[0] = make_int4(pb[0], pb[1], pb[2], pb[3]);
      dst[1] = make_int4(pb[4], pb[5], pb[6], pb[7]);
      dst[2] = make_int4(pb[8], pb[9], pb[10], pb[11]);
      dst[3] = make_int4(pb[12], pb[13], pb[14], pb[15]);
    }
    e0 += __shfl_xor(e0, 1); e0 += __shfl_xor(e0, 2);
    e1 += __shfl_xor(e1, 1); e1 += __shfl_xor(e1, 2);
    e2 += __shfl_xor(e2, 1); e2 += __shfl_xor(e2, 2);
    if (part == 0){
      float m = fmaxf(e0, fmaxf(e1, e2));
      float p0 = __expf(e0-m), p1 = __expf(e1-m), p2 = __expf(e2-m);
      float inv = 1.f/(p0+p1+p2);
      adp[row*3+0] = p0*inv; adp[row*3+1] = p1*inv; adp[row*3+2] = p2*inv;
    }
  }
}

// shared stats epilogue for 4-wave GEMM blocks (sred must hold 1024 floats)
__device__ __forceinline__ void gemm_stats_epi(float* csum, float* csq, float* sred,
                                               int wave, int l4, int l16, int tid,
                                               float* __restrict__ stats)
{
  #pragma unroll
  for (int t = 0; t < 8; t++){
    csum[t] += __shfl_xor(csum[t], 16); csum[t] += __shfl_xor(csum[t], 32);
    csq[t]  += __shfl_xor(csq[t], 16);  csq[t]  += __shfl_xor(csq[t], 32);
  }
  if (l4 == 0){
    #pragma unroll
    for (int t = 0; t < 8; t++){
      sred[wave*128 + t*16 + l16] = csum[t];
      sred[512 + wave*128 + t*16 + l16] = csq[t];
    }
  }
  __syncthreads();
  if (tid < 128){
    float s = 0.f, q = 0.f;
    #pragma unroll
    for (int w2 = 0; w2 < 4; w2++){ s += sred[w2*128 + tid]; q += sred[512 + w2*128 + tid]; }
    atomicAdd(&stats[tid], s);
    atomicAdd(&stats[C + tid], q);
  }
}

// A staging helper: 64 rows x 128 k into As (bf16)
template<typename AT>
__device__ __forceinline__ void stage_A(const AT* __restrict__ A, unsigned short* As,
                                        int row0, int r, int s)
{
  #pragma unroll
  for (int p = 0; p < 4; p++){
    int rr = r + p * 16;
    if constexpr (sizeof(AT) == 2){
      *(int4*)(As + rr * KP + s * 8) =
        *(const int4*)((const unsigned short*)A + (size_t)(row0 + rr) * C + s * 8);
    } else {
      const float4* ap = (const float4*)((const float*)A + (size_t)(row0 + rr) * C + s * 8);
      float4 x = ap[0], y = ap[1];
      *(int4*)(As + rr * KP + s * 8) =
        make_int4(pk(x.x,x.y), pk(x.z,x.w), pk(y.x,y.y), pk(y.z,y.w));
    }
  }
}

// ---------------- GEMM: out[N,128] = A @ Bt, + fused column stats ----------------
template<typename AT>
__global__ __launch_bounds__(256, 3)
void k_gemm_plain(const AT* __restrict__ A, const unsigned short* __restrict__ Bt,
                  unsigned short* __restrict__ Out, float* __restrict__ stats)
{
  __shared__ unsigned short As[64 * KP];
  __shared__ unsigned short Bs[128 * KP];
  const int tid = threadIdx.x;
  const int row0 = blockIdx.x * 64;
  const int r = tid >> 4, s = tid & 15;
  stage_A<AT>(A, As, row0, r, s);
  #pragma unroll
  for (int p = 0; p < 8; p++){
    int nn = r + p * 16;
    *(int4*)(Bs + nn * KP + s * 8) = *(const int4*)(Bt + nn * C + s * 8);
  }
  __syncthreads();
  const int lane = tid & 63, wave = tid >> 6;
  const int l16 = lane & 15, l4 = lane >> 4, m0 = wave * 16;
  f32x4 acc[8];
  #pragma unroll
  for (int t = 0; t < 8; t++) acc[t] = (f32x4){0.f,0.f,0.f,0.f};
  #pragma unroll
  for (int kk = 0; kk < 4; kk++){
    s16x8 a = *(const s16x8*)(As + (m0 + l16) * KP + kk * 32 + l4 * 8);
    #pragma unroll
    for (int t = 0; t < 8; t++){
      s16x8 b = *(const s16x8*)(Bs + (t * 16 + l16) * KP + kk * 32 + l4 * 8);
      acc[t] = __builtin_amdgcn_mfma_f32_16x16x32_bf16(a, b, acc[t], 0, 0, 0);
    }
  }
  float csum[8], csq[8];
  #pragma unroll
  for (int t = 0; t < 8; t++){
    float ss = 0.f, qq = 0.f;
    #pragma unroll
    for (int q = 0; q < 4; q++){
      float v = acc[t][q];
      int grow = row0 + m0 + l4 * 4 + q;
      Out[(size_t)grow * C + t * 16 + l16] = f2bf(v);
      ss += v; qq += v*v;
    }
    csum[t] = ss; csq[t] = qq;
  }
  __syncthreads();
  gemm_stats_epi(csum, csq, (float*)As, wave, l4, l16, tid, stats);
}

// ---------------- dual GEMM: two weight matrices, A staged once ----------------
template<typename AT>
__global__ __launch_bounds__(256, 3)
void k_gemm_dual(const AT* __restrict__ A,
                 const unsigned short* __restrict__ Bt0, const unsigned short* __restrict__ Bt1,
                 unsigned short* __restrict__ Out0, unsigned short* __restrict__ Out1,
                 float* __restrict__ stats0, float* __restrict__ stats1)
{
  __shared__ unsigned short As[64 * KP];
  __shared__ unsigned short Bs[128 * KP];
  const int tid = threadIdx.x;
  const int row0 = blockIdx.x * 64;
  const int r = tid >> 4, s = tid & 15;
  const int lane = tid & 63, wave = tid >> 6;
  const int l16 = lane & 15, l4 = lane >> 4, m0 = wave * 16;

  stage_A<AT>(A, As, row0, r, s);
  #pragma unroll
  for (int p = 0; p < 8; p++){
    int nn = r + p * 16;
    *(int4*)(Bs + nn * KP + s * 8) = *(const int4*)(Bt0 + nn * C + s * 8);
  }
  __syncthreads();

  f32x4 acc[8];
  float csum0[8], csq0[8], csum1[8], csq1[8];

  #pragma unroll
  for (int t = 0; t < 8; t++) acc[t] = (f32x4){0.f,0.f,0.f,0.f};
  #pragma unroll
  for (int kk = 0; kk < 4; kk++){
    s16x8 a = *(const s16x8*)(As + (m0 + l16) * KP + kk * 32 + l4 * 8);
    #pragma unroll
    for (int t = 0; t < 8; t++){
      s16x8 b = *(const s16x8*)(Bs + (t * 16 + l16) * KP + kk * 32 + l4 * 8);
      acc[t] = __builtin_amdgcn_mfma_f32_16x16x32_bf16(a, b, acc[t], 0, 0, 0);
    }
  }
  #pragma unroll
  for (int t = 0; t < 8; t++){
    float ss = 0.f, qq = 0.f;
    #pragma unroll
    for (int q = 0; q < 4; q++){
      float v = acc[t][q];
      int grow = row0 + m0 + l4 * 4 + q;
      Out0[(size_t)grow * C + t * 16 + l16] = f2bf(v);
      ss += v; qq += v*v;
    }
    csum0[t] = ss; csq0[t] = qq;
  }
  __syncthreads();
  #pragma unroll
  for (int p = 0; p < 8; p++){
    int nn = r + p * 16;
    *(int4*)(Bs + nn * KP + s * 8) = *(const int4*)(Bt1 + nn * C + s * 8);
  }
  __syncthreads();

  #pragma unroll
  for (int t = 0; t < 8; t++) acc[t] = (f32x4){0.f,0.f,0.f,0.f};
  #pragma unroll
  for (int kk = 0; kk < 4; kk++){
    s16x8 a = *(const s16x8*)(As + (m0 + l16) * KP + kk * 32 + l4 * 8);
    #pragma unroll
    for (int t = 0; t < 8; t++){
      s16x8 b = *(const s16x8*)(Bs + (t * 16 + l16) * KP + kk * 32 + l4 * 8);
      acc[t] = __builtin_amdgcn_mfma_f32_16x16x32_bf16(a, b, acc[t], 0, 0, 0);
    }
  }
  #pragma unroll
  for (int t = 0; t < 8; t++){
    float ss = 0.f, qq = 0.f;
    #pragma unroll
    for (int q = 0; q < 4; q++){
      float v = acc[t][q];
      int grow = row0 + m0 + l4 * 4 + q;
      Out1[(size_t)grow * C + t * 16 + l16] = f2bf(v);
      ss += v; qq += v*v;
    }
    csum1[t] = ss; csq1[t] = qq;
  }
  __syncthreads();
  gemm_stats_epi(csum0, csq0, (float*)As, wave, l4, l16, tid, stats0);
  __syncthreads();
  gemm_stats_epi(csum1, csq1, (float*)As, wave, l4, l16, tid, stats1);
}

// ---------------- GEMM: (relu(bn(x)) - clustermean) @ w_W + global max ----------------
__global__ __launch_bounds__(256, 3)
void k_gemm_center(const unsigned short* __restrict__ PW, const unsigned short* __restrict__ Bt,
                   const int* __restrict__ cla, const float* __restrict__ S1,
                   const int* __restrict__ cnt, const float* __restrict__ st,
                   const float* __restrict__ gamma, const float* __restrict__ beta,
                   unsigned short* __restrict__ Out, unsigned int* __restrict__ gmax)
{
  __shared__ unsigned short As[64 * KP];
  __shared__ unsigned short Bs[128 * KP];
  __shared__ float wred[4];
  const int tid = threadIdx.x;
  const int row0 = blockIdx.x * 64;
  const int r = tid >> 4, s = tid & 15;
  float sc[8], sh[8];
  #pragma unroll
  for (int j = 0; j < 8; j++) bn_coef(st, gamma, beta, s*8 + j, sc[j], sh[j]);
  #pragma unroll
  for (int p = 0; p < 4; p++){
    int rr = r + p * 16;
    int grow = row0 + rr;
    int cl = cla[grow];
    float inv = 1.f / fmaxf(1.f, (float)cnt[cl]);
    int4 v = *(const int4*)(PW + (size_t)grow * C + s * 8);
    const float4* mp = (const float4*)(S1 + cl * C + s * 8);
    float4 ma = mp[0], mb = mp[1];
    float f[8];
    up2(v.x, f[0], f[1]); up2(v.y, f[2], f[3]); up2(v.z, f[4], f[5]); up2(v.w, f[6], f[7]);
    float m8[8] = {ma.x,ma.y,ma.z,ma.w,mb.x,mb.y,mb.z,mb.w};
    float o[8];
    #pragma unroll
    for (int j = 0; j < 8; j++) o[j] = fmaxf(f[j]*sc[j] + sh[j], 0.f) - m8[j]*inv;
    *(int4*)(As + rr * KP + s * 8) = make_int4(pk(o[0],o[1]), pk(o[2],o[3]), pk(o[4],o[5]), pk(o[6],o[7]));
  }
  #pragma unroll
  for (int p = 0; p < 8; p++){
    int nn = r + p * 16;
    *(int4*)(Bs + nn * KP + s * 8) = *(const int4*)(Bt + nn * C + s * 8);
  }
  __syncthreads();
  const int lane = tid & 63, wave = tid >> 6;
  const int l16 = lane & 15, l4 = lane >> 4, m0 = wave * 16;
  f32x4 acc[8];
  #pragma unroll
  for (int t = 0; t < 8; t++) acc[t] = (f32x4){0.f,0.f,0.f,0.f};
  #pragma unroll
  for (int kk = 0; kk < 4; kk++){
    s16x8 a = *(const s16x8*)(As + (m0 + l16) * KP + kk * 32 + l4 * 8);
    #pragma unroll
    for (int t = 0; t < 8; t++){
      s16x8 b = *(const s16x8*)(Bs + (t * 16 + l16) * KP + kk * 32 + l4 * 8);
      acc[t] = __builtin_amdgcn_mfma_f32_16x16x32_bf16(a, b, acc[t], 0, 0, 0);
    }
  }
  float mx = -3.4e38f;
  #pragma unroll
  for (int t = 0; t < 8; t++){
    #pragma unroll
    for (int q = 0; q < 4; q++){
      int grow = row0 + m0 + l4 * 4 + q;
      unsigned short ob = f2bf(acc[t][q]);
      Out[(size_t)grow * C + t * 16 + l16] = ob;
      mx = fmaxf(mx, bf2f(ob));
    }
  }
  #pragma unroll
  for (int off = 32; off; off >>= 1) mx = fmaxf(mx, __shfl_xor(mx, off));
  if ((tid & 63) == 0) wred[tid >> 6] = mx;
  __syncthreads();
  if (tid == 0){
    float m = fmaxf(fmaxf(wred[0], wred[1]), fmaxf(wred[2], wred[3]));
    atomicMax(gmax, encf(m));
  }
}

// ---------------- fuse GEMM: [relu(bn(xp3)), fused] @ fuse_W, K=256, + stats ----------------
__global__ __launch_bounds__(256, 2)
void k_gemm_fuse(const unsigned short* __restrict__ XP3, const float* __restrict__ adp,
                 const int* __restrict__ cl0, const int* __restrict__ cl1,
                 const int* __restrict__ cl2, const float* __restrict__ S3,
                 const float* __restrict__ st, const float* __restrict__ gamma,
                 const float* __restrict__ beta, const unsigned short* __restrict__ Bt,
                 unsigned short* __restrict__ Out, float* __restrict__ stats)
{
  __shared__ unsigned short As[64 * KP2];
  __shared__ unsigned short Bs[128 * KP];
  __shared__ float scs[C], shs[C];
  const int tid = threadIdx.x;
  if (tid < C){ float a, b; bn_coef(st, gamma, beta, tid, a, b); scs[tid] = a; shs[tid] = b; }
  __syncthreads();
  const int row0 = blockIdx.x * 64;
  const int r8 = tid >> 5, s = tid & 31;
  const int r = tid >> 4, s16i = tid & 15;
  #pragma unroll
  for (int p = 0; p < 8; p++){
    int rr = r8 + p * 8;
    int grow = row0 + rr;
    if (s < 16){
      int c0 = s * 8;
      int4 v = *(const int4*)(XP3 + (size_t)grow * C + c0);
      float f0,f1,f2,f3,f4,f5,f6,f7;
      up2(v.x,f0,f1); up2(v.y,f2,f3); up2(v.z,f4,f5); up2(v.w,f6,f7);
      float o0 = fmaxf(f0*scs[c0+0]+shs[c0+0],0.f), o1 = fmaxf(f1*scs[c0+1]+shs[c0+1],0.f);
      float o2 = fmaxf(f2*scs[c0+2]+shs[c0+2],0.f), o3 = fmaxf(f3*scs[c0+3]+shs[c0+3],0.f);
      float o4 = fmaxf(f4*scs[c0+4]+shs[c0+4],0.f), o5 = fmaxf(f5*scs[c0+5]+shs[c0+5],0.f);
      float o6 = fmaxf(f6*scs[c0+6]+shs[c0+6],0.f), o7 = fmaxf(f7*scs[c0+7]+shs[c0+7],0.f);
      *(int4*)(As + rr * KP2 + c0) = make_int4(pk(o0,o1), pk(o2,o3), pk(o4,o5), pk(o6,o7));
    } else {
      int c0 = (s - 16) * 8;
      float a0 = adp[grow*3+0], a1 = adp[grow*3+1], a2 = adp[grow*3+2];
      const float* p0 = S3 + (size_t)cl0[grow] * C + c0;
      const float* p1 = S3 + (size_t)NCLU * C + (size_t)cl1[grow] * C + c0;
      const float* p2 = S3 + (size_t)2 * NCLU * C + (size_t)cl2[grow] * C + c0;
      float o[8];
      #pragma unroll
      for (int j = 0; j < 8; j++) o[j] = a0*p0[j] + a1*p1[j] + a2*p2[j];
      *(int4*)(As + rr * KP2 + 128 + c0) = make_int4(pk(o[0],o[1]), pk(o[2],o[3]), pk(o[4],o[5]), pk(o[6],o[7]));
    }
  }
  const int lane = tid & 63, wave = tid >> 6;
  const int l16 = lane & 15, l4 = lane >> 4, m0 = wave * 16;
  f32x4 acc[8];
  #pragma unroll
  for (int t = 0; t < 8; t++) acc[t] = (f32x4){0.f,0.f,0.f,0.f};
  #pragma unroll
  for (int h = 0; h < 2; h++){
    if (h) __syncthreads();
    #pragma unroll
    for (int p = 0; p < 8; p++){
      int nn = r + p * 16;
      *(int4*)(Bs + nn * KP + s16i * 8) = *(const int4*)(Bt + nn * 256 + h * 128 + s16i * 8);
    }
    __syncthreads();
    #pragma unroll
    for (int kk = 0; kk < 4; kk++){
      s16x8 a = *(const s16x8*)(As + (m0 + l16) * KP2 + h * 128 + kk * 32 + l4 * 8);
      #pragma unroll
      for (int t = 0; t < 8; t++){
        s16x8 b = *(const s16x8*)(Bs + (t * 16 + l16) * KP + kk * 32 + l4 * 8);
        acc[t] = __builtin_amdgcn_mfma_f32_16x16x32_bf16(a, b, acc[t], 0, 0, 0);
      }
    }
  }
  float csum[8], csq[8];
  #pragma unroll
  for (int t = 0; t < 8; t++){
    float ss = 0.f, qq = 0.f;
    #pragma unroll
    for (int q = 0; q < 4; q++){
      float v = acc[t][q];
      int grow = row0 + m0 + l4 * 4 + q;
      Out[(size_t)grow * C + t * 16 + l16] = f2bf(v);
      ss += v; qq += v*v;
    }
    csum[t] = ss; csq[t] = qq;
  }
  __syncthreads();
  gemm_stats_epi(csum, csq, (float*)As, wave, l4, l16, tid, stats);
}

// ---------------- submanifold conv v12: 32x32x16 MFMA, 6 waves, 3 waves/SIMD ----------------
__device__ __forceinline__ int ld_midx(const int* __restrict__ nbr, const void* __restrict__ maskp,
                                       int mm, int g){
  bool on = mm ? (((const unsigned char*)maskp)[g] != 0)
               : (((const int*)maskp)[g] != 0);
  int v = nbr[g];
  return on ? v : -1;
}

#define CONV_T 384
#define CONV_ROWS 192

template<typename OT>
__global__ __launch_bounds__(CONV_T, 3)
void k_conv(const unsigned short* __restrict__ In, const unsigned short* __restrict__ Wt,
            const int* __restrict__ nbr, const void* __restrict__ maskp,
            const int* __restrict__ mmode, OT* __restrict__ Out, float* __restrict__ stats)
{
  __shared__ unsigned short Bs[2][128*128];   // 64 KiB, pre-swizzled source
  const int tid = threadIdx.x;
  const int lane = tid & 63, wave = tid >> 6;   // 6 waves
  const int l31 = lane & 31, half = lane >> 5;
  const int row0 = blockIdx.x * CONV_ROWS;      // 192 rows/block, 32 rows/wave
  const int mm = *mmode;
  const int rg = row0 + wave*32 + l31;          // this lane's row
  const bool rok = rg < N_PTS;
  const int rgs = rok ? rg : 0;                 // safe row for idx loads
  const s16x8 z8 = (s16x8){0,0,0,0,0,0,0,0};

  auto stage_B = [&](int buf, int k){
    const char* gsrc = (const char*)(Wt + k*16384);
    char* lbase = (char*)&Bs[buf][0];
    #pragma unroll
    for (int p = 0; p < 5; p++){
      int chunk = p*CONV_T + wave*64;           // wave-uniform LDS base (0..1919)
      __builtin_amdgcn_global_load_lds(
        (const unsigned int*)(gsrc + (size_t)(chunk + lane)*16),
        (unsigned int*)(lbase + (size_t)chunk*16), 16, 0, 0);
    }
    if (wave < 2){                              // remainder 1920..2047
      int chunk = 1920 + wave*64;
      __builtin_amdgcn_global_load_lds(
        (const unsigned int*)(gsrc + (size_t)(chunk + lane)*16),
        (unsigned int*)(lbase + (size_t)chunk*16), 16, 0, 0);
    }
  };

  f32x16 acc[4];
  #pragma unroll
  for (int t = 0; t < 4; t++)
    acc[t] = (f32x16){0,0,0,0,0,0,0,0,0,0,0,0,0,0,0,0};

  s16x8 A0[8], A1[8];
  auto gather = [&](s16x8* dA, int gi){
    #pragma unroll
    for (int s = 0; s < 8; s++)
      dA[s] = (gi >= 0) ? *(const s16x8*)(In + (size_t)gi*C + s*16 + half*8) : z8;
  };
  auto compute = [&](const s16x8* a, int buf){
    #pragma unroll
    for (int s = 0; s < 8; s++){
      #pragma unroll
      for (int t = 0; t < 4; t++){
        int n = t*32 + l31;
        s16x8 b = *(const s16x8*)(&Bs[buf][n*128 + (((s*2 + half) ^ (n & 15)) << 3)]);
        acc[t] = __builtin_amdgcn_mfma_f32_32x32x16_bf16(a[s], b, acc[t], 0, 0, 0);
      }
    }
  };
  auto midx = [&](int k)->int{
    int v = ld_midx(nbr, maskp, mm, rgs*K27 + k);
    return rok ? v : -1;
  };

  // prologue: B[0], A(k=0), idx(k=1)
  stage_B(0, 0);
  int i0 = midx(0);
  gather(A0, i0);
  i0 = midx(1);
  __syncthreads();

  #pragma unroll 1
  for (int kb = 0; kb < 13; kb++){
    const int k = kb * 2;
    stage_B(1, k + 1);
    gather(A1, i0);
    i0 = midx(k + 2);
    compute(A0, 0);
    __syncthreads();
    stage_B(0, k + 2);
    gather(A0, i0);
    if (kb < 12) i0 = midx(k + 3);
    compute(A1, 1);
    __syncthreads();
  }
  compute(A0, 0);   // k = 26

  // epilogue: write + fused column stats
  // C/D layout (verified): col = lane&31, row = (reg&3) + 8*(reg>>2) + 4*(lane>>5)
  float csum[4], csq[4];
  #pragma unroll
  for (int t = 0; t < 4; t++){
    float ss = 0.f, qq = 0.f;
    #pragma unroll
    for (int r = 0; r < 16; r++){
      float v = acc[t][r];
      int grow = row0 + wave*32 + (r & 3) + 8*(r >> 2) + 4*half;
      if (grow < N_PTS){
        if constexpr (sizeof(OT) == 2) Out[(size_t)grow * C + t*32 + l31] = f2bf(v);
        else                           Out[(size_t)grow * C + t*32 + l31] = v;
      }
      ss += v; qq += v*v;   // OOB rows have acc=0 -> harmless
    }
    csum[t] = ss; csq[t] = qq;
  }
  #pragma unroll
  for (int t = 0; t < 4; t++){
    csum[t] += __shfl_xor(csum[t], 32);
    csq[t]  += __shfl_xor(csq[t], 32);
  }
  __syncthreads();
  float* sred = (float*)Bs;   // 6 waves x 128 cols (sum) + same (sq)
  if (half == 0){
    #pragma unroll
    for (int t = 0; t < 4; t++){
      sred[wave*128 + t*32 + l31] = csum[t];
      sred[768 + wave*128 + t*32 + l31] = csq[t];
    }
  }
  __syncthreads();
  if (tid < 128){
    float s = 0.f, q = 0.f;
    #pragma unroll
    for (int w2 = 0; w2 < 6; w2++){ s += sred[w2*128 + tid]; q += sred[768 + w2*128 + tid]; }
    atomicAdd(&stats[tid], s);
    atomicAdd(&stats[C + tid], q);
  }
}

// ---------------- elementwise kernels ----------------
template<int RELU>
__global__ void k_bnapply(const unsigned short* __restrict__ X, unsigned short* __restrict__ Y,
                          const float* __restrict__ st, const float* __restrict__ gamma,
                          const float* __restrict__ beta)
{
  const int total = N_PTS * 16;
  for (int idx = blockIdx.x*blockDim.x + threadIdx.x; idx < total; idx += gridDim.x*blockDim.x){
    int c0 = (idx & 15) * 8;
    int4 v = *(const int4*)(X + (size_t)idx * 8);
    float f[8];
    up2(v.x, f[0], f[1]); up2(v.y, f[2], f[3]); up2(v.z, f[4], f[5]); up2(v.w, f[6], f[7]);
    float o[8];
    #pragma unroll
    for (int j = 0; j < 8; j++){
      float sc, sh; bn_coef(st, gamma, beta, c0 + j, sc, sh);
      float t = f[j] * sc + sh;
      if (RELU) t = fmaxf(t, 0.f);
      o[j] = t;
    }
    *(int4*)(Y + (size_t)idx * 8) = make_int4(pk(o[0],o[1]), pk(o[2],o[3]), pk(o[4],o[5]), pk(o[6],o[7]));
  }
}

__global__ void k_fres(const unsigned short* __restrict__ G, const float* __restrict__ st,
                       const float* __restrict__ gamma, const float* __restrict__ beta,
                       const float* __restrict__ feat, unsigned short* __restrict__ FB)
{
  const int total = N_PTS * 16;
  for (int idx = blockIdx.x*blockDim.x + threadIdx.x; idx < total; idx += gridDim.x*blockDim.x){
    int c0 = (idx & 15) * 8;
    int4 v = *(const int4*)(G + (size_t)idx * 8);
    float f[8];
    up2(v.x, f[0], f[1]); up2(v.y, f[2], f[3]); up2(v.z, f[4], f[5]); up2(v.w, f[6], f[7]);
    const float4* fp = (const float4*)(feat + (size_t)idx * 8);
    float4 fa = fp[0], fb4 = fp[1];
    float fe[8] = {fa.x,fa.y,fa.z,fa.w,fb4.x,fb4.y,fb4.z,fb4.w};
    float o[8];
    #pragma unroll
    for (int j = 0; j < 8; j++){
      float sc, sh; bn_coef(st, gamma, beta, c0 + j, sc, sh);
      o[j] = fmaxf(f[j]*sc + sh, 0.f) + fe[j];
    }
    *(int4*)(FB + (size_t)idx * 8) = make_int4(pk(o[0],o[1]), pk(o[2],o[3]), pk(o[4],o[5]), pk(o[6],o[7]));
  }
}

__global__ void k_final(float* __restrict__ H2, const float* __restrict__ st,
                        const float* __restrict__ gamma, const float* __restrict__ beta,
                        const unsigned short* __restrict__ FB)
{
  const int total = N_PTS * 16;
  for (int idx = blockIdx.x*blockDim.x + threadIdx.x; idx < total; idx += gridDim.x*blockDim.x){
    int c0 = (idx & 15) * 8;
    float4* hp = (float4*)(H2 + (size_t)idx * 8);
    float4 a = hp[0], b = hp[1];
    int4 vf = *(const int4*)(FB + (size_t)idx * 8);
    float fr[8];
    up2(vf.x, fr[0], fr[1]); up2(vf.y, fr[2], fr[3]); up2(vf.z, fr[4], fr[5]); up2(vf.w, fr[6], fr[7]);
    float h[8] = {a.x,a.y,a.z,a.w,b.x,b.y,b.z,b.w};
    #pragma unroll
    for (int j = 0; j < 8; j++){
      float sc, sh; bn_coef(st, gamma, beta, c0 + j, sc, sh);
      h[j] = fmaxf(h[j]*sc + sh + fr[j], 0.f);
    }
    hp[0] = make_float4(h[0],h[1],h[2],h[3]);
    hp[1] = make_float4(h[4],h[5],h[6],h[7]);
  }
}

extern "C" void kernel_launch(void* const* d_in, const int* in_sizes, int n_in,
                              void* d_out, int out_size, void* d_ws, size_t ws_size,
                              hipStream_t stream)
{
  (void)in_sizes; (void)n_in; (void)out_size;
  const float* feat   = (const float*)d_in[0];
  const int* cls[3]   = {(const int*)d_in[1], (const int*)d_in[2], (const int*)d_in[3]};
  const int* nbr      = (const int*)d_in[4];
  const void* mask    = d_in[5];
  const float* lw_W   = (const float*)d_in[6];
  const float* lw_g   = (const float*)d_in[7];
  const float* lw_b   = (const float*)d_in[8];
  const float* w_W    = (const float*)d_in[9];
  const float* proj_W = (const float*)d_in[10];
  const float* proj_g = (const float*)d_in[11];
  const float* proj_b = (const float*)d_in[12];
  const float* adW    = (const float*)d_in[13];
  const float* fuse_W = (const float*)d_in[14];
  const float* fuse_g = (const float*)d_in[15];
  const float* fuse_b = (const float*)d_in[16];
  const float* conv_W = (const float*)d_in[17];
  const float* conv_g = (const float*)d_in[18];
  const float* conv_b = (const float*)d_in[19];

  char* w = (char*)d_ws;
  float*          stats  = (float*)(w + 0);            // 10 slots x 256 f32
  unsigned int*   gmax   = (unsigned int*)(w + 10240); // 3
  int*            mmode  = (int*)(w + 10240 + 16);
  int*            hist   = (int*)(w + 10496);          // 3*2048
  int*            starts = (int*)(w + 35072);          // 3*2049
  int*            cursor = (int*)(w + 59904);          // 3*2048
  int*            perm   = (int*)(w + 84480);          // 3*N
  float*          S1     = (float*)(w + 2004480);      // 2048*128
  float*          S3     = (float*)(w + 4101632);      // 3*2048*128
  float*          adp    = (float*)(w + 7247360);      // N*3
  unsigned short* tlw    = (unsigned short*)(w + 9167360);
  unsigned short* tw     = (unsigned short*)(w + 9265664);
  unsigned short* tproj  = (unsigned short*)(w + 9363968);
  unsigned short* tfuse  = (unsigned short*)(w + 9495040);
  unsigned short* tconv  = (unsigned short*)(w + 9560576);
  unsigned short* B1     = (unsigned short*)(w + 11330048);
  unsigned short* B2     = (unsigned short*)(w + 52290048);
  unsigned short* B3     = (unsigned short*)(w + 93250048);
  // base ws usage: 134,210,048 bytes; optional featb adds 40,960,000
  const bool useb = ws_size >= (size_t)175170048;
  unsigned short* featb = useb ? (unsigned short*)(w + 134210048) : nullptr;

  hipMemsetAsync(d_ws, 0, 35072, stream); // stats + gmax + mmode + hist

  k_prep_weights<<<65, 256, 0, stream>>>(lw_W, w_W, proj_W, conv_W, fuse_W,
                                         tlw, tw, tproj, tconv, tfuse);
  k_detect_mask<<<1, 256, 0, stream>>>((const unsigned int*)mask, mmode);
  k_hist<<<1024, 256, 0, stream>>>(cls[0], cls[1], cls[2], hist);
  k_prefix<<<3, 256, 0, stream>>>(hist, starts, cursor);
  k_scatter<<<1024, 256, 0, stream>>>(cls[0], cls[1], cls[2], cursor, perm);
  k_adp<<<2500, 256, 0, stream>>>(feat, adW, adp, featb);

  if (useb) k_gemm_plain<unsigned short><<<2500, 256, 0, stream>>>(featb, tlw, B1, stats);
  else      k_gemm_plain<float><<<2500, 256, 0, stream>>>(feat, tlw, B1, stats);

  for (int i = 0; i < 3; i++){
    k_seg<0><<<2048, 256, 0, stream>>>(B1, perm + i*N_PTS, starts + i*(NCLU+1),
                                       stats + i*256, lw_g + i*C, lw_b + i*C, S1);
    k_gemm_center<<<2500, 256, 0, stream>>>(B1, tw + i*16384, cls[i], S1, hist + i*NCLU,
                                            stats + i*256, lw_g + i*C, lw_b + i*C, B3, gmax + i);
    const unsigned short* w0 = tproj + i*16384;
    const unsigned short* w1 = (i < 2) ? (tlw + (i+1)*16384) : (tproj + 3*16384);
    float* st1 = (i < 2) ? (stats + (i+1)*256) : (stats + 6*256);
    if (useb) k_gemm_dual<unsigned short><<<2500, 256, 0, stream>>>(featb, w0, w1, B2, B1,
                                                                    stats + (3+i)*256, st1);
    else      k_gemm_dual<float><<<2500, 256, 0, stream>>>(feat, w0, w1, B2, B1,
                                                           stats + (3+i)*256, st1);
    k_seg12<<<2048, 256, 0, stream>>>(B2, B3, perm + i*N_PTS, starts + i*(NCLU+1),
                                      stats + (3+i)*256, proj_g + i*C, proj_b + i*C,
                                      gmax + i, S3 + (size_t)i*NCLU*C);
  }

  k_gemm_fuse<<<2500, 256, 0, stream>>>(B1, adp, cls[0], cls[1], cls[2], S3,
                                        stats + 6*256, proj_g + 3*C, proj_b + 3*C, tfuse,
                                        B2, stats + 7*256);
  k_fres<<<2048, 256, 0, stream>>>(B2, stats + 7*256, fuse_g, fuse_b, feat, B3);

  const int convGrid = (N_PTS + CONV_ROWS - 1) / CONV_ROWS;  // 834
  k_conv<unsigned short><<<convGrid, CONV_T, 0, stream>>>(B3, tconv, nbr, mask, mmode, B1, stats + 8*256);
  k_bnapply<1><<<2048, 256, 0, stream>>>(B1, B2, stats + 8*256, conv_g, conv_b);
  k_conv<float><<<convGrid, CONV_T, 0, stream>>>(B2, tconv + 27*16384, nbr, mask, mmode,
                                                 (float*)d_out, stats + 9*256);
  k_final<<<2048, 256, 0, stream>>>((float*)d_out, stats + 9*256, conv_g + C, conv_b + C, B3);
}

// Round 13
// 1413.879 us; speedup vs baseline: 1.0756x; 1.0756x over previous
//
#include <hip/hip_runtime.h>
#include <stdint.h>

#define N_PTS 160000
#define C 128
#define K27 27
#define NCLU 2048
#define BN_EPS 1e-5f
#define KP 136   // padded LDS k-stride (bf16 elems) for K=128 GEMM tiles
#define KP2 264  // for K=256 fuse tile

typedef float f32x4 __attribute__((ext_vector_type(4)));
typedef float f32x16 __attribute__((ext_vector_type(16)));
typedef short s16x8 __attribute__((ext_vector_type(8)));

__device__ __forceinline__ float bf2f(unsigned short u){
  union { unsigned int i; float f; } v; v.i = ((unsigned int)u) << 16; return v.f;
}
__device__ __forceinline__ unsigned short f2bf(float f){
  union { float f; unsigned int i; } v; v.f = f;
  unsigned int u = v.i;
  u += 0x7FFFu + ((u >> 16) & 1u);
  return (unsigned short)(u >> 16);
}
__device__ __forceinline__ unsigned int pk(float a, float b){
  return (unsigned int)f2bf(a) | ((unsigned int)f2bf(b) << 16);
}
__device__ __forceinline__ void up2(int w, float& a, float& b){
  a = bf2f((unsigned short)(w & 0xFFFF));
  b = bf2f((unsigned short)(((unsigned int)w) >> 16));
}
__device__ __forceinline__ unsigned int encf(float f){
  union { float f; unsigned int i; } v; v.f = f;
  return ((int)v.i < 0) ? ~v.i : (v.i | 0x80000000u);
}
__device__ __forceinline__ float decf(unsigned int e){
  union { unsigned int i; float f; } v;
  v.i = ((int)e < 0) ? (e ^ 0x80000000u) : ~e;
  return v.f;
}
__device__ __forceinline__ void bn_coef(const float* st, const float* gamma, const float* beta,
                                        int c, float& sc, float& sh){
  float mean = st[c] * (1.0f / N_PTS);
  float var  = st[C + c] * (1.0f / N_PTS) - mean * mean;
  float g = gamma[c] * rsqrtf(fmaxf(var, 0.f) + BN_EPS);
  sc = g; sh = beta[c] - mean * g;
}

// ---------------- weight prep: f32 -> bf16, transposed to [n][k] ----------------
// tconv gets the conv-LDS XOR swizzle pre-applied (n&15: 16 slots over 32 lanes -> 2-way, free)
__global__ void k_prep_weights(const float* __restrict__ lw, const float* __restrict__ w,
                               const float* __restrict__ proj, const float* __restrict__ conv,
                               const float* __restrict__ fuse,
                               unsigned short* __restrict__ tlw, unsigned short* __restrict__ tw,
                               unsigned short* __restrict__ tproj, unsigned short* __restrict__ tconv,
                               unsigned short* __restrict__ tfuse)
{
  int z = blockIdx.x, tid = threadIdx.x;
  if (z < 64){
    const float* src; unsigned short* dst; bool swz = false;
    if (z < 3){ src = lw + z*16384; dst = tlw + z*16384; }
    else if (z < 6){ src = w + (z-3)*16384; dst = tw + (z-3)*16384; }
    else if (z < 10){ src = proj + (z-6)*16384; dst = tproj + (z-6)*16384; }
    else { src = conv + (z-10)*16384; dst = tconv + (z-10)*16384; swz = true; }
    for (int i = tid; i < 16384; i += 256){
      int n = i >> 7, k = i & 127;
      int pos = swz ? (n*128 + (((k >> 3) ^ (n & 15)) << 3) + (k & 7)) : i;
      dst[pos] = f2bf(src[k*128 + n]);
    }
  } else {
    for (int i = tid; i < 32768; i += 256){
      int n = i >> 8, k = i & 255;
      tfuse[i] = f2bf(fuse[k*128 + n]);
    }
  }
}

// ---------------- mask dtype detection (int32 vs packed bytes) ----------------
__global__ void k_detect_mask(const unsigned int* __restrict__ mw, int* __restrict__ mmode)
{
  __shared__ int flag;
  if (threadIdx.x == 0) flag = 0;
  __syncthreads();
  for (int i = threadIdx.x; i < 4096; i += 256)
    if (mw[i] > 1u) flag = 1;
  __syncthreads();
  if (threadIdx.x == 0) *mmode = flag;
}

// ---------------- cluster histogram / prefix / scatter ----------------
__global__ void k_hist(const int* __restrict__ c0, const int* __restrict__ c1,
                       const int* __restrict__ c2, int* __restrict__ hist)
{
  int idx = blockIdx.x*blockDim.x + threadIdx.x;
  int stride = gridDim.x*blockDim.x;
  for (; idx < 3*N_PTS; idx += stride){
    int j = idx / N_PTS, r = idx - j*N_PTS;
    const int* cp = (j==0)?c0:((j==1)?c1:c2);
    atomicAdd(&hist[j*NCLU + cp[r]], 1);
  }
}

__global__ void k_prefix(const int* __restrict__ hist, int* __restrict__ starts,
                         int* __restrict__ cursor)
{
  int j = blockIdx.x, tid = threadIdx.x;
  __shared__ int buf[NCLU];
  __shared__ int csum[256];
  for (int i = tid; i < NCLU; i += 256) buf[i] = hist[j*NCLU + i];
  __syncthreads();
  int s = 0;
  #pragma unroll
  for (int k = 0; k < 8; k++) s += buf[tid*8 + k];
  csum[tid] = s;
  __syncthreads();
  if (tid == 0){
    int run = 0;
    for (int i = 0; i < 256; i++){ int t = csum[i]; csum[i] = run; run += t; }
  }
  __syncthreads();
  int acc = csum[tid];
  #pragma unroll
  for (int k = 0; k < 8; k++){
    int i = tid*8 + k;
    starts[j*(NCLU+1) + i] = acc;
    cursor[j*NCLU + i] = acc;
    acc += buf[i];
  }
  if (tid == 255) starts[j*(NCLU+1) + NCLU] = acc;
}

__global__ void k_scatter(const int* __restrict__ c0, const int* __restrict__ c1,
                          const int* __restrict__ c2, int* __restrict__ cursor,
                          int* __restrict__ perm)
{
  int idx = blockIdx.x*blockDim.x + threadIdx.x;
  int stride = gridDim.x*blockDim.x;
  for (; idx < 3*N_PTS; idx += stride){
    int j = idx / N_PTS, r = idx - j*N_PTS;
    const int* cp = (j==0)?c0:((j==1)?c1:c2);
    int cl = cp[r];
    int slot = atomicAdd(&cursor[j*NCLU + cl], 1);
    perm[j*N_PTS + slot] = r;
  }
}

// ---------------- segment reduction V0: S1 = per-cluster sum of relu(bn(x)) ----------------
template<int V>
__global__ void k_seg(const unsigned short* __restrict__ X,
                      const int* __restrict__ perm, const int* __restrict__ starts,
                      const float* __restrict__ st, const float* __restrict__ gamma,
                      const float* __restrict__ beta, float* __restrict__ S)
{
  __shared__ float red[16*128];
  const int cl = blockIdx.x;
  const int p0 = starts[cl], p1 = starts[cl+1];
  const int g = threadIdx.x >> 4, s = threadIdx.x & 15;
  const int c0 = s * 8;
  float sc[8], sh[8];
  #pragma unroll
  for (int j = 0; j < 8; j++) bn_coef(st, gamma, beta, c0 + j, sc[j], sh[j]);
  float acc[8];
  #pragma unroll
  for (int j = 0; j < 8; j++) acc[j] = 0.f;
  for (int p = p0 + g; p < p1; p += 16){
    int row = perm[p];
    int4 v = *(const int4*)(X + (size_t)row*C + c0);
    float f[8];
    up2(v.x, f[0], f[1]); up2(v.y, f[2], f[3]); up2(v.z, f[4], f[5]); up2(v.w, f[6], f[7]);
    #pragma unroll
    for (int j = 0; j < 8; j++) acc[j] += fmaxf(f[j]*sc[j] + sh[j], 0.f);
  }
  #pragma unroll
  for (int j = 0; j < 8; j++) red[g*128 + c0 + j] = acc[j];
  __syncthreads();
  if (threadIdx.x < 128){
    float t = 0.f;
    #pragma unroll
    for (int gg = 0; gg < 16; gg++) t += red[gg*128 + threadIdx.x];
    S[cl*C + threadIdx.x] = t;
  }
}

// ---------------- single-pass seg12 ----------------
__global__ void k_seg12(const unsigned short* __restrict__ XP, const unsigned short* __restrict__ X2,
                        const int* __restrict__ perm, const int* __restrict__ starts,
                        const float* __restrict__ st, const float* __restrict__ gamma,
                        const float* __restrict__ beta, const unsigned int* __restrict__ genc,
                        float* __restrict__ S3)
{
  __shared__ float red[16*128];
  const int cl = blockIdx.x;
  const int p0 = starts[cl], p1 = starts[cl+1];
  const int g = threadIdx.x >> 4, s = threadIdx.x & 15;
  const int c0 = s * 8;
  const float gm = decf(*genc);
  float sc[8], sh[8];
  #pragma unroll
  for (int j = 0; j < 8; j++) bn_coef(st, gamma, beta, c0 + j, sc[j], sh[j]);

  float accN[8], accD[8];
  #pragma unroll
  for (int j = 0; j < 8; j++){ accN[j] = 0.f; accD[j] = 0.f; }
  for (int p = p0 + g; p < p1; p += 16){
    int row = perm[p];
    int4 v  = *(const int4*)(XP + (size_t)row*C + c0);
    int4 v2 = *(const int4*)(X2 + (size_t)row*C + c0);
    float f[8], x2[8];
    up2(v.x, f[0], f[1]); up2(v.y, f[2], f[3]); up2(v.z, f[4], f[5]); up2(v.w, f[6], f[7]);
    up2(v2.x, x2[0], x2[1]); up2(v2.y, x2[2], x2[3]); up2(v2.z, x2[4], x2[5]); up2(v2.w, x2[6], x2[7]);
    #pragma unroll
    for (int j = 0; j < 8; j++){
      float e = __expf(x2[j] - gm);
      accD[j] += e;
      accN[j] += fmaxf(f[j]*sc[j] + sh[j], 0.f) * e;
    }
  }
  #pragma unroll
  for (int j = 0; j < 8; j++) red[g*128 + c0 + j] = accN[j];
  __syncthreads();
  float tN = 0.f;
  if (threadIdx.x < 128){
    #pragma unroll
    for (int gg = 0; gg < 16; gg++) tN += red[gg*128 + threadIdx.x];
  }
  __syncthreads();
  #pragma unroll
  for (int j = 0; j < 8; j++) red[g*128 + c0 + j] = accD[j];
  __syncthreads();
  if (threadIdx.x < 128){
    float tD = 0.f;
    #pragma unroll
    for (int gg = 0; gg < 16; gg++) tD += red[gg*128 + threadIdx.x];
    S3[cl*C + threadIdx.x] = tN / (tD + 1e-6f);
  }
}

// ---------------- adaptive softmax weights (+ bf16 feat side-write) ----------------
__global__ void k_adp(const float* __restrict__ feat, const float* __restrict__ aW,
                      float* __restrict__ adp, unsigned short* __restrict__ featb)
{
  __shared__ float wsh[384];
  int tid = threadIdx.x;
  for (int i = tid; i < 384; i += 256) wsh[i] = aW[i];
  __syncthreads();
  int gidx = blockIdx.x*256 + tid;
  int stride = gridDim.x*256;
  for (int t4 = gidx; t4 < N_PTS*4; t4 += stride){
    int row = t4 >> 2, part = t4 & 3;
    float e0=0.f, e1=0.f, e2=0.f;
    const float* fr = feat + (size_t)row*C + part*32;
    unsigned int pb[16];
    #pragma unroll
    for (int c = 0; c < 32; c += 4){
      float4 v = *(const float4*)(fr + c);
      int cc = part*32 + c;
      e0 += v.x*wsh[cc*3+0] + v.y*wsh[(cc+1)*3+0] + v.z*wsh[(cc+2)*3+0] + v.w*wsh[(cc+3)*3+0];
      e1 += v.x*wsh[cc*3+1] + v.y*wsh[(cc+1)*3+1] + v.z*wsh[(cc+2)*3+1] + v.w*wsh[(cc+3)*3+1];
      e2 += v.x*wsh[cc*3+2] + v.y*wsh[(cc+1)*3+2] + v.z*wsh[(cc+2)*3+2] + v.w*wsh[(cc+3)*3+2];
      pb[(c>>1)]   = pk(v.x, v.y);
      pb[(c>>1)+1] = pk(v.z, v.w);
    }
    if (featb){
      int4* dst = (int4*)(featb + (size_t)row*C + part*32);
      dst[0] = make_int4(pb[0], pb[1], pb[2], pb[3]);
      dst[1] = make_int4(pb[4], pb[5], pb[6], pb[7]);
      dst[2] = make_int4(pb[8], pb[9], pb[10], pb[11]);
      dst[3] = make_int4(pb[12], pb[13], pb[14], pb[15]);
    }
    e0 += __shfl_xor(e0, 1); e0 += __shfl_xor(e0, 2);
    e1 += __shfl_xor(e1, 1); e1 += __shfl_xor(e1, 2);
    e2 += __shfl_xor(e2, 1); e2 += __shfl_xor(e2, 2);
    if (part == 0){
      float m = fmaxf(e0, fmaxf(e1, e2));
      float p0 = __expf(e0-m), p1 = __expf(e1-m), p2 = __expf(e2-m);
      float inv = 1.f/(p0+p1+p2);
      adp[row*3+0] = p0*inv; adp[row*3+1] = p1*inv; adp[row*3+2] = p2*inv;
    }
  }
}

// shared stats epilogue for 4-wave GEMM blocks (sred must hold 1024 floats)
__device__ __forceinline__ void gemm_stats_epi(float* csum, float* csq, float* sred,
                                               int wave, int l4, int l16, int tid,
                                               float* __restrict__ stats)
{
  #pragma unroll
  for (int t = 0; t < 8; t++){
    csum[t] += __shfl_xor(csum[t], 16); csum[t] += __shfl_xor(csum[t], 32);
    csq[t]  += __shfl_xor(csq[t], 16);  csq[t]  += __shfl_xor(csq[t], 32);
  }
  if (l4 == 0){
    #pragma unroll
    for (int t = 0; t < 8; t++){
      sred[wave*128 + t*16 + l16] = csum[t];
      sred[512 + wave*128 + t*16 + l16] = csq[t];
    }
  }
  __syncthreads();
  if (tid < 128){
    float s = 0.f, q = 0.f;
    #pragma unroll
    for (int w2 = 0; w2 < 4; w2++){ s += sred[w2*128 + tid]; q += sred[512 + w2*128 + tid]; }
    atomicAdd(&stats[tid], s);
    atomicAdd(&stats[C + tid], q);
  }
}

// A staging helper: 64 rows x 128 k into As (bf16)
template<typename AT>
__device__ __forceinline__ void stage_A(const AT* __restrict__ A, unsigned short* As,
                                        int row0, int r, int s)
{
  #pragma unroll
  for (int p = 0; p < 4; p++){
    int rr = r + p * 16;
    if constexpr (sizeof(AT) == 2){
      *(int4*)(As + rr * KP + s * 8) =
        *(const int4*)((const unsigned short*)A + (size_t)(row0 + rr) * C + s * 8);
    } else {
      const float4* ap = (const float4*)((const float*)A + (size_t)(row0 + rr) * C + s * 8);
      float4 x = ap[0], y = ap[1];
      *(int4*)(As + rr * KP + s * 8) =
        make_int4(pk(x.x,x.y), pk(x.z,x.w), pk(y.x,y.y), pk(y.z,y.w));
    }
  }
}

// ---------------- GEMM: out[N,128] = A @ Bt, + fused column stats ----------------
template<typename AT>
__global__ __launch_bounds__(256, 3)
void k_gemm_plain(const AT* __restrict__ A, const unsigned short* __restrict__ Bt,
                  unsigned short* __restrict__ Out, float* __restrict__ stats)
{
  __shared__ unsigned short As[64 * KP];
  __shared__ unsigned short Bs[128 * KP];
  const int tid = threadIdx.x;
  const int row0 = blockIdx.x * 64;
  const int r = tid >> 4, s = tid & 15;
  stage_A<AT>(A, As, row0, r, s);
  #pragma unroll
  for (int p = 0; p < 8; p++){
    int nn = r + p * 16;
    *(int4*)(Bs + nn * KP + s * 8) = *(const int4*)(Bt + nn * C + s * 8);
  }
  __syncthreads();
  const int lane = tid & 63, wave = tid >> 6;
  const int l16 = lane & 15, l4 = lane >> 4, m0 = wave * 16;
  f32x4 acc[8];
  #pragma unroll
  for (int t = 0; t < 8; t++) acc[t] = (f32x4){0.f,0.f,0.f,0.f};
  #pragma unroll
  for (int kk = 0; kk < 4; kk++){
    s16x8 a = *(const s16x8*)(As + (m0 + l16) * KP + kk * 32 + l4 * 8);
    #pragma unroll
    for (int t = 0; t < 8; t++){
      s16x8 b = *(const s16x8*)(Bs + (t * 16 + l16) * KP + kk * 32 + l4 * 8);
      acc[t] = __builtin_amdgcn_mfma_f32_16x16x32_bf16(a, b, acc[t], 0, 0, 0);
    }
  }
  float csum[8], csq[8];
  #pragma unroll
  for (int t = 0; t < 8; t++){
    float ss = 0.f, qq = 0.f;
    #pragma unroll
    for (int q = 0; q < 4; q++){
      float v = acc[t][q];
      int grow = row0 + m0 + l4 * 4 + q;
      Out[(size_t)grow * C + t * 16 + l16] = f2bf(v);
      ss += v; qq += v*v;
    }
    csum[t] = ss; csq[t] = qq;
  }
  __syncthreads();
  gemm_stats_epi(csum, csq, (float*)As, wave, l4, l16, tid, stats);
}

// ---------------- dual GEMM: two weight matrices, A staged once ----------------
template<typename AT>
__global__ __launch_bounds__(256, 3)
void k_gemm_dual(const AT* __restrict__ A,
                 const unsigned short* __restrict__ Bt0, const unsigned short* __restrict__ Bt1,
                 unsigned short* __restrict__ Out0, unsigned short* __restrict__ Out1,
                 float* __restrict__ stats0, float* __restrict__ stats1)
{
  __shared__ unsigned short As[64 * KP];
  __shared__ unsigned short Bs[128 * KP];
  const int tid = threadIdx.x;
  const int row0 = blockIdx.x * 64;
  const int r = tid >> 4, s = tid & 15;
  const int lane = tid & 63, wave = tid >> 6;
  const int l16 = lane & 15, l4 = lane >> 4, m0 = wave * 16;

  stage_A<AT>(A, As, row0, r, s);
  #pragma unroll
  for (int p = 0; p < 8; p++){
    int nn = r + p * 16;
    *(int4*)(Bs + nn * KP + s * 8) = *(const int4*)(Bt0 + nn * C + s * 8);
  }
  __syncthreads();

  f32x4 acc[8];
  float csum0[8], csq0[8], csum1[8], csq1[8];

  #pragma unroll
  for (int t = 0; t < 8; t++) acc[t] = (f32x4){0.f,0.f,0.f,0.f};
  #pragma unroll
  for (int kk = 0; kk < 4; kk++){
    s16x8 a = *(const s16x8*)(As + (m0 + l16) * KP + kk * 32 + l4 * 8);
    #pragma unroll
    for (int t = 0; t < 8; t++){
      s16x8 b = *(const s16x8*)(Bs + (t * 16 + l16) * KP + kk * 32 + l4 * 8);
      acc[t] = __builtin_amdgcn_mfma_f32_16x16x32_bf16(a, b, acc[t], 0, 0, 0);
    }
  }
  #pragma unroll
  for (int t = 0; t < 8; t++){
    float ss = 0.f, qq = 0.f;
    #pragma unroll
    for (int q = 0; q < 4; q++){
      float v = acc[t][q];
      int grow = row0 + m0 + l4 * 4 + q;
      Out0[(size_t)grow * C + t * 16 + l16] = f2bf(v);
      ss += v; qq += v*v;
    }
    csum0[t] = ss; csq0[t] = qq;
  }
  __syncthreads();
  #pragma unroll
  for (int p = 0; p < 8; p++){
    int nn = r + p * 16;
    *(int4*)(Bs + nn * KP + s * 8) = *(const int4*)(Bt1 + nn * C + s * 8);
  }
  __syncthreads();

  #pragma unroll
  for (int t = 0; t < 8; t++) acc[t] = (f32x4){0.f,0.f,0.f,0.f};
  #pragma unroll
  for (int kk = 0; kk < 4; kk++){
    s16x8 a = *(const s16x8*)(As + (m0 + l16) * KP + kk * 32 + l4 * 8);
    #pragma unroll
    for (int t = 0; t < 8; t++){
      s16x8 b = *(const s16x8*)(Bs + (t * 16 + l16) * KP + kk * 32 + l4 * 8);
      acc[t] = __builtin_amdgcn_mfma_f32_16x16x32_bf16(a, b, acc[t], 0, 0, 0);
    }
  }
  #pragma unroll
  for (int t = 0; t < 8; t++){
    float ss = 0.f, qq = 0.f;
    #pragma unroll
    for (int q = 0; q < 4; q++){
      float v = acc[t][q];
      int grow = row0 + m0 + l4 * 4 + q;
      Out1[(size_t)grow * C + t * 16 + l16] = f2bf(v);
      ss += v; qq += v*v;
    }
    csum1[t] = ss; csq1[t] = qq;
  }
  __syncthreads();
  gemm_stats_epi(csum0, csq0, (float*)As, wave, l4, l16, tid, stats0);
  __syncthreads();
  gemm_stats_epi(csum1, csq1, (float*)As, wave, l4, l16, tid, stats1);
}

// ---------------- GEMM: (relu(bn(x)) - clustermean) @ w_W + global max ----------------
__global__ __launch_bounds__(256, 3)
void k_gemm_center(const unsigned short* __restrict__ PW, const unsigned short* __restrict__ Bt,
                   const int* __restrict__ cla, const float* __restrict__ S1,
                   const int* __restrict__ cnt, const float* __restrict__ st,
                   const float* __restrict__ gamma, const float* __restrict__ beta,
                   unsigned short* __restrict__ Out, unsigned int* __restrict__ gmax)
{
  __shared__ unsigned short As[64 * KP];
  __shared__ unsigned short Bs[128 * KP];
  __shared__ float wred[4];
  const int tid = threadIdx.x;
  const int row0 = blockIdx.x * 64;
  const int r = tid >> 4, s = tid & 15;
  float sc[8], sh[8];
  #pragma unroll
  for (int j = 0; j < 8; j++) bn_coef(st, gamma, beta, s*8 + j, sc[j], sh[j]);
  #pragma unroll
  for (int p = 0; p < 4; p++){
    int rr = r + p * 16;
    int grow = row0 + rr;
    int cl = cla[grow];
    float inv = 1.f / fmaxf(1.f, (float)cnt[cl]);
    int4 v = *(const int4*)(PW + (size_t)grow * C + s * 8);
    const float4* mp = (const float4*)(S1 + cl * C + s * 8);
    float4 ma = mp[0], mb = mp[1];
    float f[8];
    up2(v.x, f[0], f[1]); up2(v.y, f[2], f[3]); up2(v.z, f[4], f[5]); up2(v.w, f[6], f[7]);
    float m8[8] = {ma.x,ma.y,ma.z,ma.w,mb.x,mb.y,mb.z,mb.w};
    float o[8];
    #pragma unroll
    for (int j = 0; j < 8; j++) o[j] = fmaxf(f[j]*sc[j] + sh[j], 0.f) - m8[j]*inv;
    *(int4*)(As + rr * KP + s * 8) = make_int4(pk(o[0],o[1]), pk(o[2],o[3]), pk(o[4],o[5]), pk(o[6],o[7]));
  }
  #pragma unroll
  for (int p = 0; p < 8; p++){
    int nn = r + p * 16;
    *(int4*)(Bs + nn * KP + s * 8) = *(const int4*)(Bt + nn * C + s * 8);
  }
  __syncthreads();
  const int lane = tid & 63, wave = tid >> 6;
  const int l16 = lane & 15, l4 = lane >> 4, m0 = wave * 16;
  f32x4 acc[8];
  #pragma unroll
  for (int t = 0; t < 8; t++) acc[t] = (f32x4){0.f,0.f,0.f,0.f};
  #pragma unroll
  for (int kk = 0; kk < 4; kk++){
    s16x8 a = *(const s16x8*)(As + (m0 + l16) * KP + kk * 32 + l4 * 8);
    #pragma unroll
    for (int t = 0; t < 8; t++){
      s16x8 b = *(const s16x8*)(Bs + (t * 16 + l16) * KP + kk * 32 + l4 * 8);
      acc[t] = __builtin_amdgcn_mfma_f32_16x16x32_bf16(a, b, acc[t], 0, 0, 0);
    }
  }
  float mx = -3.4e38f;
  #pragma unroll
  for (int t = 0; t < 8; t++){
    #pragma unroll
    for (int q = 0; q < 4; q++){
      int grow = row0 + m0 + l4 * 4 + q;
      unsigned short ob = f2bf(acc[t][q]);
      Out[(size_t)grow * C + t * 16 + l16] = ob;
      mx = fmaxf(mx, bf2f(ob));
    }
  }
  #pragma unroll
  for (int off = 32; off; off >>= 1) mx = fmaxf(mx, __shfl_xor(mx, off));
  if ((tid & 63) == 0) wred[tid >> 6] = mx;
  __syncthreads();
  if (tid == 0){
    float m = fmaxf(fmaxf(wred[0], wred[1]), fmaxf(wred[2], wred[3]));
    atomicMax(gmax, encf(m));
  }
}

// ---------------- fuse GEMM: [relu(bn(xp3)), fused] @ fuse_W, K=256, + stats ----------------
__global__ __launch_bounds__(256, 2)
void k_gemm_fuse(const unsigned short* __restrict__ XP3, const float* __restrict__ adp,
                 const int* __restrict__ cl0, const int* __restrict__ cl1,
                 const int* __restrict__ cl2, const float* __restrict__ S3,
                 const float* __restrict__ st, const float* __restrict__ gamma,
                 const float* __restrict__ beta, const unsigned short* __restrict__ Bt,
                 unsigned short* __restrict__ Out, float* __restrict__ stats)
{
  __shared__ unsigned short As[64 * KP2];
  __shared__ unsigned short Bs[128 * KP];
  __shared__ float scs[C], shs[C];
  const int tid = threadIdx.x;
  if (tid < C){ float a, b; bn_coef(st, gamma, beta, tid, a, b); scs[tid] = a; shs[tid] = b; }
  __syncthreads();
  const int row0 = blockIdx.x * 64;
  const int r8 = tid >> 5, s = tid & 31;
  const int r = tid >> 4, s16i = tid & 15;
  #pragma unroll
  for (int p = 0; p < 8; p++){
    int rr = r8 + p * 8;
    int grow = row0 + rr;
    if (s < 16){
      int c0 = s * 8;
      int4 v = *(const int4*)(XP3 + (size_t)grow * C + c0);
      float f0,f1,f2,f3,f4,f5,f6,f7;
      up2(v.x,f0,f1); up2(v.y,f2,f3); up2(v.z,f4,f5); up2(v.w,f6,f7);
      float o0 = fmaxf(f0*scs[c0+0]+shs[c0+0],0.f), o1 = fmaxf(f1*scs[c0+1]+shs[c0+1],0.f);
      float o2 = fmaxf(f2*scs[c0+2]+shs[c0+2],0.f), o3 = fmaxf(f3*scs[c0+3]+shs[c0+3],0.f);
      float o4 = fmaxf(f4*scs[c0+4]+shs[c0+4],0.f), o5 = fmaxf(f5*scs[c0+5]+shs[c0+5],0.f);
      float o6 = fmaxf(f6*scs[c0+6]+shs[c0+6],0.f), o7 = fmaxf(f7*scs[c0+7]+shs[c0+7],0.f);
      *(int4*)(As + rr * KP2 + c0) = make_int4(pk(o0,o1), pk(o2,o3), pk(o4,o5), pk(o6,o7));
    } else {
      int c0 = (s - 16) * 8;
      float a0 = adp[grow*3+0], a1 = adp[grow*3+1], a2 = adp[grow*3+2];
      const float* p0 = S3 + (size_t)cl0[grow] * C + c0;
      const float* p1 = S3 + (size_t)NCLU * C + (size_t)cl1[grow] * C + c0;
      const float* p2 = S3 + (size_t)2 * NCLU * C + (size_t)cl2[grow] * C + c0;
      float o[8];
      #pragma unroll
      for (int j = 0; j < 8; j++) o[j] = a0*p0[j] + a1*p1[j] + a2*p2[j];
      *(int4*)(As + rr * KP2 + 128 + c0) = make_int4(pk(o[0],o[1]), pk(o[2],o[3]), pk(o[4],o[5]), pk(o[6],o[7]));
    }
  }
  const int lane = tid & 63, wave = tid >> 6;
  const int l16 = lane & 15, l4 = lane >> 4, m0 = wave * 16;
  f32x4 acc[8];
  #pragma unroll
  for (int t = 0; t < 8; t++) acc[t] = (f32x4){0.f,0.f,0.f,0.f};
  #pragma unroll
  for (int h = 0; h < 2; h++){
    if (h) __syncthreads();
    #pragma unroll
    for (int p = 0; p < 8; p++){
      int nn = r + p * 16;
      *(int4*)(Bs + nn * KP + s16i * 8) = *(const int4*)(Bt + nn * 256 + h * 128 + s16i * 8);
    }
    __syncthreads();
    #pragma unroll
    for (int kk = 0; kk < 4; kk++){
      s16x8 a = *(const s16x8*)(As + (m0 + l16) * KP2 + h * 128 + kk * 32 + l4 * 8);
      #pragma unroll
      for (int t = 0; t < 8; t++){
        s16x8 b = *(const s16x8*)(Bs + (t * 16 + l16) * KP + kk * 32 + l4 * 8);
        acc[t] = __builtin_amdgcn_mfma_f32_16x16x32_bf16(a, b, acc[t], 0, 0, 0);
      }
    }
  }
  float csum[8], csq[8];
  #pragma unroll
  for (int t = 0; t < 8; t++){
    float ss = 0.f, qq = 0.f;
    #pragma unroll
    for (int q = 0; q < 4; q++){
      float v = acc[t][q];
      int grow = row0 + m0 + l4 * 4 + q;
      Out[(size_t)grow * C + t * 16 + l16] = f2bf(v);
      ss += v; qq += v*v;
    }
    csum[t] = ss; csq[t] = qq;
  }
  __syncthreads();
  gemm_stats_epi(csum, csq, (float*)As, wave, l4, l16, tid, stats);
}

// ---------------- submanifold conv v13: 32x32x16 MFMA, single 32KB buffer, 3 blocks/CU ----------------
__device__ __forceinline__ int ld_midx(const int* __restrict__ nbr, const void* __restrict__ maskp,
                                       int mm, int g){
  bool on = mm ? (((const unsigned char*)maskp)[g] != 0)
               : (((const int*)maskp)[g] != 0);
  int v = nbr[g];
  return on ? v : -1;
}

template<typename OT>
__global__ __launch_bounds__(256, 3)
void k_conv(const unsigned short* __restrict__ In, const unsigned short* __restrict__ Wt,
            const int* __restrict__ nbr, const void* __restrict__ maskp,
            const int* __restrict__ mmode, OT* __restrict__ Out, float* __restrict__ stats)
{
  __shared__ unsigned short Bs[128*128];      // 32 KiB single buffer, pre-swizzled source
  const int tid = threadIdx.x;
  const int lane = tid & 63, wave = tid >> 6;   // 4 waves
  const int l31 = lane & 31, half = lane >> 5;
  const int row0 = blockIdx.x * 128;            // 128 rows/block, 32 rows/wave
  const int mm = *mmode;
  const int rg = row0 + wave*32 + l31;          // this lane's row
  const s16x8 z8 = (s16x8){0,0,0,0,0,0,0,0};

  auto stage_B = [&](int k){
    const char* gsrc = (const char*)(Wt + k*16384);
    char* lbase = (char*)&Bs[0];
    #pragma unroll
    for (int p = 0; p < 8; p++){
      int chunk = p*256 + wave*64;              // wave-uniform LDS base
      __builtin_amdgcn_global_load_lds(
        (const unsigned int*)(gsrc + (size_t)(chunk + lane)*16),
        (unsigned int*)(lbase + (size_t)chunk*16), 16, 0, 0);
    }
  };

  f32x16 acc[4];
  #pragma unroll
  for (int t = 0; t < 4; t++)
    acc[t] = (f32x16){0,0,0,0,0,0,0,0,0,0,0,0,0,0,0,0};

  s16x8 A0[8], A1[8];
  auto gather = [&](s16x8* dA, int gi){
    #pragma unroll
    for (int s = 0; s < 8; s++)
      dA[s] = (gi >= 0) ? *(const s16x8*)(In + (size_t)gi*C + s*16 + half*8) : z8;
  };
  auto compute = [&](const s16x8* a){
    #pragma unroll
    for (int s = 0; s < 8; s++){
      #pragma unroll
      for (int t = 0; t < 4; t++){
        int n = t*32 + l31;
        s16x8 b = *(const s16x8*)(&Bs[n*128 + (((s*2 + half) ^ (n & 15)) << 3)]);
        acc[t] = __builtin_amdgcn_mfma_f32_32x32x16_bf16(a[s], b, acc[t], 0, 0, 0);
      }
    }
  };

  // prologue: B[0], A(k=0), idx(k=1)
  stage_B(0);
  int i0 = ld_midx(nbr, maskp, mm, rg*K27 + 0);
  gather(A0, i0);
  i0 = ld_midx(nbr, maskp, mm, rg*K27 + 1);
  __syncthreads();                              // buf(W0) ready

  #pragma unroll 1
  for (int kb = 0; kb < 13; kb++){
    const int k = kb * 2;
    // even k: buf holds W[k]
    gather(A1, i0);                             // A(k+1)
    i0 = ld_midx(nbr, maskp, mm, rg*K27 + k + 2);
    compute(A0);
    __syncthreads();                            // done reading buf
    stage_B(k + 1);
    __syncthreads();                            // buf(W[k+1]) ready
    // odd k+1
    gather(A0, i0);                             // A(k+2)
    if (kb < 12) i0 = ld_midx(nbr, maskp, mm, rg*K27 + k + 3);
    compute(A1);
    __syncthreads();                            // done reading buf
    stage_B(k + 2);
    __syncthreads();                            // buf(W[k+2]) ready
  }
  compute(A0);   // k = 26

  // epilogue: write + fused column stats
  // C/D layout (verified): col = lane&31, row = (reg&3) + 8*(reg>>2) + 4*(lane>>5)
  float csum[4], csq[4];
  #pragma unroll
  for (int t = 0; t < 4; t++){
    float ss = 0.f, qq = 0.f;
    #pragma unroll
    for (int r = 0; r < 16; r++){
      float v = acc[t][r];
      int grow = row0 + wave*32 + (r & 3) + 8*(r >> 2) + 4*half;
      if constexpr (sizeof(OT) == 2) Out[(size_t)grow * C + t*32 + l31] = f2bf(v);
      else                           Out[(size_t)grow * C + t*32 + l31] = v;
      ss += v; qq += v*v;
    }
    csum[t] = ss; csq[t] = qq;
  }
  #pragma unroll
  for (int t = 0; t < 4; t++){
    csum[t] += __shfl_xor(csum[t], 32);
    csq[t]  += __shfl_xor(csq[t], 32);
  }
  __syncthreads();
  float* sred = (float*)Bs;
  if (half == 0){
    #pragma unroll
    for (int t = 0; t < 4; t++){
      sred[wave*128 + t*32 + l31] = csum[t];
      sred[512 + wave*128 + t*32 + l31] = csq[t];
    }
  }
  __syncthreads();
  if (tid < 128){
    float s = 0.f, q = 0.f;
    #pragma unroll
    for (int w2 = 0; w2 < 4; w2++){ s += sred[w2*128 + tid]; q += sred[512 + w2*128 + tid]; }
    atomicAdd(&stats[tid], s);
    atomicAdd(&stats[C + tid], q);
  }
}

// ---------------- elementwise kernels ----------------
template<int RELU>
__global__ void k_bnapply(const unsigned short* __restrict__ X, unsigned short* __restrict__ Y,
                          const float* __restrict__ st, const float* __restrict__ gamma,
                          const float* __restrict__ beta)
{
  const int total = N_PTS * 16;
  for (int idx = blockIdx.x*blockDim.x + threadIdx.x; idx < total; idx += gridDim.x*blockDim.x){
    int c0 = (idx & 15) * 8;
    int4 v = *(const int4*)(X + (size_t)idx * 8);
    float f[8];
    up2(v.x, f[0], f[1]); up2(v.y, f[2], f[3]); up2(v.z, f[4], f[5]); up2(v.w, f[6], f[7]);
    float o[8];
    #pragma unroll
    for (int j = 0; j < 8; j++){
      float sc, sh; bn_coef(st, gamma, beta, c0 + j, sc, sh);
      float t = f[j] * sc + sh;
      if (RELU) t = fmaxf(t, 0.f);
      o[j] = t;
    }
    *(int4*)(Y + (size_t)idx * 8) = make_int4(pk(o[0],o[1]), pk(o[2],o[3]), pk(o[4],o[5]), pk(o[6],o[7]));
  }
}

__global__ void k_fres(const unsigned short* __restrict__ G, const float* __restrict__ st,
                       const float* __restrict__ gamma, const float* __restrict__ beta,
                       const float* __restrict__ feat, unsigned short* __restrict__ FB)
{
  const int total = N_PTS * 16;
  for (int idx = blockIdx.x*blockDim.x + threadIdx.x; idx < total; idx += gridDim.x*blockDim.x){
    int c0 = (idx & 15) * 8;
    int4 v = *(const int4*)(G + (size_t)idx * 8);
    float f[8];
    up2(v.x, f[0], f[1]); up2(v.y, f[2], f[3]); up2(v.z, f[4], f[5]); up2(v.w, f[6], f[7]);
    const float4* fp = (const float4*)(feat + (size_t)idx * 8);
    float4 fa = fp[0], fb4 = fp[1];
    float fe[8] = {fa.x,fa.y,fa.z,fa.w,fb4.x,fb4.y,fb4.z,fb4.w};
    float o[8];
    #pragma unroll
    for (int j = 0; j < 8; j++){
      float sc, sh; bn_coef(st, gamma, beta, c0 + j, sc, sh);
      o[j] = fmaxf(f[j]*sc + sh, 0.f) + fe[j];
    }
    *(int4*)(FB + (size_t)idx * 8) = make_int4(pk(o[0],o[1]), pk(o[2],o[3]), pk(o[4],o[5]), pk(o[6],o[7]));
  }
}

__global__ void k_final(float* __restrict__ H2, const float* __restrict__ st,
                        const float* __restrict__ gamma, const float* __restrict__ beta,
                        const unsigned short* __restrict__ FB)
{
  const int total = N_PTS * 16;
  for (int idx = blockIdx.x*blockDim.x + threadIdx.x; idx < total; idx += gridDim.x*blockDim.x){
    int c0 = (idx & 15) * 8;
    float4* hp = (float4*)(H2 + (size_t)idx * 8);
    float4 a = hp[0], b = hp[1];
    int4 vf = *(const int4*)(FB + (size_t)idx * 8);
    float fr[8];
    up2(vf.x, fr[0], fr[1]); up2(vf.y, fr[2], fr[3]); up2(vf.z, fr[4], fr[5]); up2(vf.w, fr[6], fr[7]);
    float h[8] = {a.x,a.y,a.z,a.w,b.x,b.y,b.z,b.w};
    #pragma unroll
    for (int j = 0; j < 8; j++){
      float sc, sh; bn_coef(st, gamma, beta, c0 + j, sc, sh);
      h[j] = fmaxf(h[j]*sc + sh + fr[j], 0.f);
    }
    hp[0] = make_float4(h[0],h[1],h[2],h[3]);
    hp[1] = make_float4(h[4],h[5],h[6],h[7]);
  }
}

extern "C" void kernel_launch(void* const* d_in, const int* in_sizes, int n_in,
                              void* d_out, int out_size, void* d_ws, size_t ws_size,
                              hipStream_t stream)
{
  (void)in_sizes; (void)n_in; (void)out_size;
  const float* feat   = (const float*)d_in[0];
  const int* cls[3]   = {(const int*)d_in[1], (const int*)d_in[2], (const int*)d_in[3]};
  const int* nbr      = (const int*)d_in[4];
  const void* mask    = d_in[5];
  const float* lw_W   = (const float*)d_in[6];
  const float* lw_g   = (const float*)d_in[7];
  const float* lw_b   = (const float*)d_in[8];
  const float* w_W    = (const float*)d_in[9];
  const float* proj_W = (const float*)d_in[10];
  const float* proj_g = (const float*)d_in[11];
  const float* proj_b = (const float*)d_in[12];
  const float* adW    = (const float*)d_in[13];
  const float* fuse_W = (const float*)d_in[14];
  const float* fuse_g = (const float*)d_in[15];
  const float* fuse_b = (const float*)d_in[16];
  const float* conv_W = (const float*)d_in[17];
  const float* conv_g = (const float*)d_in[18];
  const float* conv_b = (const float*)d_in[19];

  char* w = (char*)d_ws;
  float*          stats  = (float*)(w + 0);            // 10 slots x 256 f32
  unsigned int*   gmax   = (unsigned int*)(w + 10240); // 3
  int*            mmode  = (int*)(w + 10240 + 16);
  int*            hist   = (int*)(w + 10496);          // 3*2048
  int*            starts = (int*)(w + 35072);          // 3*2049
  int*            cursor = (int*)(w + 59904);          // 3*2048
  int*            perm   = (int*)(w + 84480);          // 3*N
  float*          S1     = (float*)(w + 2004480);      // 2048*128
  float*          S3     = (float*)(w + 4101632);      // 3*2048*128
  float*          adp    = (float*)(w + 7247360);      // N*3
  unsigned short* tlw    = (unsigned short*)(w + 9167360);
  unsigned short* tw     = (unsigned short*)(w + 9265664);
  unsigned short* tproj  = (unsigned short*)(w + 9363968);
  unsigned short* tfuse  = (unsigned short*)(w + 9495040);
  unsigned short* tconv  = (unsigned short*)(w + 9560576);
  unsigned short* B1     = (unsigned short*)(w + 11330048);
  unsigned short* B2     = (unsigned short*)(w + 52290048);
  unsigned short* B3     = (unsigned short*)(w + 93250048);
  // base ws usage: 134,210,048 bytes; optional featb adds 40,960,000
  const bool useb = ws_size >= (size_t)175170048;
  unsigned short* featb = useb ? (unsigned short*)(w + 134210048) : nullptr;

  hipMemsetAsync(d_ws, 0, 35072, stream); // stats + gmax + mmode + hist

  k_prep_weights<<<65, 256, 0, stream>>>(lw_W, w_W, proj_W, conv_W, fuse_W,
                                         tlw, tw, tproj, tconv, tfuse);
  k_detect_mask<<<1, 256, 0, stream>>>((const unsigned int*)mask, mmode);
  k_hist<<<1024, 256, 0, stream>>>(cls[0], cls[1], cls[2], hist);
  k_prefix<<<3, 256, 0, stream>>>(hist, starts, cursor);
  k_scatter<<<1024, 256, 0, stream>>>(cls[0], cls[1], cls[2], cursor, perm);
  k_adp<<<2500, 256, 0, stream>>>(feat, adW, adp, featb);

  if (useb) k_gemm_plain<unsigned short><<<2500, 256, 0, stream>>>(featb, tlw, B1, stats);
  else      k_gemm_plain<float><<<2500, 256, 0, stream>>>(feat, tlw, B1, stats);

  for (int i = 0; i < 3; i++){
    k_seg<0><<<2048, 256, 0, stream>>>(B1, perm + i*N_PTS, starts + i*(NCLU+1),
                                       stats + i*256, lw_g + i*C, lw_b + i*C, S1);
    k_gemm_center<<<2500, 256, 0, stream>>>(B1, tw + i*16384, cls[i], S1, hist + i*NCLU,
                                            stats + i*256, lw_g + i*C, lw_b + i*C, B3, gmax + i);
    const unsigned short* w0 = tproj + i*16384;
    const unsigned short* w1 = (i < 2) ? (tlw + (i+1)*16384) : (tproj + 3*16384);
    float* st1 = (i < 2) ? (stats + (i+1)*256) : (stats + 6*256);
    if (useb) k_gemm_dual<unsigned short><<<2500, 256, 0, stream>>>(featb, w0, w1, B2, B1,
                                                                    stats + (3+i)*256, st1);
    else      k_gemm_dual<float><<<2500, 256, 0, stream>>>(feat, w0, w1, B2, B1,
                                                           stats + (3+i)*256, st1);
    k_seg12<<<2048, 256, 0, stream>>>(B2, B3, perm + i*N_PTS, starts + i*(NCLU+1),
                                      stats + (3+i)*256, proj_g + i*C, proj_b + i*C,
                                      gmax + i, S3 + (size_t)i*NCLU*C);
  }

  k_gemm_fuse<<<2500, 256, 0, stream>>>(B1, adp, cls[0], cls[1], cls[2], S3,
                                        stats + 6*256, proj_g + 3*C, proj_b + 3*C, tfuse,
                                        B2, stats + 7*256);
  k_fres<<<2048, 256, 0, stream>>>(B2, stats + 7*256, fuse_g, fuse_b, feat, B3);

  k_conv<unsigned short><<<1250, 256, 0, stream>>>(B3, tconv, nbr, mask, mmode, B1, stats + 8*256);
  k_bnapply<1><<<2048, 256, 0, stream>>>(B1, B2, stats + 8*256, conv_g, conv_b);
  k_conv<float><<<1250, 256, 0, stream>>>(B2, tconv + 27*16384, nbr, mask, mmode,
                                          (float*)d_out, stats + 9*256);
  k_final<<<2048, 256, 0, stream>>>((float*)d_out, stats + 9*256, conv_g + C, conv_b + C, B3);
}

// Round 14
// 1245.814 us; speedup vs baseline: 1.2207x; 1.1349x over previous
//
#include <hip/hip_runtime.h>
#include <stdint.h>

#define N_PTS 160000
#define C 128
#define K27 27
#define NCLU 2048
#define BN_EPS 1e-5f
#define KP 136   // padded LDS k-stride (bf16 elems) for K=128 GEMM tiles
#define KP2 264  // for K=256 fuse tile

typedef float f32x4 __attribute__((ext_vector_type(4)));
typedef float f32x16 __attribute__((ext_vector_type(16)));
typedef short s16x8 __attribute__((ext_vector_type(8)));

__device__ __forceinline__ float bf2f(unsigned short u){
  union { unsigned int i; float f; } v; v.i = ((unsigned int)u) << 16; return v.f;
}
__device__ __forceinline__ unsigned short f2bf(float f){
  union { float f; unsigned int i; } v; v.f = f;
  unsigned int u = v.i;
  u += 0x7FFFu + ((u >> 16) & 1u);
  return (unsigned short)(u >> 16);
}
__device__ __forceinline__ unsigned int pk(float a, float b){
  return (unsigned int)f2bf(a) | ((unsigned int)f2bf(b) << 16);
}
__device__ __forceinline__ void up2(int w, float& a, float& b){
  a = bf2f((unsigned short)(w & 0xFFFF));
  b = bf2f((unsigned short)(((unsigned int)w) >> 16));
}
__device__ __forceinline__ unsigned int encf(float f){
  union { float f; unsigned int i; } v; v.f = f;
  return ((int)v.i < 0) ? ~v.i : (v.i | 0x80000000u);
}
__device__ __forceinline__ float decf(unsigned int e){
  union { unsigned int i; float f; } v;
  v.i = ((int)e < 0) ? (e ^ 0x80000000u) : ~e;
  return v.f;
}
__device__ __forceinline__ void bn_coef(const float* st, const float* gamma, const float* beta,
                                        int c, float& sc, float& sh){
  float mean = st[c] * (1.0f / N_PTS);
  float var  = st[C + c] * (1.0f / N_PTS) - mean * mean;
  float g = gamma[c] * rsqrtf(fmaxf(var, 0.f) + BN_EPS);
  sc = g; sh = beta[c] - mean * g;
}

// ---------------- weight prep: f32 -> bf16, transposed to [n][k] ----------------
// tconv gets the conv-LDS XOR swizzle pre-applied (n&15: 16 slots over 32 lanes -> 2-way, free)
__global__ void k_prep_weights(const float* __restrict__ lw, const float* __restrict__ w,
                               const float* __restrict__ proj, const float* __restrict__ conv,
                               const float* __restrict__ fuse,
                               unsigned short* __restrict__ tlw, unsigned short* __restrict__ tw,
                               unsigned short* __restrict__ tproj, unsigned short* __restrict__ tconv,
                               unsigned short* __restrict__ tfuse)
{
  int z = blockIdx.x, tid = threadIdx.x;
  if (z < 64){
    const float* src; unsigned short* dst; bool swz = false;
    if (z < 3){ src = lw + z*16384; dst = tlw + z*16384; }
    else if (z < 6){ src = w + (z-3)*16384; dst = tw + (z-3)*16384; }
    else if (z < 10){ src = proj + (z-6)*16384; dst = tproj + (z-6)*16384; }
    else { src = conv + (z-10)*16384; dst = tconv + (z-10)*16384; swz = true; }
    for (int i = tid; i < 16384; i += 256){
      int n = i >> 7, k = i & 127;
      int pos = swz ? (n*128 + (((k >> 3) ^ (n & 15)) << 3) + (k & 7)) : i;
      dst[pos] = f2bf(src[k*128 + n]);
    }
  } else {
    for (int i = tid; i < 32768; i += 256){
      int n = i >> 8, k = i & 255;
      tfuse[i] = f2bf(fuse[k*128 + n]);
    }
  }
}

// ---------------- mask dtype detection (int32 vs packed bytes) ----------------
__global__ void k_detect_mask(const unsigned int* __restrict__ mw, int* __restrict__ mmode)
{
  __shared__ int flag;
  if (threadIdx.x == 0) flag = 0;
  __syncthreads();
  for (int i = threadIdx.x; i < 4096; i += 256)
    if (mw[i] > 1u) flag = 1;
  __syncthreads();
  if (threadIdx.x == 0) *mmode = flag;
}

// ---------------- cluster histogram / prefix / scatter ----------------
__global__ void k_hist(const int* __restrict__ c0, const int* __restrict__ c1,
                       const int* __restrict__ c2, int* __restrict__ hist)
{
  int idx = blockIdx.x*blockDim.x + threadIdx.x;
  int stride = gridDim.x*blockDim.x;
  for (; idx < 3*N_PTS; idx += stride){
    int j = idx / N_PTS, r = idx - j*N_PTS;
    const int* cp = (j==0)?c0:((j==1)?c1:c2);
    atomicAdd(&hist[j*NCLU + cp[r]], 1);
  }
}

__global__ void k_prefix(const int* __restrict__ hist, int* __restrict__ starts,
                         int* __restrict__ cursor)
{
  int j = blockIdx.x, tid = threadIdx.x;
  __shared__ int buf[NCLU];
  __shared__ int csum[256];
  for (int i = tid; i < NCLU; i += 256) buf[i] = hist[j*NCLU + i];
  __syncthreads();
  int s = 0;
  #pragma unroll
  for (int k = 0; k < 8; k++) s += buf[tid*8 + k];
  csum[tid] = s;
  __syncthreads();
  if (tid == 0){
    int run = 0;
    for (int i = 0; i < 256; i++){ int t = csum[i]; csum[i] = run; run += t; }
  }
  __syncthreads();
  int acc = csum[tid];
  #pragma unroll
  for (int k = 0; k < 8; k++){
    int i = tid*8 + k;
    starts[j*(NCLU+1) + i] = acc;
    cursor[j*NCLU + i] = acc;
    acc += buf[i];
  }
  if (tid == 255) starts[j*(NCLU+1) + NCLU] = acc;
}

__global__ void k_scatter(const int* __restrict__ c0, const int* __restrict__ c1,
                          const int* __restrict__ c2, int* __restrict__ cursor,
                          int* __restrict__ perm)
{
  int idx = blockIdx.x*blockDim.x + threadIdx.x;
  int stride = gridDim.x*blockDim.x;
  for (; idx < 3*N_PTS; idx += stride){
    int j = idx / N_PTS, r = idx - j*N_PTS;
    const int* cp = (j==0)?c0:((j==1)?c1:c2);
    int cl = cp[r];
    int slot = atomicAdd(&cursor[j*NCLU + cl], 1);
    perm[j*N_PTS + slot] = r;
  }
}

// ---------------- segment reduction V0: S1 = per-cluster sum of relu(bn(x)) ----------------
template<int V>
__global__ void k_seg(const unsigned short* __restrict__ X,
                      const int* __restrict__ perm, const int* __restrict__ starts,
                      const float* __restrict__ st, const float* __restrict__ gamma,
                      const float* __restrict__ beta, float* __restrict__ S)
{
  __shared__ float red[16*128];
  const int cl = blockIdx.x;
  const int p0 = starts[cl], p1 = starts[cl+1];
  const int g = threadIdx.x >> 4, s = threadIdx.x & 15;
  const int c0 = s * 8;
  float sc[8], sh[8];
  #pragma unroll
  for (int j = 0; j < 8; j++) bn_coef(st, gamma, beta, c0 + j, sc[j], sh[j]);
  float acc[8];
  #pragma unroll
  for (int j = 0; j < 8; j++) acc[j] = 0.f;
  for (int p = p0 + g; p < p1; p += 16){
    int row = perm[p];
    int4 v = *(const int4*)(X + (size_t)row*C + c0);
    float f[8];
    up2(v.x, f[0], f[1]); up2(v.y, f[2], f[3]); up2(v.z, f[4], f[5]); up2(v.w, f[6], f[7]);
    #pragma unroll
    for (int j = 0; j < 8; j++) acc[j] += fmaxf(f[j]*sc[j] + sh[j], 0.f);
  }
  #pragma unroll
  for (int j = 0; j < 8; j++) red[g*128 + c0 + j] = acc[j];
  __syncthreads();
  if (threadIdx.x < 128){
    float t = 0.f;
    #pragma unroll
    for (int gg = 0; gg < 16; gg++) t += red[gg*128 + threadIdx.x];
    S[cl*C + threadIdx.x] = t;
  }
}

// ---------------- single-pass seg12 ----------------
__global__ void k_seg12(const unsigned short* __restrict__ XP, const unsigned short* __restrict__ X2,
                        const int* __restrict__ perm, const int* __restrict__ starts,
                        const float* __restrict__ st, const float* __restrict__ gamma,
                        const float* __restrict__ beta, const unsigned int* __restrict__ genc,
                        float* __restrict__ S3)
{
  __shared__ float red[16*128];
  const int cl = blockIdx.x;
  const int p0 = starts[cl], p1 = starts[cl+1];
  const int g = threadIdx.x >> 4, s = threadIdx.x & 15;
  const int c0 = s * 8;
  const float gm = decf(*genc);
  float sc[8], sh[8];
  #pragma unroll
  for (int j = 0; j < 8; j++) bn_coef(st, gamma, beta, c0 + j, sc[j], sh[j]);

  float accN[8], accD[8];
  #pragma unroll
  for (int j = 0; j < 8; j++){ accN[j] = 0.f; accD[j] = 0.f; }
  for (int p = p0 + g; p < p1; p += 16){
    int row = perm[p];
    int4 v  = *(const int4*)(XP + (size_t)row*C + c0);
    int4 v2 = *(const int4*)(X2 + (size_t)row*C + c0);
    float f[8], x2[8];
    up2(v.x, f[0], f[1]); up2(v.y, f[2], f[3]); up2(v.z, f[4], f[5]); up2(v.w, f[6], f[7]);
    up2(v2.x, x2[0], x2[1]); up2(v2.y, x2[2], x2[3]); up2(v2.z, x2[4], x2[5]); up2(v2.w, x2[6], x2[7]);
    #pragma unroll
    for (int j = 0; j < 8; j++){
      float e = __expf(x2[j] - gm);
      accD[j] += e;
      accN[j] += fmaxf(f[j]*sc[j] + sh[j], 0.f) * e;
    }
  }
  #pragma unroll
  for (int j = 0; j < 8; j++) red[g*128 + c0 + j] = accN[j];
  __syncthreads();
  float tN = 0.f;
  if (threadIdx.x < 128){
    #pragma unroll
    for (int gg = 0; gg < 16; gg++) tN += red[gg*128 + threadIdx.x];
  }
  __syncthreads();
  #pragma unroll
  for (int j = 0; j < 8; j++) red[g*128 + c0 + j] = accD[j];
  __syncthreads();
  if (threadIdx.x < 128){
    float tD = 0.f;
    #pragma unroll
    for (int gg = 0; gg < 16; gg++) tD += red[gg*128 + threadIdx.x];
    S3[cl*C + threadIdx.x] = tN / (tD + 1e-6f);
  }
}

// ---------------- adaptive softmax weights (+ bf16 feat side-write) ----------------
__global__ void k_adp(const float* __restrict__ feat, const float* __restrict__ aW,
                      float* __restrict__ adp, unsigned short* __restrict__ featb)
{
  __shared__ float wsh[384];
  int tid = threadIdx.x;
  for (int i = tid; i < 384; i += 256) wsh[i] = aW[i];
  __syncthreads();
  int gidx = blockIdx.x*256 + tid;
  int stride = gridDim.x*256;
  for (int t4 = gidx; t4 < N_PTS*4; t4 += stride){
    int row = t4 >> 2, part = t4 & 3;
    float e0=0.f, e1=0.f, e2=0.f;
    const float* fr = feat + (size_t)row*C + part*32;
    unsigned int pb[16];
    #pragma unroll
    for (int c = 0; c < 32; c += 4){
      float4 v = *(const float4*)(fr + c);
      int cc = part*32 + c;
      e0 += v.x*wsh[cc*3+0] + v.y*wsh[(cc+1)*3+0] + v.z*wsh[(cc+2)*3+0] + v.w*wsh[(cc+3)*3+0];
      e1 += v.x*wsh[cc*3+1] + v.y*wsh[(cc+1)*3+1] + v.z*wsh[(cc+2)*3+1] + v.w*wsh[(cc+3)*3+1];
      e2 += v.x*wsh[cc*3+2] + v.y*wsh[(cc+1)*3+2] + v.z*wsh[(cc+2)*3+2] + v.w*wsh[(cc+3)*3+2];
      pb[(c>>1)]   = pk(v.x, v.y);
      pb[(c>>1)+1] = pk(v.z, v.w);
    }
    if (featb){
      int4* dst = (int4*)(featb + (size_t)row*C + part*32);
      dst[0] = make_int4(pb[0], pb[1], pb[2], pb[3]);
      dst[1] = make_int4(pb[4], pb[5], pb[6], pb[7]);
      dst[2] = make_int4(pb[8], pb[9], pb[10], pb[11]);
      dst[3] = make_int4(pb[12], pb[13], pb[14], pb[15]);
    }
    e0 += __shfl_xor(e0, 1); e0 += __shfl_xor(e0, 2);
    e1 += __shfl_xor(e1, 1); e1 += __shfl_xor(e1, 2);
    e2 += __shfl_xor(e2, 1); e2 += __shfl_xor(e2, 2);
    if (part == 0){
      float m = fmaxf(e0, fmaxf(e1, e2));
      float p0 = __expf(e0-m), p1 = __expf(e1-m), p2 = __expf(e2-m);
      float inv = 1.f/(p0+p1+p2);
      adp[row*3+0] = p0*inv; adp[row*3+1] = p1*inv; adp[row*3+2] = p2*inv;
    }
  }
}

// shared stats epilogue for 4-wave GEMM blocks (sred must hold 1024 floats)
__device__ __forceinline__ void gemm_stats_epi(float* csum, float* csq, float* sred,
                                               int wave, int l4, int l16, int tid,
                                               float* __restrict__ stats)
{
  #pragma unroll
  for (int t = 0; t < 8; t++){
    csum[t] += __shfl_xor(csum[t], 16); csum[t] += __shfl_xor(csum[t], 32);
    csq[t]  += __shfl_xor(csq[t], 16);  csq[t]  += __shfl_xor(csq[t], 32);
  }
  if (l4 == 0){
    #pragma unroll
    for (int t = 0; t < 8; t++){
      sred[wave*128 + t*16 + l16] = csum[t];
      sred[512 + wave*128 + t*16 + l16] = csq[t];
    }
  }
  __syncthreads();
  if (tid < 128){
    float s = 0.f, q = 0.f;
    #pragma unroll
    for (int w2 = 0; w2 < 4; w2++){ s += sred[w2*128 + tid]; q += sred[512 + w2*128 + tid]; }
    atomicAdd(&stats[tid], s);
    atomicAdd(&stats[C + tid], q);
  }
}

// A staging helper: 64 rows x 128 k into As (bf16)
template<typename AT>
__device__ __forceinline__ void stage_A(const AT* __restrict__ A, unsigned short* As,
                                        int row0, int r, int s)
{
  #pragma unroll
  for (int p = 0; p < 4; p++){
    int rr = r + p * 16;
    if constexpr (sizeof(AT) == 2){
      *(int4*)(As + rr * KP + s * 8) =
        *(const int4*)((const unsigned short*)A + (size_t)(row0 + rr) * C + s * 8);
    } else {
      const float4* ap = (const float4*)((const float*)A + (size_t)(row0 + rr) * C + s * 8);
      float4 x = ap[0], y = ap[1];
      *(int4*)(As + rr * KP + s * 8) =
        make_int4(pk(x.x,x.y), pk(x.z,x.w), pk(y.x,y.y), pk(y.z,y.w));
    }
  }
}

// ---------------- GEMM: out[N,128] = A @ Bt, + fused column stats ----------------
template<typename AT>
__global__ __launch_bounds__(256, 3)
void k_gemm_plain(const AT* __restrict__ A, const unsigned short* __restrict__ Bt,
                  unsigned short* __restrict__ Out, float* __restrict__ stats)
{
  __shared__ unsigned short As[64 * KP];
  __shared__ unsigned short Bs[128 * KP];
  const int tid = threadIdx.x;
  const int row0 = blockIdx.x * 64;
  const int r = tid >> 4, s = tid & 15;
  stage_A<AT>(A, As, row0, r, s);
  #pragma unroll
  for (int p = 0; p < 8; p++){
    int nn = r + p * 16;
    *(int4*)(Bs + nn * KP + s * 8) = *(const int4*)(Bt + nn * C + s * 8);
  }
  __syncthreads();
  const int lane = tid & 63, wave = tid >> 6;
  const int l16 = lane & 15, l4 = lane >> 4, m0 = wave * 16;
  f32x4 acc[8];
  #pragma unroll
  for (int t = 0; t < 8; t++) acc[t] = (f32x4){0.f,0.f,0.f,0.f};
  #pragma unroll
  for (int kk = 0; kk < 4; kk++){
    s16x8 a = *(const s16x8*)(As + (m0 + l16) * KP + kk * 32 + l4 * 8);
    #pragma unroll
    for (int t = 0; t < 8; t++){
      s16x8 b = *(const s16x8*)(Bs + (t * 16 + l16) * KP + kk * 32 + l4 * 8);
      acc[t] = __builtin_amdgcn_mfma_f32_16x16x32_bf16(a, b, acc[t], 0, 0, 0);
    }
  }
  float csum[8], csq[8];
  #pragma unroll
  for (int t = 0; t < 8; t++){
    float ss = 0.f, qq = 0.f;
    #pragma unroll
    for (int q = 0; q < 4; q++){
      float v = acc[t][q];
      int grow = row0 + m0 + l4 * 4 + q;
      Out[(size_t)grow * C + t * 16 + l16] = f2bf(v);
      ss += v; qq += v*v;
    }
    csum[t] = ss; csq[t] = qq;
  }
  __syncthreads();
  gemm_stats_epi(csum, csq, (float*)As, wave, l4, l16, tid, stats);
}

// ---------------- dual GEMM: two weight matrices, A staged once ----------------
template<typename AT>
__global__ __launch_bounds__(256, 3)
void k_gemm_dual(const AT* __restrict__ A,
                 const unsigned short* __restrict__ Bt0, const unsigned short* __restrict__ Bt1,
                 unsigned short* __restrict__ Out0, unsigned short* __restrict__ Out1,
                 float* __restrict__ stats0, float* __restrict__ stats1)
{
  __shared__ unsigned short As[64 * KP];
  __shared__ unsigned short Bs[128 * KP];
  const int tid = threadIdx.x;
  const int row0 = blockIdx.x * 64;
  const int r = tid >> 4, s = tid & 15;
  const int lane = tid & 63, wave = tid >> 6;
  const int l16 = lane & 15, l4 = lane >> 4, m0 = wave * 16;

  stage_A<AT>(A, As, row0, r, s);
  #pragma unroll
  for (int p = 0; p < 8; p++){
    int nn = r + p * 16;
    *(int4*)(Bs + nn * KP + s * 8) = *(const int4*)(Bt0 + nn * C + s * 8);
  }
  __syncthreads();

  f32x4 acc[8];
  float csum0[8], csq0[8], csum1[8], csq1[8];

  #pragma unroll
  for (int t = 0; t < 8; t++) acc[t] = (f32x4){0.f,0.f,0.f,0.f};
  #pragma unroll
  for (int kk = 0; kk < 4; kk++){
    s16x8 a = *(const s16x8*)(As + (m0 + l16) * KP + kk * 32 + l4 * 8);
    #pragma unroll
    for (int t = 0; t < 8; t++){
      s16x8 b = *(const s16x8*)(Bs + (t * 16 + l16) * KP + kk * 32 + l4 * 8);
      acc[t] = __builtin_amdgcn_mfma_f32_16x16x32_bf16(a, b, acc[t], 0, 0, 0);
    }
  }
  #pragma unroll
  for (int t = 0; t < 8; t++){
    float ss = 0.f, qq = 0.f;
    #pragma unroll
    for (int q = 0; q < 4; q++){
      float v = acc[t][q];
      int grow = row0 + m0 + l4 * 4 + q;
      Out0[(size_t)grow * C + t * 16 + l16] = f2bf(v);
      ss += v; qq += v*v;
    }
    csum0[t] = ss; csq0[t] = qq;
  }
  __syncthreads();
  #pragma unroll
  for (int p = 0; p < 8; p++){
    int nn = r + p * 16;
    *(int4*)(Bs + nn * KP + s * 8) = *(const int4*)(Bt1 + nn * C + s * 8);
  }
  __syncthreads();

  #pragma unroll
  for (int t = 0; t < 8; t++) acc[t] = (f32x4){0.f,0.f,0.f,0.f};
  #pragma unroll
  for (int kk = 0; kk < 4; kk++){
    s16x8 a = *(const s16x8*)(As + (m0 + l16) * KP + kk * 32 + l4 * 8);
    #pragma unroll
    for (int t = 0; t < 8; t++){
      s16x8 b = *(const s16x8*)(Bs + (t * 16 + l16) * KP + kk * 32 + l4 * 8);
      acc[t] = __builtin_amdgcn_mfma_f32_16x16x32_bf16(a, b, acc[t], 0, 0, 0);
    }
  }
  #pragma unroll
  for (int t = 0; t < 8; t++){
    float ss = 0.f, qq = 0.f;
    #pragma unroll
    for (int q = 0; q < 4; q++){
      float v = acc[t][q];
      int grow = row0 + m0 + l4 * 4 + q;
      Out1[(size_t)grow * C + t * 16 + l16] = f2bf(v);
      ss += v; qq += v*v;
    }
    csum1[t] = ss; csq1[t] = qq;
  }
  __syncthreads();
  gemm_stats_epi(csum0, csq0, (float*)As, wave, l4, l16, tid, stats0);
  __syncthreads();
  gemm_stats_epi(csum1, csq1, (float*)As, wave, l4, l16, tid, stats1);
}

// ---------------- GEMM: (relu(bn(x)) - clustermean) @ w_W + global max ----------------
__global__ __launch_bounds__(256, 3)
void k_gemm_center(const unsigned short* __restrict__ PW, const unsigned short* __restrict__ Bt,
                   const int* __restrict__ cla, const float* __restrict__ S1,
                   const int* __restrict__ cnt, const float* __restrict__ st,
                   const float* __restrict__ gamma, const float* __restrict__ beta,
                   unsigned short* __restrict__ Out, unsigned int* __restrict__ gmax)
{
  __shared__ unsigned short As[64 * KP];
  __shared__ unsigned short Bs[128 * KP];
  __shared__ float wred[4];
  const int tid = threadIdx.x;
  const int row0 = blockIdx.x * 64;
  const int r = tid >> 4, s = tid & 15;
  float sc[8], sh[8];
  #pragma unroll
  for (int j = 0; j < 8; j++) bn_coef(st, gamma, beta, s*8 + j, sc[j], sh[j]);
  #pragma unroll
  for (int p = 0; p < 4; p++){
    int rr = r + p * 16;
    int grow = row0 + rr;
    int cl = cla[grow];
    float inv = 1.f / fmaxf(1.f, (float)cnt[cl]);
    int4 v = *(const int4*)(PW + (size_t)grow * C + s * 8);
    const float4* mp = (const float4*)(S1 + cl * C + s * 8);
    float4 ma = mp[0], mb = mp[1];
    float f[8];
    up2(v.x, f[0], f[1]); up2(v.y, f[2], f[3]); up2(v.z, f[4], f[5]); up2(v.w, f[6], f[7]);
    float m8[8] = {ma.x,ma.y,ma.z,ma.w,mb.x,mb.y,mb.z,mb.w};
    float o[8];
    #pragma unroll
    for (int j = 0; j < 8; j++) o[j] = fmaxf(f[j]*sc[j] + sh[j], 0.f) - m8[j]*inv;
    *(int4*)(As + rr * KP + s * 8) = make_int4(pk(o[0],o[1]), pk(o[2],o[3]), pk(o[4],o[5]), pk(o[6],o[7]));
  }
  #pragma unroll
  for (int p = 0; p < 8; p++){
    int nn = r + p * 16;
    *(int4*)(Bs + nn * KP + s * 8) = *(const int4*)(Bt + nn * C + s * 8);
  }
  __syncthreads();
  const int lane = tid & 63, wave = tid >> 6;
  const int l16 = lane & 15, l4 = lane >> 4, m0 = wave * 16;
  f32x4 acc[8];
  #pragma unroll
  for (int t = 0; t < 8; t++) acc[t] = (f32x4){0.f,0.f,0.f,0.f};
  #pragma unroll
  for (int kk = 0; kk < 4; kk++){
    s16x8 a = *(const s16x8*)(As + (m0 + l16) * KP + kk * 32 + l4 * 8);
    #pragma unroll
    for (int t = 0; t < 8; t++){
      s16x8 b = *(const s16x8*)(Bs + (t * 16 + l16) * KP + kk * 32 + l4 * 8);
      acc[t] = __builtin_amdgcn_mfma_f32_16x16x32_bf16(a, b, acc[t], 0, 0, 0);
    }
  }
  float mx = -3.4e38f;
  #pragma unroll
  for (int t = 0; t < 8; t++){
    #pragma unroll
    for (int q = 0; q < 4; q++){
      int grow = row0 + m0 + l4 * 4 + q;
      unsigned short ob = f2bf(acc[t][q]);
      Out[(size_t)grow * C + t * 16 + l16] = ob;
      mx = fmaxf(mx, bf2f(ob));
    }
  }
  #pragma unroll
  for (int off = 32; off; off >>= 1) mx = fmaxf(mx, __shfl_xor(mx, off));
  if ((tid & 63) == 0) wred[tid >> 6] = mx;
  __syncthreads();
  if (tid == 0){
    float m = fmaxf(fmaxf(wred[0], wred[1]), fmaxf(wred[2], wred[3]));
    atomicMax(gmax, encf(m));
  }
}

// ---------------- fuse GEMM: [relu(bn(xp3)), fused] @ fuse_W, K=256, + stats ----------------
__global__ __launch_bounds__(256, 2)
void k_gemm_fuse(const unsigned short* __restrict__ XP3, const float* __restrict__ adp,
                 const int* __restrict__ cl0, const int* __restrict__ cl1,
                 const int* __restrict__ cl2, const float* __restrict__ S3,
                 const float* __restrict__ st, const float* __restrict__ gamma,
                 const float* __restrict__ beta, const unsigned short* __restrict__ Bt,
                 unsigned short* __restrict__ Out, float* __restrict__ stats)
{
  __shared__ unsigned short As[64 * KP2];
  __shared__ unsigned short Bs[128 * KP];
  __shared__ float scs[C], shs[C];
  const int tid = threadIdx.x;
  if (tid < C){ float a, b; bn_coef(st, gamma, beta, tid, a, b); scs[tid] = a; shs[tid] = b; }
  __syncthreads();
  const int row0 = blockIdx.x * 64;
  const int r8 = tid >> 5, s = tid & 31;
  const int r = tid >> 4, s16i = tid & 15;
  #pragma unroll
  for (int p = 0; p < 8; p++){
    int rr = r8 + p * 8;
    int grow = row0 + rr;
    if (s < 16){
      int c0 = s * 8;
      int4 v = *(const int4*)(XP3 + (size_t)grow * C + c0);
      float f0,f1,f2,f3,f4,f5,f6,f7;
      up2(v.x,f0,f1); up2(v.y,f2,f3); up2(v.z,f4,f5); up2(v.w,f6,f7);
      float o0 = fmaxf(f0*scs[c0+0]+shs[c0+0],0.f), o1 = fmaxf(f1*scs[c0+1]+shs[c0+1],0.f);
      float o2 = fmaxf(f2*scs[c0+2]+shs[c0+2],0.f), o3 = fmaxf(f3*scs[c0+3]+shs[c0+3],0.f);
      float o4 = fmaxf(f4*scs[c0+4]+shs[c0+4],0.f), o5 = fmaxf(f5*scs[c0+5]+shs[c0+5],0.f);
      float o6 = fmaxf(f6*scs[c0+6]+shs[c0+6],0.f), o7 = fmaxf(f7*scs[c0+7]+shs[c0+7],0.f);
      *(int4*)(As + rr * KP2 + c0) = make_int4(pk(o0,o1), pk(o2,o3), pk(o4,o5), pk(o6,o7));
    } else {
      int c0 = (s - 16) * 8;
      float a0 = adp[grow*3+0], a1 = adp[grow*3+1], a2 = adp[grow*3+2];
      const float* p0 = S3 + (size_t)cl0[grow] * C + c0;
      const float* p1 = S3 + (size_t)NCLU * C + (size_t)cl1[grow] * C + c0;
      const float* p2 = S3 + (size_t)2 * NCLU * C + (size_t)cl2[grow] * C + c0;
      float o[8];
      #pragma unroll
      for (int j = 0; j < 8; j++) o[j] = a0*p0[j] + a1*p1[j] + a2*p2[j];
      *(int4*)(As + rr * KP2 + 128 + c0) = make_int4(pk(o[0],o[1]), pk(o[2],o[3]), pk(o[4],o[5]), pk(o[6],o[7]));
    }
  }
  const int lane = tid & 63, wave = tid >> 6;
  const int l16 = lane & 15, l4 = lane >> 4, m0 = wave * 16;
  f32x4 acc[8];
  #pragma unroll
  for (int t = 0; t < 8; t++) acc[t] = (f32x4){0.f,0.f,0.f,0.f};
  #pragma unroll
  for (int h = 0; h < 2; h++){
    if (h) __syncthreads();
    #pragma unroll
    for (int p = 0; p < 8; p++){
      int nn = r + p * 16;
      *(int4*)(Bs + nn * KP + s16i * 8) = *(const int4*)(Bt + nn * 256 + h * 128 + s16i * 8);
    }
    __syncthreads();
    #pragma unroll
    for (int kk = 0; kk < 4; kk++){
      s16x8 a = *(const s16x8*)(As + (m0 + l16) * KP2 + h * 128 + kk * 32 + l4 * 8);
      #pragma unroll
      for (int t = 0; t < 8; t++){
        s16x8 b = *(const s16x8*)(Bs + (t * 16 + l16) * KP + kk * 32 + l4 * 8);
        acc[t] = __builtin_amdgcn_mfma_f32_16x16x32_bf16(a, b, acc[t], 0, 0, 0);
      }
    }
  }
  float csum[8], csq[8];
  #pragma unroll
  for (int t = 0; t < 8; t++){
    float ss = 0.f, qq = 0.f;
    #pragma unroll
    for (int q = 0; q < 4; q++){
      float v = acc[t][q];
      int grow = row0 + m0 + l4 * 4 + q;
      Out[(size_t)grow * C + t * 16 + l16] = f2bf(v);
      ss += v; qq += v*v;
    }
    csum[t] = ss; csq[t] = qq;
  }
  __syncthreads();
  gemm_stats_epi(csum, csq, (float*)As, wave, l4, l16, tid, stats);
}

// ---------------- submanifold conv v14: 32x32x16 MFMA, single 32KB buffer, lb(256,2) ----------------
__device__ __forceinline__ int ld_midx(const int* __restrict__ nbr, const void* __restrict__ maskp,
                                       int mm, int g){
  bool on = mm ? (((const unsigned char*)maskp)[g] != 0)
               : (((const int*)maskp)[g] != 0);
  int v = nbr[g];
  return on ? v : -1;
}

template<typename OT>
__global__ __launch_bounds__(256, 2)
void k_conv(const unsigned short* __restrict__ In, const unsigned short* __restrict__ Wt,
            const int* __restrict__ nbr, const void* __restrict__ maskp,
            const int* __restrict__ mmode, OT* __restrict__ Out, float* __restrict__ stats)
{
  __shared__ unsigned short Bs[128*128];      // 32 KiB single buffer, pre-swizzled source
  const int tid = threadIdx.x;
  const int lane = tid & 63, wave = tid >> 6;   // 4 waves
  const int l31 = lane & 31, half = lane >> 5;
  const int row0 = blockIdx.x * 128;            // 128 rows/block, 32 rows/wave
  const int mm = *mmode;
  const int rg = row0 + wave*32 + l31;          // this lane's row
  const s16x8 z8 = (s16x8){0,0,0,0,0,0,0,0};

  auto stage_B = [&](int k){
    const char* gsrc = (const char*)(Wt + k*16384);
    char* lbase = (char*)&Bs[0];
    #pragma unroll
    for (int p = 0; p < 8; p++){
      int chunk = p*256 + wave*64;              // wave-uniform LDS base
      __builtin_amdgcn_global_load_lds(
        (const unsigned int*)(gsrc + (size_t)(chunk + lane)*16),
        (unsigned int*)(lbase + (size_t)chunk*16), 16, 0, 0);
    }
  };

  f32x16 acc[4];
  #pragma unroll
  for (int t = 0; t < 4; t++)
    acc[t] = (f32x16){0,0,0,0,0,0,0,0,0,0,0,0,0,0,0,0};

  s16x8 A0[8], A1[8];
  auto gather = [&](s16x8* dA, int gi){
    #pragma unroll
    for (int s = 0; s < 8; s++)
      dA[s] = (gi >= 0) ? *(const s16x8*)(In + (size_t)gi*C + s*16 + half*8) : z8;
  };
  auto compute = [&](const s16x8* a){
    #pragma unroll
    for (int s = 0; s < 8; s++){
      #pragma unroll
      for (int t = 0; t < 4; t++){
        int n = t*32 + l31;
        s16x8 b = *(const s16x8*)(&Bs[n*128 + (((s*2 + half) ^ (n & 15)) << 3)]);
        acc[t] = __builtin_amdgcn_mfma_f32_32x32x16_bf16(a[s], b, acc[t], 0, 0, 0);
      }
    }
  };

  // prologue: B[0], A(k=0), idx(k=1)
  stage_B(0);
  int i0 = ld_midx(nbr, maskp, mm, rg*K27 + 0);
  gather(A0, i0);
  i0 = ld_midx(nbr, maskp, mm, rg*K27 + 1);
  __syncthreads();                              // buf(W0) ready

  #pragma unroll 1
  for (int kb = 0; kb < 13; kb++){
    const int k = kb * 2;
    // even k: buf holds W[k]
    gather(A1, i0);                             // A(k+1)
    i0 = ld_midx(nbr, maskp, mm, rg*K27 + k + 2);
    compute(A0);
    __syncthreads();                            // done reading buf
    stage_B(k + 1);
    __syncthreads();                            // buf(W[k+1]) ready
    // odd k+1
    gather(A0, i0);                             // A(k+2)
    if (kb < 12) i0 = ld_midx(nbr, maskp, mm, rg*K27 + k + 3);
    compute(A1);
    __syncthreads();                            // done reading buf
    stage_B(k + 2);
    __syncthreads();                            // buf(W[k+2]) ready
  }
  compute(A0);   // k = 26

  // epilogue: write + fused column stats
  // C/D layout (verified): col = lane&31, row = (reg&3) + 8*(reg>>2) + 4*(lane>>5)
  float csum[4], csq[4];
  #pragma unroll
  for (int t = 0; t < 4; t++){
    float ss = 0.f, qq = 0.f;
    #pragma unroll
    for (int r = 0; r < 16; r++){
      float v = acc[t][r];
      int grow = row0 + wave*32 + (r & 3) + 8*(r >> 2) + 4*half;
      if constexpr (sizeof(OT) == 2) Out[(size_t)grow * C + t*32 + l31] = f2bf(v);
      else                           Out[(size_t)grow * C + t*32 + l31] = v;
      ss += v; qq += v*v;
    }
    csum[t] = ss; csq[t] = qq;
  }
  #pragma unroll
  for (int t = 0; t < 4; t++){
    csum[t] += __shfl_xor(csum[t], 32);
    csq[t]  += __shfl_xor(csq[t], 32);
  }
  __syncthreads();
  float* sred = (float*)Bs;
  if (half == 0){
    #pragma unroll
    for (int t = 0; t < 4; t++){
      sred[wave*128 + t*32 + l31] = csum[t];
      sred[512 + wave*128 + t*32 + l31] = csq[t];
    }
  }
  __syncthreads();
  if (tid < 128){
    float s = 0.f, q = 0.f;
    #pragma unroll
    for (int w2 = 0; w2 < 4; w2++){ s += sred[w2*128 + tid]; q += sred[512 + w2*128 + tid]; }
    atomicAdd(&stats[tid], s);
    atomicAdd(&stats[C + tid], q);
  }
}

// ---------------- elementwise kernels ----------------
template<int RELU>
__global__ void k_bnapply(const unsigned short* __restrict__ X, unsigned short* __restrict__ Y,
                          const float* __restrict__ st, const float* __restrict__ gamma,
                          const float* __restrict__ beta)
{
  const int total = N_PTS * 16;
  for (int idx = blockIdx.x*blockDim.x + threadIdx.x; idx < total; idx += gridDim.x*blockDim.x){
    int c0 = (idx & 15) * 8;
    int4 v = *(const int4*)(X + (size_t)idx * 8);
    float f[8];
    up2(v.x, f[0], f[1]); up2(v.y, f[2], f[3]); up2(v.z, f[4], f[5]); up2(v.w, f[6], f[7]);
    float o[8];
    #pragma unroll
    for (int j = 0; j < 8; j++){
      float sc, sh; bn_coef(st, gamma, beta, c0 + j, sc, sh);
      float t = f[j] * sc + sh;
      if (RELU) t = fmaxf(t, 0.f);
      o[j] = t;
    }
    *(int4*)(Y + (size_t)idx * 8) = make_int4(pk(o[0],o[1]), pk(o[2],o[3]), pk(o[4],o[5]), pk(o[6],o[7]));
  }
}

__global__ void k_fres(const unsigned short* __restrict__ G, const float* __restrict__ st,
                       const float* __restrict__ gamma, const float* __restrict__ beta,
                       const float* __restrict__ feat, unsigned short* __restrict__ FB)
{
  const int total = N_PTS * 16;
  for (int idx = blockIdx.x*blockDim.x + threadIdx.x; idx < total; idx += gridDim.x*blockDim.x){
    int c0 = (idx & 15) * 8;
    int4 v = *(const int4*)(G + (size_t)idx * 8);
    float f[8];
    up2(v.x, f[0], f[1]); up2(v.y, f[2], f[3]); up2(v.z, f[4], f[5]); up2(v.w, f[6], f[7]);
    const float4* fp = (const float4*)(feat + (size_t)idx * 8);
    float4 fa = fp[0], fb4 = fp[1];
    float fe[8] = {fa.x,fa.y,fa.z,fa.w,fb4.x,fb4.y,fb4.z,fb4.w};
    float o[8];
    #pragma unroll
    for (int j = 0; j < 8; j++){
      float sc, sh; bn_coef(st, gamma, beta, c0 + j, sc, sh);
      o[j] = fmaxf(f[j]*sc + sh, 0.f) + fe[j];
    }
    *(int4*)(FB + (size_t)idx * 8) = make_int4(pk(o[0],o[1]), pk(o[2],o[3]), pk(o[4],o[5]), pk(o[6],o[7]));
  }
}

__global__ void k_final(float* __restrict__ H2, const float* __restrict__ st,
                        const float* __restrict__ gamma, const float* __restrict__ beta,
                        const unsigned short* __restrict__ FB)
{
  const int total = N_PTS * 16;
  for (int idx = blockIdx.x*blockDim.x + threadIdx.x; idx < total; idx += gridDim.x*blockDim.x){
    int c0 = (idx & 15) * 8;
    float4* hp = (float4*)(H2 + (size_t)idx * 8);
    float4 a = hp[0], b = hp[1];
    int4 vf = *(const int4*)(FB + (size_t)idx * 8);
    float fr[8];
    up2(vf.x, fr[0], fr[1]); up2(vf.y, fr[2], fr[3]); up2(vf.z, fr[4], fr[5]); up2(vf.w, fr[6], fr[7]);
    float h[8] = {a.x,a.y,a.z,a.w,b.x,b.y,b.z,b.w};
    #pragma unroll
    for (int j = 0; j < 8; j++){
      float sc, sh; bn_coef(st, gamma, beta, c0 + j, sc, sh);
      h[j] = fmaxf(h[j]*sc + sh + fr[j], 0.f);
    }
    hp[0] = make_float4(h[0],h[1],h[2],h[3]);
    hp[1] = make_float4(h[4],h[5],h[6],h[7]);
  }
}

extern "C" void kernel_launch(void* const* d_in, const int* in_sizes, int n_in,
                              void* d_out, int out_size, void* d_ws, size_t ws_size,
                              hipStream_t stream)
{
  (void)in_sizes; (void)n_in; (void)out_size;
  const float* feat   = (const float*)d_in[0];
  const int* cls[3]   = {(const int*)d_in[1], (const int*)d_in[2], (const int*)d_in[3]};
  const int* nbr      = (const int*)d_in[4];
  const void* mask    = d_in[5];
  const float* lw_W   = (const float*)d_in[6];
  const float* lw_g   = (const float*)d_in[7];
  const float* lw_b   = (const float*)d_in[8];
  const float* w_W    = (const float*)d_in[9];
  const float* proj_W = (const float*)d_in[10];
  const float* proj_g = (const float*)d_in[11];
  const float* proj_b = (const float*)d_in[12];
  const float* adW    = (const float*)d_in[13];
  const float* fuse_W = (const float*)d_in[14];
  const float* fuse_g = (const float*)d_in[15];
  const float* fuse_b = (const float*)d_in[16];
  const float* conv_W = (const float*)d_in[17];
  const float* conv_g = (const float*)d_in[18];
  const float* conv_b = (const float*)d_in[19];

  char* w = (char*)d_ws;
  float*          stats  = (float*)(w + 0);            // 10 slots x 256 f32
  unsigned int*   gmax   = (unsigned int*)(w + 10240); // 3
  int*            mmode  = (int*)(w + 10240 + 16);
  int*            hist   = (int*)(w + 10496);          // 3*2048
  int*            starts = (int*)(w + 35072);          // 3*2049
  int*            cursor = (int*)(w + 59904);          // 3*2048
  int*            perm   = (int*)(w + 84480);          // 3*N
  float*          S1     = (float*)(w + 2004480);      // 2048*128
  float*          S3     = (float*)(w + 4101632);      // 3*2048*128
  float*          adp    = (float*)(w + 7247360);      // N*3
  unsigned short* tlw    = (unsigned short*)(w + 9167360);
  unsigned short* tw     = (unsigned short*)(w + 9265664);
  unsigned short* tproj  = (unsigned short*)(w + 9363968);
  unsigned short* tfuse  = (unsigned short*)(w + 9495040);
  unsigned short* tconv  = (unsigned short*)(w + 9560576);
  unsigned short* B1     = (unsigned short*)(w + 11330048);
  unsigned short* B2     = (unsigned short*)(w + 52290048);
  unsigned short* B3     = (unsigned short*)(w + 93250048);
  // base ws usage: 134,210,048 bytes; optional featb adds 40,960,000
  const bool useb = ws_size >= (size_t)175170048;
  unsigned short* featb = useb ? (unsigned short*)(w + 134210048) : nullptr;

  hipMemsetAsync(d_ws, 0, 35072, stream); // stats + gmax + mmode + hist

  k_prep_weights<<<65, 256, 0, stream>>>(lw_W, w_W, proj_W, conv_W, fuse_W,
                                         tlw, tw, tproj, tconv, tfuse);
  k_detect_mask<<<1, 256, 0, stream>>>((const unsigned int*)mask, mmode);
  k_hist<<<1024, 256, 0, stream>>>(cls[0], cls[1], cls[2], hist);
  k_prefix<<<3, 256, 0, stream>>>(hist, starts, cursor);
  k_scatter<<<1024, 256, 0, stream>>>(cls[0], cls[1], cls[2], cursor, perm);
  k_adp<<<2500, 256, 0, stream>>>(feat, adW, adp, featb);

  if (useb) k_gemm_plain<unsigned short><<<2500, 256, 0, stream>>>(featb, tlw, B1, stats);
  else      k_gemm_plain<float><<<2500, 256, 0, stream>>>(feat, tlw, B1, stats);

  for (int i = 0; i < 3; i++){
    k_seg<0><<<2048, 256, 0, stream>>>(B1, perm + i*N_PTS, starts + i*(NCLU+1),
                                       stats + i*256, lw_g + i*C, lw_b + i*C, S1);
    k_gemm_center<<<2500, 256, 0, stream>>>(B1, tw + i*16384, cls[i], S1, hist + i*NCLU,
                                            stats + i*256, lw_g + i*C, lw_b + i*C, B3, gmax + i);
    const unsigned short* w0 = tproj + i*16384;
    const unsigned short* w1 = (i < 2) ? (tlw + (i+1)*16384) : (tproj + 3*16384);
    float* st1 = (i < 2) ? (stats + (i+1)*256) : (stats + 6*256);
    if (useb) k_gemm_dual<unsigned short><<<2500, 256, 0, stream>>>(featb, w0, w1, B2, B1,
                                                                    stats + (3+i)*256, st1);
    else      k_gemm_dual<float><<<2500, 256, 0, stream>>>(feat, w0, w1, B2, B1,
                                                           stats + (3+i)*256, st1);
    k_seg12<<<2048, 256, 0, stream>>>(B2, B3, perm + i*N_PTS, starts + i*(NCLU+1),
                                      stats + (3+i)*256, proj_g + i*C, proj_b + i*C,
                                      gmax + i, S3 + (size_t)i*NCLU*C);
  }

  k_gemm_fuse<<<2500, 256, 0, stream>>>(B1, adp, cls[0], cls[1], cls[2], S3,
                                        stats + 6*256, proj_g + 3*C, proj_b + 3*C, tfuse,
                                        B2, stats + 7*256);
  k_fres<<<2048, 256, 0, stream>>>(B2, stats + 7*256, fuse_g, fuse_b, feat, B3);

  k_conv<unsigned short><<<1250, 256, 0, stream>>>(B3, tconv, nbr, mask, mmode, B1, stats + 8*256);
  k_bnapply<1><<<2048, 256, 0, stream>>>(B1, B2, stats + 8*256, conv_g, conv_b);
  k_conv<float><<<1250, 256, 0, stream>>>(B2, tconv + 27*16384, nbr, mask, mmode,
                                          (float*)d_out, stats + 9*256);
  k_final<<<2048, 256, 0, stream>>>((float*)d_out, stats + 9*256, conv_g + C, conv_b + C, B3);
}

// Round 15
// 1217.374 us; speedup vs baseline: 1.2492x; 1.0234x over previous
//
#include <hip/hip_runtime.h>
#include <stdint.h>

#define N_PTS 160000
#define C 128
#define K27 27
#define NCLU 2048
#define BN_EPS 1e-5f
#define KP 136   // padded LDS k-stride (bf16 elems) for K=128 GEMM tiles
#define KP2 264  // for K=256 fuse tile

typedef float f32x4 __attribute__((ext_vector_type(4)));
typedef float f32x16 __attribute__((ext_vector_type(16)));
typedef short s16x8 __attribute__((ext_vector_type(8)));

__device__ __forceinline__ float bf2f(unsigned short u){
  union { unsigned int i; float f; } v; v.i = ((unsigned int)u) << 16; return v.f;
}
__device__ __forceinline__ unsigned short f2bf(float f){
  union { float f; unsigned int i; } v; v.f = f;
  unsigned int u = v.i;
  u += 0x7FFFu + ((u >> 16) & 1u);
  return (unsigned short)(u >> 16);
}
__device__ __forceinline__ unsigned int pk(float a, float b){
  return (unsigned int)f2bf(a) | ((unsigned int)f2bf(b) << 16);
}
__device__ __forceinline__ void up2(int w, float& a, float& b){
  a = bf2f((unsigned short)(w & 0xFFFF));
  b = bf2f((unsigned short)(((unsigned int)w) >> 16));
}
__device__ __forceinline__ unsigned int encf(float f){
  union { float f; unsigned int i; } v; v.f = f;
  return ((int)v.i < 0) ? ~v.i : (v.i | 0x80000000u);
}
__device__ __forceinline__ float decf(unsigned int e){
  union { unsigned int i; float f; } v;
  v.i = ((int)e < 0) ? (e ^ 0x80000000u) : ~e;
  return v.f;
}
__device__ __forceinline__ void bn_coef(const float* st, const float* gamma, const float* beta,
                                        int c, float& sc, float& sh){
  float mean = st[c] * (1.0f / N_PTS);
  float var  = st[C + c] * (1.0f / N_PTS) - mean * mean;
  float g = gamma[c] * rsqrtf(fmaxf(var, 0.f) + BN_EPS);
  sc = g; sh = beta[c] - mean * g;
}

// ---------------- weight prep: f32 -> bf16, transposed to [n][k] ----------------
// tconv gets the conv-LDS XOR swizzle pre-applied (n&15: 16 slots over 32 lanes -> 2-way, free)
__global__ void k_prep_weights(const float* __restrict__ lw, const float* __restrict__ w,
                               const float* __restrict__ proj, const float* __restrict__ conv,
                               const float* __restrict__ fuse,
                               unsigned short* __restrict__ tlw, unsigned short* __restrict__ tw,
                               unsigned short* __restrict__ tproj, unsigned short* __restrict__ tconv,
                               unsigned short* __restrict__ tfuse)
{
  int z = blockIdx.x, tid = threadIdx.x;
  if (z < 64){
    const float* src; unsigned short* dst; bool swz = false;
    if (z < 3){ src = lw + z*16384; dst = tlw + z*16384; }
    else if (z < 6){ src = w + (z-3)*16384; dst = tw + (z-3)*16384; }
    else if (z < 10){ src = proj + (z-6)*16384; dst = tproj + (z-6)*16384; }
    else { src = conv + (z-10)*16384; dst = tconv + (z-10)*16384; swz = true; }
    for (int i = tid; i < 16384; i += 256){
      int n = i >> 7, k = i & 127;
      int pos = swz ? (n*128 + (((k >> 3) ^ (n & 15)) << 3) + (k & 7)) : i;
      dst[pos] = f2bf(src[k*128 + n]);
    }
  } else {
    for (int i = tid; i < 32768; i += 256){
      int n = i >> 8, k = i & 255;
      tfuse[i] = f2bf(fuse[k*128 + n]);
    }
  }
}

// ---------------- mask dtype detection (int32 vs packed bytes) ----------------
__global__ void k_detect_mask(const unsigned int* __restrict__ mw, int* __restrict__ mmode)
{
  __shared__ int flag;
  if (threadIdx.x == 0) flag = 0;
  __syncthreads();
  for (int i = threadIdx.x; i < 4096; i += 256)
    if (mw[i] > 1u) flag = 1;
  __syncthreads();
  if (threadIdx.x == 0) *mmode = flag;
}

// ---------------- cluster histogram / prefix / scatter ----------------
__global__ void k_hist(const int* __restrict__ c0, const int* __restrict__ c1,
                       const int* __restrict__ c2, int* __restrict__ hist)
{
  int idx = blockIdx.x*blockDim.x + threadIdx.x;
  int stride = gridDim.x*blockDim.x;
  for (; idx < 3*N_PTS; idx += stride){
    int j = idx / N_PTS, r = idx - j*N_PTS;
    const int* cp = (j==0)?c0:((j==1)?c1:c2);
    atomicAdd(&hist[j*NCLU + cp[r]], 1);
  }
}

__global__ void k_prefix(const int* __restrict__ hist, int* __restrict__ starts,
                         int* __restrict__ cursor)
{
  int j = blockIdx.x, tid = threadIdx.x;
  __shared__ int buf[NCLU];
  __shared__ int csum[256];
  for (int i = tid; i < NCLU; i += 256) buf[i] = hist[j*NCLU + i];
  __syncthreads();
  int s = 0;
  #pragma unroll
  for (int k = 0; k < 8; k++) s += buf[tid*8 + k];
  csum[tid] = s;
  __syncthreads();
  if (tid == 0){
    int run = 0;
    for (int i = 0; i < 256; i++){ int t = csum[i]; csum[i] = run; run += t; }
  }
  __syncthreads();
  int acc = csum[tid];
  #pragma unroll
  for (int k = 0; k < 8; k++){
    int i = tid*8 + k;
    starts[j*(NCLU+1) + i] = acc;
    cursor[j*NCLU + i] = acc;
    acc += buf[i];
  }
  if (tid == 255) starts[j*(NCLU+1) + NCLU] = acc;
}

__global__ void k_scatter(const int* __restrict__ c0, const int* __restrict__ c1,
                          const int* __restrict__ c2, int* __restrict__ cursor,
                          int* __restrict__ perm)
{
  int idx = blockIdx.x*blockDim.x + threadIdx.x;
  int stride = gridDim.x*blockDim.x;
  for (; idx < 3*N_PTS; idx += stride){
    int j = idx / N_PTS, r = idx - j*N_PTS;
    const int* cp = (j==0)?c0:((j==1)?c1:c2);
    int cl = cp[r];
    int slot = atomicAdd(&cursor[j*NCLU + cl], 1);
    perm[j*N_PTS + slot] = r;
  }
}

// ---------------- segment reduction V0: S1 = per-cluster sum of relu(bn(x)) ----------------
template<int V>
__global__ void k_seg(const unsigned short* __restrict__ X,
                      const int* __restrict__ perm, const int* __restrict__ starts,
                      const float* __restrict__ st, const float* __restrict__ gamma,
                      const float* __restrict__ beta, float* __restrict__ S)
{
  __shared__ float red[16*128];
  const int cl = blockIdx.x;
  const int p0 = starts[cl], p1 = starts[cl+1];
  const int g = threadIdx.x >> 4, s = threadIdx.x & 15;
  const int c0 = s * 8;
  float sc[8], sh[8];
  #pragma unroll
  for (int j = 0; j < 8; j++) bn_coef(st, gamma, beta, c0 + j, sc[j], sh[j]);
  float acc[8];
  #pragma unroll
  for (int j = 0; j < 8; j++) acc[j] = 0.f;
  for (int p = p0 + g; p < p1; p += 16){
    int row = perm[p];
    int4 v = *(const int4*)(X + (size_t)row*C + c0);
    float f[8];
    up2(v.x, f[0], f[1]); up2(v.y, f[2], f[3]); up2(v.z, f[4], f[5]); up2(v.w, f[6], f[7]);
    #pragma unroll
    for (int j = 0; j < 8; j++) acc[j] += fmaxf(f[j]*sc[j] + sh[j], 0.f);
  }
  #pragma unroll
  for (int j = 0; j < 8; j++) red[g*128 + c0 + j] = acc[j];
  __syncthreads();
  if (threadIdx.x < 128){
    float t = 0.f;
    #pragma unroll
    for (int gg = 0; gg < 16; gg++) t += red[gg*128 + threadIdx.x];
    S[cl*C + threadIdx.x] = t;
  }
}

// ---------------- single-pass seg12 ----------------
__global__ void k_seg12(const unsigned short* __restrict__ XP, const unsigned short* __restrict__ X2,
                        const int* __restrict__ perm, const int* __restrict__ starts,
                        const float* __restrict__ st, const float* __restrict__ gamma,
                        const float* __restrict__ beta, const unsigned int* __restrict__ genc,
                        float* __restrict__ S3)
{
  __shared__ float red[16*128];
  const int cl = blockIdx.x;
  const int p0 = starts[cl], p1 = starts[cl+1];
  const int g = threadIdx.x >> 4, s = threadIdx.x & 15;
  const int c0 = s * 8;
  const float gm = decf(*genc);
  float sc[8], sh[8];
  #pragma unroll
  for (int j = 0; j < 8; j++) bn_coef(st, gamma, beta, c0 + j, sc[j], sh[j]);

  float accN[8], accD[8];
  #pragma unroll
  for (int j = 0; j < 8; j++){ accN[j] = 0.f; accD[j] = 0.f; }
  for (int p = p0 + g; p < p1; p += 16){
    int row = perm[p];
    int4 v  = *(const int4*)(XP + (size_t)row*C + c0);
    int4 v2 = *(const int4*)(X2 + (size_t)row*C + c0);
    float f[8], x2[8];
    up2(v.x, f[0], f[1]); up2(v.y, f[2], f[3]); up2(v.z, f[4], f[5]); up2(v.w, f[6], f[7]);
    up2(v2.x, x2[0], x2[1]); up2(v2.y, x2[2], x2[3]); up2(v2.z, x2[4], x2[5]); up2(v2.w, x2[6], x2[7]);
    #pragma unroll
    for (int j = 0; j < 8; j++){
      float e = __expf(x2[j] - gm);
      accD[j] += e;
      accN[j] += fmaxf(f[j]*sc[j] + sh[j], 0.f) * e;
    }
  }
  #pragma unroll
  for (int j = 0; j < 8; j++) red[g*128 + c0 + j] = accN[j];
  __syncthreads();
  float tN = 0.f;
  if (threadIdx.x < 128){
    #pragma unroll
    for (int gg = 0; gg < 16; gg++) tN += red[gg*128 + threadIdx.x];
  }
  __syncthreads();
  #pragma unroll
  for (int j = 0; j < 8; j++) red[g*128 + c0 + j] = accD[j];
  __syncthreads();
  if (threadIdx.x < 128){
    float tD = 0.f;
    #pragma unroll
    for (int gg = 0; gg < 16; gg++) tD += red[gg*128 + threadIdx.x];
    S3[cl*C + threadIdx.x] = tN / (tD + 1e-6f);
  }
}

// ---------------- adaptive softmax weights (+ bf16 feat side-write) ----------------
__global__ void k_adp(const float* __restrict__ feat, const float* __restrict__ aW,
                      float* __restrict__ adp, unsigned short* __restrict__ featb)
{
  __shared__ float wsh[384];
  int tid = threadIdx.x;
  for (int i = tid; i < 384; i += 256) wsh[i] = aW[i];
  __syncthreads();
  int gidx = blockIdx.x*256 + tid;
  int stride = gridDim.x*256;
  for (int t4 = gidx; t4 < N_PTS*4; t4 += stride){
    int row = t4 >> 2, part = t4 & 3;
    float e0=0.f, e1=0.f, e2=0.f;
    const float* fr = feat + (size_t)row*C + part*32;
    unsigned int pb[16];
    #pragma unroll
    for (int c = 0; c < 32; c += 4){
      float4 v = *(const float4*)(fr + c);
      int cc = part*32 + c;
      e0 += v.x*wsh[cc*3+0] + v.y*wsh[(cc+1)*3+0] + v.z*wsh[(cc+2)*3+0] + v.w*wsh[(cc+3)*3+0];
      e1 += v.x*wsh[cc*3+1] + v.y*wsh[(cc+1)*3+1] + v.z*wsh[(cc+2)*3+1] + v.w*wsh[(cc+3)*3+1];
      e2 += v.x*wsh[cc*3+2] + v.y*wsh[(cc+1)*3+2] + v.z*wsh[(cc+2)*3+2] + v.w*wsh[(cc+3)*3+2];
      pb[(c>>1)]   = pk(v.x, v.y);
      pb[(c>>1)+1] = pk(v.z, v.w);
    }
    if (featb){
      int4* dst = (int4*)(featb + (size_t)row*C + part*32);
      dst[0] = make_int4(pb[0], pb[1], pb[2], pb[3]);
      dst[1] = make_int4(pb[4], pb[5], pb[6], pb[7]);
      dst[2] = make_int4(pb[8], pb[9], pb[10], pb[11]);
      dst[3] = make_int4(pb[12], pb[13], pb[14], pb[15]);
    }
    e0 += __shfl_xor(e0, 1); e0 += __shfl_xor(e0, 2);
    e1 += __shfl_xor(e1, 1); e1 += __shfl_xor(e1, 2);
    e2 += __shfl_xor(e2, 1); e2 += __shfl_xor(e2, 2);
    if (part == 0){
      float m = fmaxf(e0, fmaxf(e1, e2));
      float p0 = __expf(e0-m), p1 = __expf(e1-m), p2 = __expf(e2-m);
      float inv = 1.f/(p0+p1+p2);
      adp[row*3+0] = p0*inv; adp[row*3+1] = p1*inv; adp[row*3+2] = p2*inv;
    }
  }
}

// shared stats epilogue for 4-wave GEMM blocks (sred must hold 1024 floats)
__device__ __forceinline__ void gemm_stats_epi(float* csum, float* csq, float* sred,
                                               int wave, int l4, int l16, int tid,
                                               float* __restrict__ stats)
{
  #pragma unroll
  for (int t = 0; t < 8; t++){
    csum[t] += __shfl_xor(csum[t], 16); csum[t] += __shfl_xor(csum[t], 32);
    csq[t]  += __shfl_xor(csq[t], 16);  csq[t]  += __shfl_xor(csq[t], 32);
  }
  if (l4 == 0){
    #pragma unroll
    for (int t = 0; t < 8; t++){
      sred[wave*128 + t*16 + l16] = csum[t];
      sred[512 + wave*128 + t*16 + l16] = csq[t];
    }
  }
  __syncthreads();
  if (tid < 128){
    float s = 0.f, q = 0.f;
    #pragma unroll
    for (int w2 = 0; w2 < 4; w2++){ s += sred[w2*128 + tid]; q += sred[512 + w2*128 + tid]; }
    atomicAdd(&stats[tid], s);
    atomicAdd(&stats[C + tid], q);
  }
}

// A staging helper: 64 rows x 128 k into As (bf16)
template<typename AT>
__device__ __forceinline__ void stage_A(const AT* __restrict__ A, unsigned short* As,
                                        int row0, int r, int s)
{
  #pragma unroll
  for (int p = 0; p < 4; p++){
    int rr = r + p * 16;
    if constexpr (sizeof(AT) == 2){
      *(int4*)(As + rr * KP + s * 8) =
        *(const int4*)((const unsigned short*)A + (size_t)(row0 + rr) * C + s * 8);
    } else {
      const float4* ap = (const float4*)((const float*)A + (size_t)(row0 + rr) * C + s * 8);
      float4 x = ap[0], y = ap[1];
      *(int4*)(As + rr * KP + s * 8) =
        make_int4(pk(x.x,x.y), pk(x.z,x.w), pk(y.x,y.y), pk(y.z,y.w));
    }
  }
}

// ---------------- GEMM: out[N,128] = A @ Bt, + fused column stats ----------------
template<typename AT>
__global__ __launch_bounds__(256, 3)
void k_gemm_plain(const AT* __restrict__ A, const unsigned short* __restrict__ Bt,
                  unsigned short* __restrict__ Out, float* __restrict__ stats)
{
  __shared__ unsigned short As[64 * KP];
  __shared__ unsigned short Bs[128 * KP];
  const int tid = threadIdx.x;
  const int row0 = blockIdx.x * 64;
  const int r = tid >> 4, s = tid & 15;
  stage_A<AT>(A, As, row0, r, s);
  #pragma unroll
  for (int p = 0; p < 8; p++){
    int nn = r + p * 16;
    *(int4*)(Bs + nn * KP + s * 8) = *(const int4*)(Bt + nn * C + s * 8);
  }
  __syncthreads();
  const int lane = tid & 63, wave = tid >> 6;
  const int l16 = lane & 15, l4 = lane >> 4, m0 = wave * 16;
  f32x4 acc[8];
  #pragma unroll
  for (int t = 0; t < 8; t++) acc[t] = (f32x4){0.f,0.f,0.f,0.f};
  #pragma unroll
  for (int kk = 0; kk < 4; kk++){
    s16x8 a = *(const s16x8*)(As + (m0 + l16) * KP + kk * 32 + l4 * 8);
    #pragma unroll
    for (int t = 0; t < 8; t++){
      s16x8 b = *(const s16x8*)(Bs + (t * 16 + l16) * KP + kk * 32 + l4 * 8);
      acc[t] = __builtin_amdgcn_mfma_f32_16x16x32_bf16(a, b, acc[t], 0, 0, 0);
    }
  }
  float csum[8], csq[8];
  #pragma unroll
  for (int t = 0; t < 8; t++){
    float ss = 0.f, qq = 0.f;
    #pragma unroll
    for (int q = 0; q < 4; q++){
      float v = acc[t][q];
      int grow = row0 + m0 + l4 * 4 + q;
      Out[(size_t)grow * C + t * 16 + l16] = f2bf(v);
      ss += v; qq += v*v;
    }
    csum[t] = ss; csq[t] = qq;
  }
  __syncthreads();
  gemm_stats_epi(csum, csq, (float*)As, wave, l4, l16, tid, stats);
}

// ---------------- dual GEMM: two weight matrices, A staged once ----------------
template<typename AT>
__global__ __launch_bounds__(256, 3)
void k_gemm_dual(const AT* __restrict__ A,
                 const unsigned short* __restrict__ Bt0, const unsigned short* __restrict__ Bt1,
                 unsigned short* __restrict__ Out0, unsigned short* __restrict__ Out1,
                 float* __restrict__ stats0, float* __restrict__ stats1)
{
  __shared__ unsigned short As[64 * KP];
  __shared__ unsigned short Bs[128 * KP];
  const int tid = threadIdx.x;
  const int row0 = blockIdx.x * 64;
  const int r = tid >> 4, s = tid & 15;
  const int lane = tid & 63, wave = tid >> 6;
  const int l16 = lane & 15, l4 = lane >> 4, m0 = wave * 16;

  stage_A<AT>(A, As, row0, r, s);
  #pragma unroll
  for (int p = 0; p < 8; p++){
    int nn = r + p * 16;
    *(int4*)(Bs + nn * KP + s * 8) = *(const int4*)(Bt0 + nn * C + s * 8);
  }
  __syncthreads();

  f32x4 acc[8];
  float csum0[8], csq0[8], csum1[8], csq1[8];

  #pragma unroll
  for (int t = 0; t < 8; t++) acc[t] = (f32x4){0.f,0.f,0.f,0.f};
  #pragma unroll
  for (int kk = 0; kk < 4; kk++){
    s16x8 a = *(const s16x8*)(As + (m0 + l16) * KP + kk * 32 + l4 * 8);
    #pragma unroll
    for (int t = 0; t < 8; t++){
      s16x8 b = *(const s16x8*)(Bs + (t * 16 + l16) * KP + kk * 32 + l4 * 8);
      acc[t] = __builtin_amdgcn_mfma_f32_16x16x32_bf16(a, b, acc[t], 0, 0, 0);
    }
  }
  #pragma unroll
  for (int t = 0; t < 8; t++){
    float ss = 0.f, qq = 0.f;
    #pragma unroll
    for (int q = 0; q < 4; q++){
      float v = acc[t][q];
      int grow = row0 + m0 + l4 * 4 + q;
      Out0[(size_t)grow * C + t * 16 + l16] = f2bf(v);
      ss += v; qq += v*v;
    }
    csum0[t] = ss; csq0[t] = qq;
  }
  __syncthreads();
  #pragma unroll
  for (int p = 0; p < 8; p++){
    int nn = r + p * 16;
    *(int4*)(Bs + nn * KP + s * 8) = *(const int4*)(Bt1 + nn * C + s * 8);
  }
  __syncthreads();

  #pragma unroll
  for (int t = 0; t < 8; t++) acc[t] = (f32x4){0.f,0.f,0.f,0.f};
  #pragma unroll
  for (int kk = 0; kk < 4; kk++){
    s16x8 a = *(const s16x8*)(As + (m0 + l16) * KP + kk * 32 + l4 * 8);
    #pragma unroll
    for (int t = 0; t < 8; t++){
      s16x8 b = *(const s16x8*)(Bs + (t * 16 + l16) * KP + kk * 32 + l4 * 8);
      acc[t] = __builtin_amdgcn_mfma_f32_16x16x32_bf16(a, b, acc[t], 0, 0, 0);
    }
  }
  #pragma unroll
  for (int t = 0; t < 8; t++){
    float ss = 0.f, qq = 0.f;
    #pragma unroll
    for (int q = 0; q < 4; q++){
      float v = acc[t][q];
      int grow = row0 + m0 + l4 * 4 + q;
      Out1[(size_t)grow * C + t * 16 + l16] = f2bf(v);
      ss += v; qq += v*v;
    }
    csum1[t] = ss; csq1[t] = qq;
  }
  __syncthreads();
  gemm_stats_epi(csum0, csq0, (float*)As, wave, l4, l16, tid, stats0);
  __syncthreads();
  gemm_stats_epi(csum1, csq1, (float*)As, wave, l4, l16, tid, stats1);
}

// ---------------- GEMM: (relu(bn(x)) - clustermean) @ w_W + global max ----------------
__global__ __launch_bounds__(256, 3)
void k_gemm_center(const unsigned short* __restrict__ PW, const unsigned short* __restrict__ Bt,
                   const int* __restrict__ cla, const float* __restrict__ S1,
                   const int* __restrict__ cnt, const float* __restrict__ st,
                   const float* __restrict__ gamma, const float* __restrict__ beta,
                   unsigned short* __restrict__ Out, unsigned int* __restrict__ gmax)
{
  __shared__ unsigned short As[64 * KP];
  __shared__ unsigned short Bs[128 * KP];
  __shared__ float wred[4];
  const int tid = threadIdx.x;
  const int row0 = blockIdx.x * 64;
  const int r = tid >> 4, s = tid & 15;
  float sc[8], sh[8];
  #pragma unroll
  for (int j = 0; j < 8; j++) bn_coef(st, gamma, beta, s*8 + j, sc[j], sh[j]);
  #pragma unroll
  for (int p = 0; p < 4; p++){
    int rr = r + p * 16;
    int grow = row0 + rr;
    int cl = cla[grow];
    float inv = 1.f / fmaxf(1.f, (float)cnt[cl]);
    int4 v = *(const int4*)(PW + (size_t)grow * C + s * 8);
    const float4* mp = (const float4*)(S1 + cl * C + s * 8);
    float4 ma = mp[0], mb = mp[1];
    float f[8];
    up2(v.x, f[0], f[1]); up2(v.y, f[2], f[3]); up2(v.z, f[4], f[5]); up2(v.w, f[6], f[7]);
    float m8[8] = {ma.x,ma.y,ma.z,ma.w,mb.x,mb.y,mb.z,mb.w};
    float o[8];
    #pragma unroll
    for (int j = 0; j < 8; j++) o[j] = fmaxf(f[j]*sc[j] + sh[j], 0.f) - m8[j]*inv;
    *(int4*)(As + rr * KP + s * 8) = make_int4(pk(o[0],o[1]), pk(o[2],o[3]), pk(o[4],o[5]), pk(o[6],o[7]));
  }
  #pragma unroll
  for (int p = 0; p < 8; p++){
    int nn = r + p * 16;
    *(int4*)(Bs + nn * KP + s * 8) = *(const int4*)(Bt + nn * C + s * 8);
  }
  __syncthreads();
  const int lane = tid & 63, wave = tid >> 6;
  const int l16 = lane & 15, l4 = lane >> 4, m0 = wave * 16;
  f32x4 acc[8];
  #pragma unroll
  for (int t = 0; t < 8; t++) acc[t] = (f32x4){0.f,0.f,0.f,0.f};
  #pragma unroll
  for (int kk = 0; kk < 4; kk++){
    s16x8 a = *(const s16x8*)(As + (m0 + l16) * KP + kk * 32 + l4 * 8);
    #pragma unroll
    for (int t = 0; t < 8; t++){
      s16x8 b = *(const s16x8*)(Bs + (t * 16 + l16) * KP + kk * 32 + l4 * 8);
      acc[t] = __builtin_amdgcn_mfma_f32_16x16x32_bf16(a, b, acc[t], 0, 0, 0);
    }
  }
  float mx = -3.4e38f;
  #pragma unroll
  for (int t = 0; t < 8; t++){
    #pragma unroll
    for (int q = 0; q < 4; q++){
      int grow = row0 + m0 + l4 * 4 + q;
      unsigned short ob = f2bf(acc[t][q]);
      Out[(size_t)grow * C + t * 16 + l16] = ob;
      mx = fmaxf(mx, bf2f(ob));
    }
  }
  #pragma unroll
  for (int off = 32; off; off >>= 1) mx = fmaxf(mx, __shfl_xor(mx, off));
  if ((tid & 63) == 0) wred[tid >> 6] = mx;
  __syncthreads();
  if (tid == 0){
    float m = fmaxf(fmaxf(wred[0], wred[1]), fmaxf(wred[2], wred[3]));
    atomicMax(gmax, encf(m));
  }
}

// ---------------- fuse GEMM: [relu(bn(xp3)), fused] @ fuse_W, K=256, + stats ----------------
__global__ __launch_bounds__(256, 2)
void k_gemm_fuse(const unsigned short* __restrict__ XP3, const float* __restrict__ adp,
                 const int* __restrict__ cl0, const int* __restrict__ cl1,
                 const int* __restrict__ cl2, const float* __restrict__ S3,
                 const float* __restrict__ st, const float* __restrict__ gamma,
                 const float* __restrict__ beta, const unsigned short* __restrict__ Bt,
                 unsigned short* __restrict__ Out, float* __restrict__ stats)
{
  __shared__ unsigned short As[64 * KP2];
  __shared__ unsigned short Bs[128 * KP];
  __shared__ float scs[C], shs[C];
  const int tid = threadIdx.x;
  if (tid < C){ float a, b; bn_coef(st, gamma, beta, tid, a, b); scs[tid] = a; shs[tid] = b; }
  __syncthreads();
  const int row0 = blockIdx.x * 64;
  const int r8 = tid >> 5, s = tid & 31;
  const int r = tid >> 4, s16i = tid & 15;
  #pragma unroll
  for (int p = 0; p < 8; p++){
    int rr = r8 + p * 8;
    int grow = row0 + rr;
    if (s < 16){
      int c0 = s * 8;
      int4 v = *(const int4*)(XP3 + (size_t)grow * C + c0);
      float f0,f1,f2,f3,f4,f5,f6,f7;
      up2(v.x,f0,f1); up2(v.y,f2,f3); up2(v.z,f4,f5); up2(v.w,f6,f7);
      float o0 = fmaxf(f0*scs[c0+0]+shs[c0+0],0.f), o1 = fmaxf(f1*scs[c0+1]+shs[c0+1],0.f);
      float o2 = fmaxf(f2*scs[c0+2]+shs[c0+2],0.f), o3 = fmaxf(f3*scs[c0+3]+shs[c0+3],0.f);
      float o4 = fmaxf(f4*scs[c0+4]+shs[c0+4],0.f), o5 = fmaxf(f5*scs[c0+5]+shs[c0+5],0.f);
      float o6 = fmaxf(f6*scs[c0+6]+shs[c0+6],0.f), o7 = fmaxf(f7*scs[c0+7]+shs[c0+7],0.f);
      *(int4*)(As + rr * KP2 + c0) = make_int4(pk(o0,o1), pk(o2,o3), pk(o4,o5), pk(o6,o7));
    } else {
      int c0 = (s - 16) * 8;
      float a0 = adp[grow*3+0], a1 = adp[grow*3+1], a2 = adp[grow*3+2];
      const float* p0 = S3 + (size_t)cl0[grow] * C + c0;
      const float* p1 = S3 + (size_t)NCLU * C + (size_t)cl1[grow] * C + c0;
      const float* p2 = S3 + (size_t)2 * NCLU * C + (size_t)cl2[grow] * C + c0;
      float o[8];
      #pragma unroll
      for (int j = 0; j < 8; j++) o[j] = a0*p0[j] + a1*p1[j] + a2*p2[j];
      *(int4*)(As + rr * KP2 + 128 + c0) = make_int4(pk(o[0],o[1]), pk(o[2],o[3]), pk(o[4],o[5]), pk(o[6],o[7]));
    }
  }
  const int lane = tid & 63, wave = tid >> 6;
  const int l16 = lane & 15, l4 = lane >> 4, m0 = wave * 16;
  f32x4 acc[8];
  #pragma unroll
  for (int t = 0; t < 8; t++) acc[t] = (f32x4){0.f,0.f,0.f,0.f};
  #pragma unroll
  for (int h = 0; h < 2; h++){
    if (h) __syncthreads();
    #pragma unroll
    for (int p = 0; p < 8; p++){
      int nn = r + p * 16;
      *(int4*)(Bs + nn * KP + s16i * 8) = *(const int4*)(Bt + nn * 256 + h * 128 + s16i * 8);
    }
    __syncthreads();
    #pragma unroll
    for (int kk = 0; kk < 4; kk++){
      s16x8 a = *(const s16x8*)(As + (m0 + l16) * KP2 + h * 128 + kk * 32 + l4 * 8);
      #pragma unroll
      for (int t = 0; t < 8; t++){
        s16x8 b = *(const s16x8*)(Bs + (t * 16 + l16) * KP + kk * 32 + l4 * 8);
        acc[t] = __builtin_amdgcn_mfma_f32_16x16x32_bf16(a, b, acc[t], 0, 0, 0);
      }
    }
  }
  float csum[8], csq[8];
  #pragma unroll
  for (int t = 0; t < 8; t++){
    float ss = 0.f, qq = 0.f;
    #pragma unroll
    for (int q = 0; q < 4; q++){
      float v = acc[t][q];
      int grow = row0 + m0 + l4 * 4 + q;
      Out[(size_t)grow * C + t * 16 + l16] = f2bf(v);
      ss += v; qq += v*v;
    }
    csum[t] = ss; csq[t] = qq;
  }
  __syncthreads();
  gemm_stats_epi(csum, csq, (float*)As, wave, l4, l16, tid, stats);
}

// ---------------- submanifold conv v11: 32x32x16 MFMA + n&15 swizzle ----------------
__device__ __forceinline__ int ld_midx(const int* __restrict__ nbr, const void* __restrict__ maskp,
                                       int mm, int g){
  bool on = mm ? (((const unsigned char*)maskp)[g] != 0)
               : (((const int*)maskp)[g] != 0);
  int v = nbr[g];
  return on ? v : -1;
}

template<typename OT>
__global__ __launch_bounds__(256, 2)
void k_conv(const unsigned short* __restrict__ In, const unsigned short* __restrict__ Wt,
            const int* __restrict__ nbr, const void* __restrict__ maskp,
            const int* __restrict__ mmode, OT* __restrict__ Out, float* __restrict__ stats)
{
  __shared__ unsigned short Bs[2][128*128];   // 64 KiB, pre-swizzled source
  const int tid = threadIdx.x;
  const int lane = tid & 63, wave = tid >> 6;   // 4 waves
  const int l31 = lane & 31, half = lane >> 5;
  const int row0 = blockIdx.x * 128;            // 128 rows/block, 32 rows/wave
  const int mm = *mmode;
  const int rg = row0 + wave*32 + l31;          // this lane's row
  const s16x8 z8 = (s16x8){0,0,0,0,0,0,0,0};

  auto stage_B = [&](int buf, int k){
    const char* gsrc = (const char*)(Wt + k*16384);
    char* lbase = (char*)&Bs[buf][0];
    #pragma unroll
    for (int p = 0; p < 8; p++){
      int chunk = p*256 + wave*64;              // wave-uniform LDS base
      __builtin_amdgcn_global_load_lds(
        (const unsigned int*)(gsrc + (size_t)(chunk + lane)*16),
        (unsigned int*)(lbase + (size_t)chunk*16), 16, 0, 0);
    }
  };

  f32x16 acc[4];
  #pragma unroll
  for (int t = 0; t < 4; t++)
    acc[t] = (f32x16){0,0,0,0,0,0,0,0,0,0,0,0,0,0,0,0};

  s16x8 A0[8], A1[8];
  auto gather = [&](s16x8* dA, int gi){
    #pragma unroll
    for (int s = 0; s < 8; s++)
      dA[s] = (gi >= 0) ? *(const s16x8*)(In + (size_t)gi*C + s*16 + half*8) : z8;
  };
  auto compute = [&](const s16x8* a, int buf){
    #pragma unroll
    for (int s = 0; s < 8; s++){
      #pragma unroll
      for (int t = 0; t < 4; t++){
        int n = t*32 + l31;
        s16x8 b = *(const s16x8*)(&Bs[buf][n*128 + (((s*2 + half) ^ (n & 15)) << 3)]);
        acc[t] = __builtin_amdgcn_mfma_f32_32x32x16_bf16(a[s], b, acc[t], 0, 0, 0);
      }
    }
  };

  // prologue: B[0], A(k=0), idx(k=1)
  stage_B(0, 0);
  int i0 = ld_midx(nbr, maskp, mm, rg*K27 + 0);
  gather(A0, i0);
  i0 = ld_midx(nbr, maskp, mm, rg*K27 + 1);
  __syncthreads();

  #pragma unroll 1
  for (int kb = 0; kb < 13; kb++){
    const int k = kb * 2;
    stage_B(1, k + 1);
    gather(A1, i0);
    i0 = ld_midx(nbr, maskp, mm, rg*K27 + k + 2);
    compute(A0, 0);
    __syncthreads();
    stage_B(0, k + 2);
    gather(A0, i0);
    if (kb < 12) i0 = ld_midx(nbr, maskp, mm, rg*K27 + k + 3);
    compute(A1, 1);
    __syncthreads();
  }
  compute(A0, 0);   // k = 26

  // epilogue: write + fused column stats
  // C/D layout (verified): col = lane&31, row = (reg&3) + 8*(reg>>2) + 4*(lane>>5)
  float csum[4], csq[4];
  #pragma unroll
  for (int t = 0; t < 4; t++){
    float ss = 0.f, qq = 0.f;
    #pragma unroll
    for (int r = 0; r < 16; r++){
      float v = acc[t][r];
      int grow = row0 + wave*32 + (r & 3) + 8*(r >> 2) + 4*half;
      if constexpr (sizeof(OT) == 2) Out[(size_t)grow * C + t*32 + l31] = f2bf(v);
      else                           Out[(size_t)grow * C + t*32 + l31] = v;
      ss += v; qq += v*v;
    }
    csum[t] = ss; csq[t] = qq;
  }
  #pragma unroll
  for (int t = 0; t < 4; t++){
    csum[t] += __shfl_xor(csum[t], 32);
    csq[t]  += __shfl_xor(csq[t], 32);
  }
  __syncthreads();
  float* sred = (float*)Bs;
  if (half == 0){
    #pragma unroll
    for (int t = 0; t < 4; t++){
      sred[wave*128 + t*32 + l31] = csum[t];
      sred[512 + wave*128 + t*32 + l31] = csq[t];
    }
  }
  __syncthreads();
  if (tid < 128){
    float s = 0.f, q = 0.f;
    #pragma unroll
    for (int w2 = 0; w2 < 4; w2++){ s += sred[w2*128 + tid]; q += sred[512 + w2*128 + tid]; }
    atomicAdd(&stats[tid], s);
    atomicAdd(&stats[C + tid], q);
  }
}

// ---------------- elementwise kernels ----------------
template<int RELU>
__global__ void k_bnapply(const unsigned short* __restrict__ X, unsigned short* __restrict__ Y,
                          const float* __restrict__ st, const float* __restrict__ gamma,
                          const float* __restrict__ beta)
{
  const int total = N_PTS * 16;
  for (int idx = blockIdx.x*blockDim.x + threadIdx.x; idx < total; idx += gridDim.x*blockDim.x){
    int c0 = (idx & 15) * 8;
    int4 v = *(const int4*)(X + (size_t)idx * 8);
    float f[8];
    up2(v.x, f[0], f[1]); up2(v.y, f[2], f[3]); up2(v.z, f[4], f[5]); up2(v.w, f[6], f[7]);
    float o[8];
    #pragma unroll
    for (int j = 0; j < 8; j++){
      float sc, sh; bn_coef(st, gamma, beta, c0 + j, sc, sh);
      float t = f[j] * sc + sh;
      if (RELU) t = fmaxf(t, 0.f);
      o[j] = t;
    }
    *(int4*)(Y + (size_t)idx * 8) = make_int4(pk(o[0],o[1]), pk(o[2],o[3]), pk(o[4],o[5]), pk(o[6],o[7]));
  }
}

__global__ void k_fres(const unsigned short* __restrict__ G, const float* __restrict__ st,
                       const float* __restrict__ gamma, const float* __restrict__ beta,
                       const float* __restrict__ feat, unsigned short* __restrict__ FB)
{
  const int total = N_PTS * 16;
  for (int idx = blockIdx.x*blockDim.x + threadIdx.x; idx < total; idx += gridDim.x*blockDim.x){
    int c0 = (idx & 15) * 8;
    int4 v = *(const int4*)(G + (size_t)idx * 8);
    float f[8];
    up2(v.x, f[0], f[1]); up2(v.y, f[2], f[3]); up2(v.z, f[4], f[5]); up2(v.w, f[6], f[7]);
    const float4* fp = (const float4*)(feat + (size_t)idx * 8);
    float4 fa = fp[0], fb4 = fp[1];
    float fe[8] = {fa.x,fa.y,fa.z,fa.w,fb4.x,fb4.y,fb4.z,fb4.w};
    float o[8];
    #pragma unroll
    for (int j = 0; j < 8; j++){
      float sc, sh; bn_coef(st, gamma, beta, c0 + j, sc, sh);
      o[j] = fmaxf(f[j]*sc + sh, 0.f) + fe[j];
    }
    *(int4*)(FB + (size_t)idx * 8) = make_int4(pk(o[0],o[1]), pk(o[2],o[3]), pk(o[4],o[5]), pk(o[6],o[7]));
  }
}

__global__ void k_final(float* __restrict__ H2, const float* __restrict__ st,
                        const float* __restrict__ gamma, const float* __restrict__ beta,
                        const unsigned short* __restrict__ FB)
{
  const int total = N_PTS * 16;
  for (int idx = blockIdx.x*blockDim.x + threadIdx.x; idx < total; idx += gridDim.x*blockDim.x){
    int c0 = (idx & 15) * 8;
    float4* hp = (float4*)(H2 + (size_t)idx * 8);
    float4 a = hp[0], b = hp[1];
    int4 vf = *(const int4*)(FB + (size_t)idx * 8);
    float fr[8];
    up2(vf.x, fr[0], fr[1]); up2(vf.y, fr[2], fr[3]); up2(vf.z, fr[4], fr[5]); up2(vf.w, fr[6], fr[7]);
    float h[8] = {a.x,a.y,a.z,a.w,b.x,b.y,b.z,b.w};
    #pragma unroll
    for (int j = 0; j < 8; j++){
      float sc, sh; bn_coef(st, gamma, beta, c0 + j, sc, sh);
      h[j] = fmaxf(h[j]*sc + sh + fr[j], 0.f);
    }
    hp[0] = make_float4(h[0],h[1],h[2],h[3]);
    hp[1] = make_float4(h[4],h[5],h[6],h[7]);
  }
}

extern "C" void kernel_launch(void* const* d_in, const int* in_sizes, int n_in,
                              void* d_out, int out_size, void* d_ws, size_t ws_size,
                              hipStream_t stream)
{
  (void)in_sizes; (void)n_in; (void)out_size;
  const float* feat   = (const float*)d_in[0];
  const int* cls[3]   = {(const int*)d_in[1], (const int*)d_in[2], (const int*)d_in[3]};
  const int* nbr      = (const int*)d_in[4];
  const void* mask    = d_in[5];
  const float* lw_W   = (const float*)d_in[6];
  const float* lw_g   = (const float*)d_in[7];
  const float* lw_b   = (const float*)d_in[8];
  const float* w_W    = (const float*)d_in[9];
  const float* proj_W = (const float*)d_in[10];
  const float* proj_g = (const float*)d_in[11];
  const float* proj_b = (const float*)d_in[12];
  const float* adW    = (const float*)d_in[13];
  const float* fuse_W = (const float*)d_in[14];
  const float* fuse_g = (const float*)d_in[15];
  const float* fuse_b = (const float*)d_in[16];
  const float* conv_W = (const float*)d_in[17];
  const float* conv_g = (const float*)d_in[18];
  const float* conv_b = (const float*)d_in[19];

  char* w = (char*)d_ws;
  float*          stats  = (float*)(w + 0);            // 10 slots x 256 f32
  unsigned int*   gmax   = (unsigned int*)(w + 10240); // 3
  int*            mmode  = (int*)(w + 10240 + 16);
  int*            hist   = (int*)(w + 10496);          // 3*2048
  int*            starts = (int*)(w + 35072);          // 3*2049
  int*            cursor = (int*)(w + 59904);          // 3*2048
  int*            perm   = (int*)(w + 84480);          // 3*N
  float*          S1     = (float*)(w + 2004480);      // 2048*128
  float*          S3     = (float*)(w + 4101632);      // 3*2048*128
  float*          adp    = (float*)(w + 7247360);      // N*3
  unsigned short* tlw    = (unsigned short*)(w + 9167360);
  unsigned short* tw     = (unsigned short*)(w + 9265664);
  unsigned short* tproj  = (unsigned short*)(w + 9363968);
  unsigned short* tfuse  = (unsigned short*)(w + 9495040);
  unsigned short* tconv  = (unsigned short*)(w + 9560576);
  unsigned short* B1     = (unsigned short*)(w + 11330048);
  unsigned short* B2     = (unsigned short*)(w + 52290048);
  unsigned short* B3     = (unsigned short*)(w + 93250048);
  // base ws usage: 134,210,048 bytes; optional featb adds 40,960,000
  const bool useb = ws_size >= (size_t)175170048;
  unsigned short* featb = useb ? (unsigned short*)(w + 134210048) : nullptr;

  hipMemsetAsync(d_ws, 0, 35072, stream); // stats + gmax + mmode + hist

  k_prep_weights<<<65, 256, 0, stream>>>(lw_W, w_W, proj_W, conv_W, fuse_W,
                                         tlw, tw, tproj, tconv, tfuse);
  k_detect_mask<<<1, 256, 0, stream>>>((const unsigned int*)mask, mmode);
  k_hist<<<1024, 256, 0, stream>>>(cls[0], cls[1], cls[2], hist);
  k_prefix<<<3, 256, 0, stream>>>(hist, starts, cursor);
  k_scatter<<<1024, 256, 0, stream>>>(cls[0], cls[1], cls[2], cursor, perm);
  k_adp<<<2500, 256, 0, stream>>>(feat, adW, adp, featb);

  if (useb) k_gemm_plain<unsigned short><<<2500, 256, 0, stream>>>(featb, tlw, B1, stats);
  else      k_gemm_plain<float><<<2500, 256, 0, stream>>>(feat, tlw, B1, stats);

  for (int i = 0; i < 3; i++){
    k_seg<0><<<2048, 256, 0, stream>>>(B1, perm + i*N_PTS, starts + i*(NCLU+1),
                                       stats + i*256, lw_g + i*C, lw_b + i*C, S1);
    k_gemm_center<<<2500, 256, 0, stream>>>(B1, tw + i*16384, cls[i], S1, hist + i*NCLU,
                                            stats + i*256, lw_g + i*C, lw_b + i*C, B3, gmax + i);
    const unsigned short* w0 = tproj + i*16384;
    const unsigned short* w1 = (i < 2) ? (tlw + (i+1)*16384) : (tproj + 3*16384);
    float* st1 = (i < 2) ? (stats + (i+1)*256) : (stats + 6*256);
    if (useb) k_gemm_dual<unsigned short><<<2500, 256, 0, stream>>>(featb, w0, w1, B2, B1,
                                                                    stats + (3+i)*256, st1);
    else      k_gemm_dual<float><<<2500, 256, 0, stream>>>(feat, w0, w1, B2, B1,
                                                           stats + (3+i)*256, st1);
    k_seg12<<<2048, 256, 0, stream>>>(B2, B3, perm + i*N_PTS, starts + i*(NCLU+1),
                                      stats + (3+i)*256, proj_g + i*C, proj_b + i*C,
                                      gmax + i, S3 + (size_t)i*NCLU*C);
  }

  k_gemm_fuse<<<2500, 256, 0, stream>>>(B1, adp, cls[0], cls[1], cls[2], S3,
                                        stats + 6*256, proj_g + 3*C, proj_b + 3*C, tfuse,
                                        B2, stats + 7*256);
  k_fres<<<2048, 256, 0, stream>>>(B2, stats + 7*256, fuse_g, fuse_b, feat, B3);

  k_conv<unsigned short><<<1250, 256, 0, stream>>>(B3, tconv, nbr, mask, mmode, B1, stats + 8*256);
  k_bnapply<1><<<2048, 256, 0, stream>>>(B1, B2, stats + 8*256, conv_g, conv_b);
  k_conv<float><<<1250, 256, 0, stream>>>(B2, tconv + 27*16384, nbr, mask, mmode,
                                          (float*)d_out, stats + 9*256);
  k_final<<<2048, 256, 0, stream>>>((float*)d_out, stats + 9*256, conv_g + C, conv_b + C, B3);
}

// Round 16
// 1197.326 us; speedup vs baseline: 1.2701x; 1.0167x over previous
//
#include <hip/hip_runtime.h>
#include <stdint.h>

#define N_PTS 160000
#define C 128
#define K27 27
#define NCLU 2048
#define BN_EPS 1e-5f
#define KP 136   // padded LDS k-stride (bf16 elems) for K=128 GEMM tiles
#define KP2 264  // for K=256 fuse tile

typedef float f32x4 __attribute__((ext_vector_type(4)));
typedef float f32x16 __attribute__((ext_vector_type(16)));
typedef short s16x8 __attribute__((ext_vector_type(8)));

__device__ __forceinline__ float bf2f(unsigned short u){
  union { unsigned int i; float f; } v; v.i = ((unsigned int)u) << 16; return v.f;
}
__device__ __forceinline__ unsigned short f2bf(float f){
  union { float f; unsigned int i; } v; v.f = f;
  unsigned int u = v.i;
  u += 0x7FFFu + ((u >> 16) & 1u);
  return (unsigned short)(u >> 16);
}
__device__ __forceinline__ unsigned int pk(float a, float b){
  return (unsigned int)f2bf(a) | ((unsigned int)f2bf(b) << 16);
}
__device__ __forceinline__ void up2(int w, float& a, float& b){
  a = bf2f((unsigned short)(w & 0xFFFF));
  b = bf2f((unsigned short)(((unsigned int)w) >> 16));
}
__device__ __forceinline__ unsigned int encf(float f){
  union { float f; unsigned int i; } v; v.f = f;
  return ((int)v.i < 0) ? ~v.i : (v.i | 0x80000000u);
}
__device__ __forceinline__ float decf(unsigned int e){
  union { unsigned int i; float f; } v;
  v.i = ((int)e < 0) ? (e ^ 0x80000000u) : ~e;
  return v.f;
}
__device__ __forceinline__ void bn_coef(const float* st, const float* gamma, const float* beta,
                                        int c, float& sc, float& sh){
  float mean = st[c] * (1.0f / N_PTS);
  float var  = st[C + c] * (1.0f / N_PTS) - mean * mean;
  float g = gamma[c] * rsqrtf(fmaxf(var, 0.f) + BN_EPS);
  sc = g; sh = beta[c] - mean * g;
}

// ---------------- weight prep: f32 -> bf16, transposed to [n][k] ----------------
// tconv gets the conv-LDS XOR swizzle pre-applied (n&15: 16 slots over 32 lanes -> 2-way, free)
__global__ void k_prep_weights(const float* __restrict__ lw, const float* __restrict__ w,
                               const float* __restrict__ proj, const float* __restrict__ conv,
                               const float* __restrict__ fuse,
                               unsigned short* __restrict__ tlw, unsigned short* __restrict__ tw,
                               unsigned short* __restrict__ tproj, unsigned short* __restrict__ tconv,
                               unsigned short* __restrict__ tfuse)
{
  int z = blockIdx.x, tid = threadIdx.x;
  if (z < 64){
    const float* src; unsigned short* dst; bool swz = false;
    if (z < 3){ src = lw + z*16384; dst = tlw + z*16384; }
    else if (z < 6){ src = w + (z-3)*16384; dst = tw + (z-3)*16384; }
    else if (z < 10){ src = proj + (z-6)*16384; dst = tproj + (z-6)*16384; }
    else { src = conv + (z-10)*16384; dst = tconv + (z-10)*16384; swz = true; }
    for (int i = tid; i < 16384; i += 256){
      int n = i >> 7, k = i & 127;
      int pos = swz ? (n*128 + (((k >> 3) ^ (n & 15)) << 3) + (k & 7)) : i;
      dst[pos] = f2bf(src[k*128 + n]);
    }
  } else {
    for (int i = tid; i < 32768; i += 256){
      int n = i >> 8, k = i & 255;
      tfuse[i] = f2bf(fuse[k*128 + n]);
    }
  }
}

// ---------------- mask dtype detection (int32 vs packed bytes) ----------------
__global__ void k_detect_mask(const unsigned int* __restrict__ mw, int* __restrict__ mmode)
{
  __shared__ int flag;
  if (threadIdx.x == 0) flag = 0;
  __syncthreads();
  for (int i = threadIdx.x; i < 4096; i += 256)
    if (mw[i] > 1u) flag = 1;
  __syncthreads();
  if (threadIdx.x == 0) *mmode = flag;
}

// ---------------- cluster histogram / prefix / scatter ----------------
__global__ void k_hist(const int* __restrict__ c0, const int* __restrict__ c1,
                       const int* __restrict__ c2, int* __restrict__ hist)
{
  int idx = blockIdx.x*blockDim.x + threadIdx.x;
  int stride = gridDim.x*blockDim.x;
  for (; idx < 3*N_PTS; idx += stride){
    int j = idx / N_PTS, r = idx - j*N_PTS;
    const int* cp = (j==0)?c0:((j==1)?c1:c2);
    atomicAdd(&hist[j*NCLU + cp[r]], 1);
  }
}

__global__ void k_prefix(const int* __restrict__ hist, int* __restrict__ starts,
                         int* __restrict__ cursor)
{
  int j = blockIdx.x, tid = threadIdx.x;
  __shared__ int buf[NCLU];
  __shared__ int csum[256];
  for (int i = tid; i < NCLU; i += 256) buf[i] = hist[j*NCLU + i];
  __syncthreads();
  int s = 0;
  #pragma unroll
  for (int k = 0; k < 8; k++) s += buf[tid*8 + k];
  csum[tid] = s;
  __syncthreads();
  if (tid == 0){
    int run = 0;
    for (int i = 0; i < 256; i++){ int t = csum[i]; csum[i] = run; run += t; }
  }
  __syncthreads();
  int acc = csum[tid];
  #pragma unroll
  for (int k = 0; k < 8; k++){
    int i = tid*8 + k;
    starts[j*(NCLU+1) + i] = acc;
    cursor[j*NCLU + i] = acc;
    acc += buf[i];
  }
  if (tid == 255) starts[j*(NCLU+1) + NCLU] = acc;
}

__global__ void k_scatter(const int* __restrict__ c0, const int* __restrict__ c1,
                          const int* __restrict__ c2, int* __restrict__ cursor,
                          int* __restrict__ perm)
{
  int idx = blockIdx.x*blockDim.x + threadIdx.x;
  int stride = gridDim.x*blockDim.x;
  for (; idx < 3*N_PTS; idx += stride){
    int j = idx / N_PTS, r = idx - j*N_PTS;
    const int* cp = (j==0)?c0:((j==1)?c1:c2);
    int cl = cp[r];
    int slot = atomicAdd(&cursor[j*NCLU + cl], 1);
    perm[j*N_PTS + slot] = r;
  }
}

// ---------------- segment reduction V0: S1 = per-cluster sum of relu(bn(x)) ----------------
template<int V>
__global__ void k_seg(const unsigned short* __restrict__ X,
                      const int* __restrict__ perm, const int* __restrict__ starts,
                      const float* __restrict__ st, const float* __restrict__ gamma,
                      const float* __restrict__ beta, float* __restrict__ S)
{
  __shared__ float red[16*128];
  const int cl = blockIdx.x;
  const int p0 = starts[cl], p1 = starts[cl+1];
  const int g = threadIdx.x >> 4, s = threadIdx.x & 15;
  const int c0 = s * 8;
  float sc[8], sh[8];
  #pragma unroll
  for (int j = 0; j < 8; j++) bn_coef(st, gamma, beta, c0 + j, sc[j], sh[j]);
  float acc[8];
  #pragma unroll
  for (int j = 0; j < 8; j++) acc[j] = 0.f;
  for (int p = p0 + g; p < p1; p += 16){
    int row = perm[p];
    int4 v = *(const int4*)(X + (size_t)row*C + c0);
    float f[8];
    up2(v.x, f[0], f[1]); up2(v.y, f[2], f[3]); up2(v.z, f[4], f[5]); up2(v.w, f[6], f[7]);
    #pragma unroll
    for (int j = 0; j < 8; j++) acc[j] += fmaxf(f[j]*sc[j] + sh[j], 0.f);
  }
  #pragma unroll
  for (int j = 0; j < 8; j++) red[g*128 + c0 + j] = acc[j];
  __syncthreads();
  if (threadIdx.x < 128){
    float t = 0.f;
    #pragma unroll
    for (int gg = 0; gg < 16; gg++) t += red[gg*128 + threadIdx.x];
    S[cl*C + threadIdx.x] = t;
  }
}

// ---------------- single-pass seg12 ----------------
__global__ void k_seg12(const unsigned short* __restrict__ XP, const unsigned short* __restrict__ X2,
                        const int* __restrict__ perm, const int* __restrict__ starts,
                        const float* __restrict__ st, const float* __restrict__ gamma,
                        const float* __restrict__ beta, const unsigned int* __restrict__ genc,
                        float* __restrict__ S3)
{
  __shared__ float red[16*128];
  const int cl = blockIdx.x;
  const int p0 = starts[cl], p1 = starts[cl+1];
  const int g = threadIdx.x >> 4, s = threadIdx.x & 15;
  const int c0 = s * 8;
  const float gm = decf(*genc);
  float sc[8], sh[8];
  #pragma unroll
  for (int j = 0; j < 8; j++) bn_coef(st, gamma, beta, c0 + j, sc[j], sh[j]);

  float accN[8], accD[8];
  #pragma unroll
  for (int j = 0; j < 8; j++){ accN[j] = 0.f; accD[j] = 0.f; }
  for (int p = p0 + g; p < p1; p += 16){
    int row = perm[p];
    int4 v  = *(const int4*)(XP + (size_t)row*C + c0);
    int4 v2 = *(const int4*)(X2 + (size_t)row*C + c0);
    float f[8], x2[8];
    up2(v.x, f[0], f[1]); up2(v.y, f[2], f[3]); up2(v.z, f[4], f[5]); up2(v.w, f[6], f[7]);
    up2(v2.x, x2[0], x2[1]); up2(v2.y, x2[2], x2[3]); up2(v2.z, x2[4], x2[5]); up2(v2.w, x2[6], x2[7]);
    #pragma unroll
    for (int j = 0; j < 8; j++){
      float e = __expf(x2[j] - gm);
      accD[j] += e;
      accN[j] += fmaxf(f[j]*sc[j] + sh[j], 0.f) * e;
    }
  }
  #pragma unroll
  for (int j = 0; j < 8; j++) red[g*128 + c0 + j] = accN[j];
  __syncthreads();
  float tN = 0.f;
  if (threadIdx.x < 128){
    #pragma unroll
    for (int gg = 0; gg < 16; gg++) tN += red[gg*128 + threadIdx.x];
  }
  __syncthreads();
  #pragma unroll
  for (int j = 0; j < 8; j++) red[g*128 + c0 + j] = accD[j];
  __syncthreads();
  if (threadIdx.x < 128){
    float tD = 0.f;
    #pragma unroll
    for (int gg = 0; gg < 16; gg++) tD += red[gg*128 + threadIdx.x];
    S3[cl*C + threadIdx.x] = tN / (tD + 1e-6f);
  }
}

// ---------------- adaptive softmax weights (+ bf16 feat side-write) ----------------
__global__ void k_adp(const float* __restrict__ feat, const float* __restrict__ aW,
                      float* __restrict__ adp, unsigned short* __restrict__ featb)
{
  __shared__ float wsh[384];
  int tid = threadIdx.x;
  for (int i = tid; i < 384; i += 256) wsh[i] = aW[i];
  __syncthreads();
  int gidx = blockIdx.x*256 + tid;
  int stride = gridDim.x*256;
  for (int t4 = gidx; t4 < N_PTS*4; t4 += stride){
    int row = t4 >> 2, part = t4 & 3;
    float e0=0.f, e1=0.f, e2=0.f;
    const float* fr = feat + (size_t)row*C + part*32;
    unsigned int pb[16];
    #pragma unroll
    for (int c = 0; c < 32; c += 4){
      float4 v = *(const float4*)(fr + c);
      int cc = part*32 + c;
      e0 += v.x*wsh[cc*3+0] + v.y*wsh[(cc+1)*3+0] + v.z*wsh[(cc+2)*3+0] + v.w*wsh[(cc+3)*3+0];
      e1 += v.x*wsh[cc*3+1] + v.y*wsh[(cc+1)*3+1] + v.z*wsh[(cc+2)*3+1] + v.w*wsh[(cc+3)*3+1];
      e2 += v.x*wsh[cc*3+2] + v.y*wsh[(cc+1)*3+2] + v.z*wsh[(cc+2)*3+2] + v.w*wsh[(cc+3)*3+2];
      pb[(c>>1)]   = pk(v.x, v.y);
      pb[(c>>1)+1] = pk(v.z, v.w);
    }
    if (featb){
      int4* dst = (int4*)(featb + (size_t)row*C + part*32);
      dst[0] = make_int4(pb[0], pb[1], pb[2], pb[3]);
      dst[1] = make_int4(pb[4], pb[5], pb[6], pb[7]);
      dst[2] = make_int4(pb[8], pb[9], pb[10], pb[11]);
      dst[3] = make_int4(pb[12], pb[13], pb[14], pb[15]);
    }
    e0 += __shfl_xor(e0, 1); e0 += __shfl_xor(e0, 2);
    e1 += __shfl_xor(e1, 1); e1 += __shfl_xor(e1, 2);
    e2 += __shfl_xor(e2, 1); e2 += __shfl_xor(e2, 2);
    if (part == 0){
      float m = fmaxf(e0, fmaxf(e1, e2));
      float p0 = __expf(e0-m), p1 = __expf(e1-m), p2 = __expf(e2-m);
      float inv = 1.f/(p0+p1+p2);
      adp[row*3+0] = p0*inv; adp[row*3+1] = p1*inv; adp[row*3+2] = p2*inv;
    }
  }
}

// shared stats epilogue for 4-wave GEMM blocks (sred must hold 1024 floats)
__device__ __forceinline__ void gemm_stats_epi(float* csum, float* csq, float* sred,
                                               int wave, int l4, int l16, int tid,
                                               float* __restrict__ stats)
{
  #pragma unroll
  for (int t = 0; t < 8; t++){
    csum[t] += __shfl_xor(csum[t], 16); csum[t] += __shfl_xor(csum[t], 32);
    csq[t]  += __shfl_xor(csq[t], 16);  csq[t]  += __shfl_xor(csq[t], 32);
  }
  if (l4 == 0){
    #pragma unroll
    for (int t = 0; t < 8; t++){
      sred[wave*128 + t*16 + l16] = csum[t];
      sred[512 + wave*128 + t*16 + l16] = csq[t];
    }
  }
  __syncthreads();
  if (tid < 128){
    float s = 0.f, q = 0.f;
    #pragma unroll
    for (int w2 = 0; w2 < 4; w2++){ s += sred[w2*128 + tid]; q += sred[512 + w2*128 + tid]; }
    atomicAdd(&stats[tid], s);
    atomicAdd(&stats[C + tid], q);
  }
}

// A staging helper: 64 rows x 128 k into As (bf16)
template<typename AT>
__device__ __forceinline__ void stage_A(const AT* __restrict__ A, unsigned short* As,
                                        int row0, int r, int s)
{
  #pragma unroll
  for (int p = 0; p < 4; p++){
    int rr = r + p * 16;
    if constexpr (sizeof(AT) == 2){
      *(int4*)(As + rr * KP + s * 8) =
        *(const int4*)((const unsigned short*)A + (size_t)(row0 + rr) * C + s * 8);
    } else {
      const float4* ap = (const float4*)((const float*)A + (size_t)(row0 + rr) * C + s * 8);
      float4 x = ap[0], y = ap[1];
      *(int4*)(As + rr * KP + s * 8) =
        make_int4(pk(x.x,x.y), pk(x.z,x.w), pk(y.x,y.y), pk(y.z,y.w));
    }
  }
}

// ---------------- GEMM: out[N,128] = A @ Bt, + fused column stats ----------------
template<typename AT>
__global__ __launch_bounds__(256, 3)
void k_gemm_plain(const AT* __restrict__ A, const unsigned short* __restrict__ Bt,
                  unsigned short* __restrict__ Out, float* __restrict__ stats)
{
  __shared__ unsigned short As[64 * KP];
  __shared__ unsigned short Bs[128 * KP];
  const int tid = threadIdx.x;
  const int row0 = blockIdx.x * 64;
  const int r = tid >> 4, s = tid & 15;
  stage_A<AT>(A, As, row0, r, s);
  #pragma unroll
  for (int p = 0; p < 8; p++){
    int nn = r + p * 16;
    *(int4*)(Bs + nn * KP + s * 8) = *(const int4*)(Bt + nn * C + s * 8);
  }
  __syncthreads();
  const int lane = tid & 63, wave = tid >> 6;
  const int l16 = lane & 15, l4 = lane >> 4, m0 = wave * 16;
  f32x4 acc[8];
  #pragma unroll
  for (int t = 0; t < 8; t++) acc[t] = (f32x4){0.f,0.f,0.f,0.f};
  #pragma unroll
  for (int kk = 0; kk < 4; kk++){
    s16x8 a = *(const s16x8*)(As + (m0 + l16) * KP + kk * 32 + l4 * 8);
    #pragma unroll
    for (int t = 0; t < 8; t++){
      s16x8 b = *(const s16x8*)(Bs + (t * 16 + l16) * KP + kk * 32 + l4 * 8);
      acc[t] = __builtin_amdgcn_mfma_f32_16x16x32_bf16(a, b, acc[t], 0, 0, 0);
    }
  }
  float csum[8], csq[8];
  #pragma unroll
  for (int t = 0; t < 8; t++){
    float ss = 0.f, qq = 0.f;
    #pragma unroll
    for (int q = 0; q < 4; q++){
      float v = acc[t][q];
      int grow = row0 + m0 + l4 * 4 + q;
      Out[(size_t)grow * C + t * 16 + l16] = f2bf(v);
      ss += v; qq += v*v;
    }
    csum[t] = ss; csq[t] = qq;
  }
  __syncthreads();
  gemm_stats_epi(csum, csq, (float*)As, wave, l4, l16, tid, stats);
}

// ---------------- dual GEMM: two weight matrices, A staged once ----------------
template<typename AT>
__global__ __launch_bounds__(256, 3)
void k_gemm_dual(const AT* __restrict__ A,
                 const unsigned short* __restrict__ Bt0, const unsigned short* __restrict__ Bt1,
                 unsigned short* __restrict__ Out0, unsigned short* __restrict__ Out1,
                 float* __restrict__ stats0, float* __restrict__ stats1)
{
  __shared__ unsigned short As[64 * KP];
  __shared__ unsigned short Bs[128 * KP];
  const int tid = threadIdx.x;
  const int row0 = blockIdx.x * 64;
  const int r = tid >> 4, s = tid & 15;
  const int lane = tid & 63, wave = tid >> 6;
  const int l16 = lane & 15, l4 = lane >> 4, m0 = wave * 16;

  stage_A<AT>(A, As, row0, r, s);
  #pragma unroll
  for (int p = 0; p < 8; p++){
    int nn = r + p * 16;
    *(int4*)(Bs + nn * KP + s * 8) = *(const int4*)(Bt0 + nn * C + s * 8);
  }
  __syncthreads();

  f32x4 acc[8];
  float csum0[8], csq0[8], csum1[8], csq1[8];

  #pragma unroll
  for (int t = 0; t < 8; t++) acc[t] = (f32x4){0.f,0.f,0.f,0.f};
  #pragma unroll
  for (int kk = 0; kk < 4; kk++){
    s16x8 a = *(const s16x8*)(As + (m0 + l16) * KP + kk * 32 + l4 * 8);
    #pragma unroll
    for (int t = 0; t < 8; t++){
      s16x8 b = *(const s16x8*)(Bs + (t * 16 + l16) * KP + kk * 32 + l4 * 8);
      acc[t] = __builtin_amdgcn_mfma_f32_16x16x32_bf16(a, b, acc[t], 0, 0, 0);
    }
  }
  #pragma unroll
  for (int t = 0; t < 8; t++){
    float ss = 0.f, qq = 0.f;
    #pragma unroll
    for (int q = 0; q < 4; q++){
      float v = acc[t][q];
      int grow = row0 + m0 + l4 * 4 + q;
      Out0[(size_t)grow * C + t * 16 + l16] = f2bf(v);
      ss += v; qq += v*v;
    }
    csum0[t] = ss; csq0[t] = qq;
  }
  __syncthreads();
  #pragma unroll
  for (int p = 0; p < 8; p++){
    int nn = r + p * 16;
    *(int4*)(Bs + nn * KP + s * 8) = *(const int4*)(Bt1 + nn * C + s * 8);
  }
  __syncthreads();

  #pragma unroll
  for (int t = 0; t < 8; t++) acc[t] = (f32x4){0.f,0.f,0.f,0.f};
  #pragma unroll
  for (int kk = 0; kk < 4; kk++){
    s16x8 a = *(const s16x8*)(As + (m0 + l16) * KP + kk * 32 + l4 * 8);
    #pragma unroll
    for (int t = 0; t < 8; t++){
      s16x8 b = *(const s16x8*)(Bs + (t * 16 + l16) * KP + kk * 32 + l4 * 8);
      acc[t] = __builtin_amdgcn_mfma_f32_16x16x32_bf16(a, b, acc[t], 0, 0, 0);
    }
  }
  #pragma unroll
  for (int t = 0; t < 8; t++){
    float ss = 0.f, qq = 0.f;
    #pragma unroll
    for (int q = 0; q < 4; q++){
      float v = acc[t][q];
      int grow = row0 + m0 + l4 * 4 + q;
      Out1[(size_t)grow * C + t * 16 + l16] = f2bf(v);
      ss += v; qq += v*v;
    }
    csum1[t] = ss; csq1[t] = qq;
  }
  __syncthreads();
  gemm_stats_epi(csum0, csq0, (float*)As, wave, l4, l16, tid, stats0);
  __syncthreads();
  gemm_stats_epi(csum1, csq1, (float*)As, wave, l4, l16, tid, stats1);
}

// ---------------- GEMM: (relu(bn(x)) - clustermean) @ w_W + global max ----------------
__global__ __launch_bounds__(256, 3)
void k_gemm_center(const unsigned short* __restrict__ PW, const unsigned short* __restrict__ Bt,
                   const int* __restrict__ cla, const float* __restrict__ S1,
                   const int* __restrict__ cnt, const float* __restrict__ st,
                   const float* __restrict__ gamma, const float* __restrict__ beta,
                   unsigned short* __restrict__ Out, unsigned int* __restrict__ gmax)
{
  __shared__ unsigned short As[64 * KP];
  __shared__ unsigned short Bs[128 * KP];
  __shared__ float wred[4];
  const int tid = threadIdx.x;
  const int row0 = blockIdx.x * 64;
  const int r = tid >> 4, s = tid & 15;
  float sc[8], sh[8];
  #pragma unroll
  for (int j = 0; j < 8; j++) bn_coef(st, gamma, beta, s*8 + j, sc[j], sh[j]);
  #pragma unroll
  for (int p = 0; p < 4; p++){
    int rr = r + p * 16;
    int grow = row0 + rr;
    int cl = cla[grow];
    float inv = 1.f / fmaxf(1.f, (float)cnt[cl]);
    int4 v = *(const int4*)(PW + (size_t)grow * C + s * 8);
    const float4* mp = (const float4*)(S1 + cl * C + s * 8);
    float4 ma = mp[0], mb = mp[1];
    float f[8];
    up2(v.x, f[0], f[1]); up2(v.y, f[2], f[3]); up2(v.z, f[4], f[5]); up2(v.w, f[6], f[7]);
    float m8[8] = {ma.x,ma.y,ma.z,ma.w,mb.x,mb.y,mb.z,mb.w};
    float o[8];
    #pragma unroll
    for (int j = 0; j < 8; j++) o[j] = fmaxf(f[j]*sc[j] + sh[j], 0.f) - m8[j]*inv;
    *(int4*)(As + rr * KP + s * 8) = make_int4(pk(o[0],o[1]), pk(o[2],o[3]), pk(o[4],o[5]), pk(o[6],o[7]));
  }
  #pragma unroll
  for (int p = 0; p < 8; p++){
    int nn = r + p * 16;
    *(int4*)(Bs + nn * KP + s * 8) = *(const int4*)(Bt + nn * C + s * 8);
  }
  __syncthreads();
  const int lane = tid & 63, wave = tid >> 6;
  const int l16 = lane & 15, l4 = lane >> 4, m0 = wave * 16;
  f32x4 acc[8];
  #pragma unroll
  for (int t = 0; t < 8; t++) acc[t] = (f32x4){0.f,0.f,0.f,0.f};
  #pragma unroll
  for (int kk = 0; kk < 4; kk++){
    s16x8 a = *(const s16x8*)(As + (m0 + l16) * KP + kk * 32 + l4 * 8);
    #pragma unroll
    for (int t = 0; t < 8; t++){
      s16x8 b = *(const s16x8*)(Bs + (t * 16 + l16) * KP + kk * 32 + l4 * 8);
      acc[t] = __builtin_amdgcn_mfma_f32_16x16x32_bf16(a, b, acc[t], 0, 0, 0);
    }
  }
  float mx = -3.4e38f;
  #pragma unroll
  for (int t = 0; t < 8; t++){
    #pragma unroll
    for (int q = 0; q < 4; q++){
      int grow = row0 + m0 + l4 * 4 + q;
      unsigned short ob = f2bf(acc[t][q]);
      Out[(size_t)grow * C + t * 16 + l16] = ob;
      mx = fmaxf(mx, bf2f(ob));
    }
  }
  #pragma unroll
  for (int off = 32; off; off >>= 1) mx = fmaxf(mx, __shfl_xor(mx, off));
  if ((tid & 63) == 0) wred[tid >> 6] = mx;
  __syncthreads();
  if (tid == 0){
    float m = fmaxf(fmaxf(wred[0], wred[1]), fmaxf(wred[2], wred[3]));
    atomicMax(gmax, encf(m));
  }
}

// ---------------- fuse GEMM: [relu(bn(xp3)), fused] @ fuse_W, K=256, + stats ----------------
__global__ __launch_bounds__(256, 2)
void k_gemm_fuse(const unsigned short* __restrict__ XP3, const float* __restrict__ adp,
                 const int* __restrict__ cl0, const int* __restrict__ cl1,
                 const int* __restrict__ cl2, const float* __restrict__ S3,
                 const float* __restrict__ st, const float* __restrict__ gamma,
                 const float* __restrict__ beta, const unsigned short* __restrict__ Bt,
                 unsigned short* __restrict__ Out, float* __restrict__ stats)
{
  __shared__ unsigned short As[64 * KP2];
  __shared__ unsigned short Bs[128 * KP];
  __shared__ float scs[C], shs[C];
  const int tid = threadIdx.x;
  if (tid < C){ float a, b; bn_coef(st, gamma, beta, tid, a, b); scs[tid] = a; shs[tid] = b; }
  __syncthreads();
  const int row0 = blockIdx.x * 64;
  const int r8 = tid >> 5, s = tid & 31;
  const int r = tid >> 4, s16i = tid & 15;
  #pragma unroll
  for (int p = 0; p < 8; p++){
    int rr = r8 + p * 8;
    int grow = row0 + rr;
    if (s < 16){
      int c0 = s * 8;
      int4 v = *(const int4*)(XP3 + (size_t)grow * C + c0);
      float f0,f1,f2,f3,f4,f5,f6,f7;
      up2(v.x,f0,f1); up2(v.y,f2,f3); up2(v.z,f4,f5); up2(v.w,f6,f7);
      float o0 = fmaxf(f0*scs[c0+0]+shs[c0+0],0.f), o1 = fmaxf(f1*scs[c0+1]+shs[c0+1],0.f);
      float o2 = fmaxf(f2*scs[c0+2]+shs[c0+2],0.f), o3 = fmaxf(f3*scs[c0+3]+shs[c0+3],0.f);
      float o4 = fmaxf(f4*scs[c0+4]+shs[c0+4],0.f), o5 = fmaxf(f5*scs[c0+5]+shs[c0+5],0.f);
      float o6 = fmaxf(f6*scs[c0+6]+shs[c0+6],0.f), o7 = fmaxf(f7*scs[c0+7]+shs[c0+7],0.f);
      *(int4*)(As + rr * KP2 + c0) = make_int4(pk(o0,o1), pk(o2,o3), pk(o4,o5), pk(o6,o7));
    } else {
      int c0 = (s - 16) * 8;
      float a0 = adp[grow*3+0], a1 = adp[grow*3+1], a2 = adp[grow*3+2];
      const float* p0 = S3 + (size_t)cl0[grow] * C + c0;
      const float* p1 = S3 + (size_t)NCLU * C + (size_t)cl1[grow] * C + c0;
      const float* p2 = S3 + (size_t)2 * NCLU * C + (size_t)cl2[grow] * C + c0;
      float o[8];
      #pragma unroll
      for (int j = 0; j < 8; j++) o[j] = a0*p0[j] + a1*p1[j] + a2*p2[j];
      *(int4*)(As + rr * KP2 + 128 + c0) = make_int4(pk(o[0],o[1]), pk(o[2],o[3]), pk(o[4],o[5]), pk(o[6],o[7]));
    }
  }
  const int lane = tid & 63, wave = tid >> 6;
  const int l16 = lane & 15, l4 = lane >> 4, m0 = wave * 16;
  f32x4 acc[8];
  #pragma unroll
  for (int t = 0; t < 8; t++) acc[t] = (f32x4){0.f,0.f,0.f,0.f};
  #pragma unroll
  for (int h = 0; h < 2; h++){
    if (h) __syncthreads();
    #pragma unroll
    for (int p = 0; p < 8; p++){
      int nn = r + p * 16;
      *(int4*)(Bs + nn * KP + s16i * 8) = *(const int4*)(Bt + nn * 256 + h * 128 + s16i * 8);
    }
    __syncthreads();
    #pragma unroll
    for (int kk = 0; kk < 4; kk++){
      s16x8 a = *(const s16x8*)(As + (m0 + l16) * KP2 + h * 128 + kk * 32 + l4 * 8);
      #pragma unroll
      for (int t = 0; t < 8; t++){
        s16x8 b = *(const s16x8*)(Bs + (t * 16 + l16) * KP + kk * 32 + l4 * 8);
        acc[t] = __builtin_amdgcn_mfma_f32_16x16x32_bf16(a, b, acc[t], 0, 0, 0);
      }
    }
  }
  float csum[8], csq[8];
  #pragma unroll
  for (int t = 0; t < 8; t++){
    float ss = 0.f, qq = 0.f;
    #pragma unroll
    for (int q = 0; q < 4; q++){
      float v = acc[t][q];
      int grow = row0 + m0 + l4 * 4 + q;
      Out[(size_t)grow * C + t * 16 + l16] = f2bf(v);
      ss += v; qq += v*v;
    }
    csum[t] = ss; csq[t] = qq;
  }
  __syncthreads();
  gemm_stats_epi(csum, csq, (float*)As, wave, l4, l16, tid, stats);
}

// ---------------- submanifold conv v15: 32x32x16, single 32KB buffer, single-A JIT gather ----------------
__device__ __forceinline__ int ld_midx(const int* __restrict__ nbr, const void* __restrict__ maskp,
                                       int mm, int g){
  bool on = mm ? (((const unsigned char*)maskp)[g] != 0)
               : (((const int*)maskp)[g] != 0);
  int v = nbr[g];
  return on ? v : -1;
}

template<typename OT>
__global__ __launch_bounds__(256, 2)
void k_conv(const unsigned short* __restrict__ In, const unsigned short* __restrict__ Wt,
            const int* __restrict__ nbr, const void* __restrict__ maskp,
            const int* __restrict__ mmode, OT* __restrict__ Out, float* __restrict__ stats)
{
  __shared__ unsigned short Bs[128*128];      // 32 KiB single buffer, pre-swizzled source
  const int tid = threadIdx.x;
  const int lane = tid & 63, wave = tid >> 6;   // 4 waves
  const int l31 = lane & 31, half = lane >> 5;
  const int row0 = blockIdx.x * 128;            // 128 rows/block, 32 rows/wave
  const int mm = *mmode;
  const int rg = row0 + wave*32 + l31;          // this lane's row
  const s16x8 z8 = (s16x8){0,0,0,0,0,0,0,0};

  auto stage_B = [&](int k){
    const char* gsrc = (const char*)(Wt + k*16384);
    char* lbase = (char*)&Bs[0];
    #pragma unroll
    for (int p = 0; p < 8; p++){
      int chunk = p*256 + wave*64;              // wave-uniform LDS base
      __builtin_amdgcn_global_load_lds(
        (const unsigned int*)(gsrc + (size_t)(chunk + lane)*16),
        (unsigned int*)(lbase + (size_t)chunk*16), 16, 0, 0);
    }
  };

  f32x16 acc[4];
  #pragma unroll
  for (int t = 0; t < 4; t++)
    acc[t] = (f32x16){0,0,0,0,0,0,0,0,0,0,0,0,0,0,0,0};

  s16x8 A[8];   // single A buffer: JIT gather (saves 32 VGPR -> 3 waves/SIMD)
  auto gather = [&](int gi){
    #pragma unroll
    for (int s = 0; s < 8; s++)
      A[s] = (gi >= 0) ? *(const s16x8*)(In + (size_t)gi*C + s*16 + half*8) : z8;
  };
  auto compute = [&](){
    #pragma unroll
    for (int s = 0; s < 8; s++){
      #pragma unroll
      for (int t = 0; t < 4; t++){
        int n = t*32 + l31;
        s16x8 b = *(const s16x8*)(&Bs[n*128 + (((s*2 + half) ^ (n & 15)) << 3)]);
        acc[t] = __builtin_amdgcn_mfma_f32_32x32x16_bf16(A[s], b, acc[t], 0, 0, 0);
      }
    }
  };

  // prologue: B[0] staged, idx(0) prefetched
  stage_B(0);
  int i0 = ld_midx(nbr, maskp, mm, rg*K27 + 0);
  __syncthreads();                              // buf(W0) ready

  #pragma unroll 1
  for (int k = 0; k < K27; k++){
    gather(i0);                                 // A(k) — independent of Bs
    if (k + 1 < K27) i0 = ld_midx(nbr, maskp, mm, rg*K27 + k + 1);
    compute();                                  // reads Bs(W[k])
    __syncthreads();                            // all reads of Bs done
    if (k + 1 < K27){
      stage_B(k + 1);
      __syncthreads();                          // buf(W[k+1]) ready
    }
  }

  // epilogue: write + fused column stats
  // C/D layout (verified): col = lane&31, row = (reg&3) + 8*(reg>>2) + 4*(lane>>5)
  float csum[4], csq[4];
  #pragma unroll
  for (int t = 0; t < 4; t++){
    float ss = 0.f, qq = 0.f;
    #pragma unroll
    for (int r = 0; r < 16; r++){
      float v = acc[t][r];
      int grow = row0 + wave*32 + (r & 3) + 8*(r >> 2) + 4*half;
      if constexpr (sizeof(OT) == 2) Out[(size_t)grow * C + t*32 + l31] = f2bf(v);
      else                           Out[(size_t)grow * C + t*32 + l31] = v;
      ss += v; qq += v*v;
    }
    csum[t] = ss; csq[t] = qq;
  }
  #pragma unroll
  for (int t = 0; t < 4; t++){
    csum[t] += __shfl_xor(csum[t], 32);
    csq[t]  += __shfl_xor(csq[t], 32);
  }
  __syncthreads();
  float* sred = (float*)Bs;
  if (half == 0){
    #pragma unroll
    for (int t = 0; t < 4; t++){
      sred[wave*128 + t*32 + l31] = csum[t];
      sred[512 + wave*128 + t*32 + l31] = csq[t];
    }
  }
  __syncthreads();
  if (tid < 128){
    float s = 0.f, q = 0.f;
    #pragma unroll
    for (int w2 = 0; w2 < 4; w2++){ s += sred[w2*128 + tid]; q += sred[512 + w2*128 + tid]; }
    atomicAdd(&stats[tid], s);
    atomicAdd(&stats[C + tid], q);
  }
}

// ---------------- elementwise kernels ----------------
template<int RELU>
__global__ void k_bnapply(const unsigned short* __restrict__ X, unsigned short* __restrict__ Y,
                          const float* __restrict__ st, const float* __restrict__ gamma,
                          const float* __restrict__ beta)
{
  const int total = N_PTS * 16;
  for (int idx = blockIdx.x*blockDim.x + threadIdx.x; idx < total; idx += gridDim.x*blockDim.x){
    int c0 = (idx & 15) * 8;
    int4 v = *(const int4*)(X + (size_t)idx * 8);
    float f[8];
    up2(v.x, f[0], f[1]); up2(v.y, f[2], f[3]); up2(v.z, f[4], f[5]); up2(v.w, f[6], f[7]);
    float o[8];
    #pragma unroll
    for (int j = 0; j < 8; j++){
      float sc, sh; bn_coef(st, gamma, beta, c0 + j, sc, sh);
      float t = f[j] * sc + sh;
      if (RELU) t = fmaxf(t, 0.f);
      o[j] = t;
    }
    *(int4*)(Y + (size_t)idx * 8) = make_int4(pk(o[0],o[1]), pk(o[2],o[3]), pk(o[4],o[5]), pk(o[6],o[7]));
  }
}

__global__ void k_fres(const unsigned short* __restrict__ G, const float* __restrict__ st,
                       const float* __restrict__ gamma, const float* __restrict__ beta,
                       const float* __restrict__ feat, unsigned short* __restrict__ FB)
{
  const int total = N_PTS * 16;
  for (int idx = blockIdx.x*blockDim.x + threadIdx.x; idx < total; idx += gridDim.x*blockDim.x){
    int c0 = (idx & 15) * 8;
    int4 v = *(const int4*)(G + (size_t)idx * 8);
    float f[8];
    up2(v.x, f[0], f[1]); up2(v.y, f[2], f[3]); up2(v.z, f[4], f[5]); up2(v.w, f[6], f[7]);
    const float4* fp = (const float4*)(feat + (size_t)idx * 8);
    float4 fa = fp[0], fb4 = fp[1];
    float fe[8] = {fa.x,fa.y,fa.z,fa.w,fb4.x,fb4.y,fb4.z,fb4.w};
    float o[8];
    #pragma unroll
    for (int j = 0; j < 8; j++){
      float sc, sh; bn_coef(st, gamma, beta, c0 + j, sc, sh);
      o[j] = fmaxf(f[j]*sc + sh, 0.f) + fe[j];
    }
    *(int4*)(FB + (size_t)idx * 8) = make_int4(pk(o[0],o[1]), pk(o[2],o[3]), pk(o[4],o[5]), pk(o[6],o[7]));
  }
}

__global__ void k_final(float* __restrict__ H2, const float* __restrict__ st,
                        const float* __restrict__ gamma, const float* __restrict__ beta,
                        const unsigned short* __restrict__ FB)
{
  const int total = N_PTS * 16;
  for (int idx = blockIdx.x*blockDim.x + threadIdx.x; idx < total; idx += gridDim.x*blockDim.x){
    int c0 = (idx & 15) * 8;
    float4* hp = (float4*)(H2 + (size_t)idx * 8);
    float4 a = hp[0], b = hp[1];
    int4 vf = *(const int4*)(FB + (size_t)idx * 8);
    float fr[8];
    up2(vf.x, fr[0], fr[1]); up2(vf.y, fr[2], fr[3]); up2(vf.z, fr[4], fr[5]); up2(vf.w, fr[6], fr[7]);
    float h[8] = {a.x,a.y,a.z,a.w,b.x,b.y,b.z,b.w};
    #pragma unroll
    for (int j = 0; j < 8; j++){
      float sc, sh; bn_coef(st, gamma, beta, c0 + j, sc, sh);
      h[j] = fmaxf(h[j]*sc + sh + fr[j], 0.f);
    }
    hp[0] = make_float4(h[0],h[1],h[2],h[3]);
    hp[1] = make_float4(h[4],h[5],h[6],h[7]);
  }
}

extern "C" void kernel_launch(void* const* d_in, const int* in_sizes, int n_in,
                              void* d_out, int out_size, void* d_ws, size_t ws_size,
                              hipStream_t stream)
{
  (void)in_sizes; (void)n_in; (void)out_size;
  const float* feat   = (const float*)d_in[0];
  const int* cls[3]   = {(const int*)d_in[1], (const int*)d_in[2], (const int*)d_in[3]};
  const int* nbr      = (const int*)d_in[4];
  const void* mask    = d_in[5];
  const float* lw_W   = (const float*)d_in[6];
  const float* lw_g   = (const float*)d_in[7];
  const float* lw_b   = (const float*)d_in[8];
  const float* w_W    = (const float*)d_in[9];
  const float* proj_W = (const float*)d_in[10];
  const float* proj_g = (const float*)d_in[11];
  const float* proj_b = (const float*)d_in[12];
  const float* adW    = (const float*)d_in[13];
  const float* fuse_W = (const float*)d_in[14];
  const float* fuse_g = (const float*)d_in[15];
  const float* fuse_b = (const float*)d_in[16];
  const float* conv_W = (const float*)d_in[17];
  const float* conv_g = (const float*)d_in[18];
  const float* conv_b = (const float*)d_in[19];

  char* w = (char*)d_ws;
  float*          stats  = (float*)(w + 0);            // 10 slots x 256 f32
  unsigned int*   gmax   = (unsigned int*)(w + 10240); // 3
  int*            mmode  = (int*)(w + 10240 + 16);
  int*            hist   = (int*)(w + 10496);          // 3*2048
  int*            starts = (int*)(w + 35072);          // 3*2049
  int*            cursor = (int*)(w + 59904);          // 3*2048
  int*            perm   = (int*)(w + 84480);          // 3*N
  float*          S1     = (float*)(w + 2004480);      // 2048*128
  float*          S3     = (float*)(w + 4101632);      // 3*2048*128
  float*          adp    = (float*)(w + 7247360);      // N*3
  unsigned short* tlw    = (unsigned short*)(w + 9167360);
  unsigned short* tw     = (unsigned short*)(w + 9265664);
  unsigned short* tproj  = (unsigned short*)(w + 9363968);
  unsigned short* tfuse  = (unsigned short*)(w + 9495040);
  unsigned short* tconv  = (unsigned short*)(w + 9560576);
  unsigned short* B1     = (unsigned short*)(w + 11330048);
  unsigned short* B2     = (unsigned short*)(w + 52290048);
  unsigned short* B3     = (unsigned short*)(w + 93250048);
  // base ws usage: 134,210,048 bytes; optional featb adds 40,960,000
  const bool useb = ws_size >= (size_t)175170048;
  unsigned short* featb = useb ? (unsigned short*)(w + 134210048) : nullptr;

  hipMemsetAsync(d_ws, 0, 35072, stream); // stats + gmax + mmode + hist

  k_prep_weights<<<65, 256, 0, stream>>>(lw_W, w_W, proj_W, conv_W, fuse_W,
                                         tlw, tw, tproj, tconv, tfuse);
  k_detect_mask<<<1, 256, 0, stream>>>((const unsigned int*)mask, mmode);
  k_hist<<<1024, 256, 0, stream>>>(cls[0], cls[1], cls[2], hist);
  k_prefix<<<3, 256, 0, stream>>>(hist, starts, cursor);
  k_scatter<<<1024, 256, 0, stream>>>(cls[0], cls[1], cls[2], cursor, perm);
  k_adp<<<2500, 256, 0, stream>>>(feat, adW, adp, featb);

  if (useb) k_gemm_plain<unsigned short><<<2500, 256, 0, stream>>>(featb, tlw, B1, stats);
  else      k_gemm_plain<float><<<2500, 256, 0, stream>>>(feat, tlw, B1, stats);

  for (int i = 0; i < 3; i++){
    k_seg<0><<<2048, 256, 0, stream>>>(B1, perm + i*N_PTS, starts + i*(NCLU+1),
                                       stats + i*256, lw_g + i*C, lw_b + i*C, S1);
    k_gemm_center<<<2500, 256, 0, stream>>>(B1, tw + i*16384, cls[i], S1, hist + i*NCLU,
                                            stats + i*256, lw_g + i*C, lw_b + i*C, B3, gmax + i);
    const unsigned short* w0 = tproj + i*16384;
    const unsigned short* w1 = (i < 2) ? (tlw + (i+1)*16384) : (tproj + 3*16384);
    float* st1 = (i < 2) ? (stats + (i+1)*256) : (stats + 6*256);
    if (useb) k_gemm_dual<unsigned short><<<2500, 256, 0, stream>>>(featb, w0, w1, B2, B1,
                                                                    stats + (3+i)*256, st1);
    else      k_gemm_dual<float><<<2500, 256, 0, stream>>>(feat, w0, w1, B2, B1,
                                                           stats + (3+i)*256, st1);
    k_seg12<<<2048, 256, 0, stream>>>(B2, B3, perm + i*N_PTS, starts + i*(NCLU+1),
                                      stats + (3+i)*256, proj_g + i*C, proj_b + i*C,
                                      gmax + i, S3 + (size_t)i*NCLU*C);
  }

  k_gemm_fuse<<<2500, 256, 0, stream>>>(B1, adp, cls[0], cls[1], cls[2], S3,
                                        stats + 6*256, proj_g + 3*C, proj_b + 3*C, tfuse,
                                        B2, stats + 7*256);
  k_fres<<<2048, 256, 0, stream>>>(B2, stats + 7*256, fuse_g, fuse_b, feat, B3);

  k_conv<unsigned short><<<1250, 256, 0, stream>>>(B3, tconv, nbr, mask, mmode, B1, stats + 8*256);
  k_bnapply<1><<<2048, 256, 0, stream>>>(B1, B2, stats + 8*256, conv_g, conv_b);
  k_conv<float><<<1250, 256, 0, stream>>>(B2, tconv + 27*16384, nbr, mask, mmode,
                                          (float*)d_out, stats + 9*256);
  k_final<<<2048, 256, 0, stream>>>((float*)d_out, stats + 9*256, conv_g + C, conv_b + C, B3);
}